// Round 14
// baseline (481.655 us; speedup 1.0000x reference)
//
#include <hip/hip_runtime.h>
#include <math.h>

// ---------------------------------------------------------------------------
// CapsuleRoutingSelfAttention — round 14: bisect round-12 regression.
// Scores reverted to round-11-proven fp32 path (Qf/Kf f32, fp32 VALU scores);
// gemm_G keeps round-12's split-K=8 + padded LDS [128][40] (audited, fp32-add-
// order-only change vs the verified split-K=4 version).
//
// Workspace (float units), 66,588,672 fl = 254.0 MiB (ws = 256 MiB):
//   u16a  [4][1024][8192] bf16 @ 0            (16M fl)
//   QT16  [4][512][1024]  bf16 @ 16,777,216   (1M fl)
//   K16   [4][1024][512]  bf16 @ 17,825,792   (1M fl)
//   Win @ 18,874,368 .. 52,428,800 (32M fl), time-multiplexed:
//     Qf  [4096,512] f32 @18,874,368 (2M) | Kf @20,971,520 (2M) [die at scores]
//     V16a [4][1024,512] bf16 @23,068,672 (1M fl)  [dies after V-transpose]
//     Pa   32 x [1024^2] f32 @18,874,368 (32M)     [G -> merge]
//     sv16a [4][1024,8192] bf16 @18,874,368 (16M fl) [sfinal -> enh]
//     Mbufa [4][1024^2] f32 @35,651,584 (4M fl)      [M its -> scldot]
//     R16  [4][1024,512] bf16 @35,651,584 (1M fl)    [gemm_R -> sfinal]
//   vVa @52,428,800 (4M) | bHa @56,623,104 (4M; ctx16 overlays)
//   cH16a @60,817,408 (2M fl) | G16a @62,914,560 (2M fl)
//   VT16a @65,011,712 (1M fl) | WT16 @66,060,288 (0.5M fl)
//   scl @66,584,576 (4,096)
// ---------------------------------------------------------------------------

#define SQ_EPS 1e-8f

typedef __attribute__((ext_vector_type(4))) int i32x4;    // 8 bf16
typedef __attribute__((ext_vector_type(4))) float f32x4;

__device__ __forceinline__ float bf2f(unsigned int u) {
  union { unsigned int i; float f; } x;
  x.i = u << 16;
  return x.f;
}
__device__ __forceinline__ unsigned short f2bf(float f) {
  union { float f; unsigned int i; } x;
  x.f = f;
  unsigned int r = x.i + 0x7fffu + ((x.i >> 16) & 1u);
  return (unsigned short)(r >> 16);
}
__device__ __forceinline__ int packbf(float a, float b) {
  return (int)((unsigned int)f2bf(a) | ((unsigned int)f2bf(b) << 16));
}

__device__ __forceinline__ f32x4 mfma_bf16(i32x4 a, i32x4 b, f32x4 c) {
  asm("v_mfma_f32_16x16x32_bf16 %0, %1, %2, %0" : "+v"(c) : "v"(a), "v"(b));
  return c;
}

__device__ __forceinline__ float wredSum(float v) {
#pragma unroll
  for (int off = 32; off > 0; off >>= 1) v += __shfl_xor(v, off);
  return v;
}
__device__ __forceinline__ float wredMax(float v) {
#pragma unroll
  for (int off = 32; off > 0; off >>= 1) v = fmaxf(v, __shfl_xor(v, off));
  return v;
}
__device__ __forceinline__ float blockSum(float v, volatile float* red) {
  v = wredSum(v);
  int wid = threadIdx.x >> 6;
  __syncthreads();
  if ((threadIdx.x & 63) == 0) red[wid] = v;
  __syncthreads();
  return red[0] + red[1] + red[2] + red[3];
}
__device__ __forceinline__ float blockMax(float v, volatile float* red) {
  v = wredMax(v);
  int wid = threadIdx.x >> 6;
  __syncthreads();
  if ((threadIdx.x & 63) == 0) red[wid] = v;
  __syncthreads();
  return fmaxf(fmaxf(red[0], red[1]), fmaxf(red[2], red[3]));
}

// ---------------------------------------------------------------------------
// W^T prep (Wq,Wk,Wv,Wo) — round-11 verbatim.  Grid (8, 8, 4).
// ---------------------------------------------------------------------------
__global__ __launch_bounds__(256) void wtrans_kernel(
    const float* __restrict__ Wq, const float* __restrict__ Wk,
    const float* __restrict__ Wv, const float* __restrict__ Wo,
    unsigned short* __restrict__ WT16) {
  __shared__ unsigned short T[64][72];
  int z = blockIdx.z;
  const float* src = (z == 0) ? Wq : (z == 1) ? Wk : (z == 2) ? Wv : Wo;
  unsigned short* dst = WT16 + (long long)z * 262144;
  int i0 = blockIdx.x * 64;
  int c0 = blockIdx.y * 64;
  int t = (int)threadIdx.x;
  int r = t >> 2, cq = (t & 3) * 16;
#pragma unroll
  for (int j = 0; j < 4; j++) {
    float4 v = *(const float4*)&src[(long long)(i0 + r) * 512 + c0 + cq + j * 4];
    T[r][cq + j * 4 + 0] = f2bf(v.x);
    T[r][cq + j * 4 + 1] = f2bf(v.y);
    T[r][cq + j * 4 + 2] = f2bf(v.z);
    T[r][cq + j * 4 + 3] = f2bf(v.w);
  }
  __syncthreads();
  int c = t >> 2, iq = (t & 3) * 16;
  unsigned short tmp[16];
#pragma unroll
  for (int j = 0; j < 16; j++) tmp[j] = T[iq + j][c];
  *(i32x4*)&dst[(long long)(c0 + c) * 512 + i0 + iq] = *(i32x4*)&tmp[0];
  *(i32x4*)&dst[(long long)(c0 + c) * 512 + i0 + iq + 8] = *(i32x4*)&tmp[8];
}

// ---------------------------------------------------------------------------
// QKV (bf16 MFMA) — round-11 verbatim: z=0 -> Qf f32, z=1 -> Kf f32 + K16,
// z=2 -> V16 bf16.  Grid (8, 64, 3).
// ---------------------------------------------------------------------------
__global__ __launch_bounds__(256) void gemm_qkv_mfma(
    const float* __restrict__ x, const unsigned short* __restrict__ WT16,
    const float* __restrict__ bq, const float* __restrict__ bk,
    const float* __restrict__ bv, float* __restrict__ Qf,
    float* __restrict__ Kf, unsigned short* __restrict__ K16,
    unsigned short* __restrict__ V16) {
  __shared__ unsigned short Asl[64][68];
  __shared__ unsigned short Bsl[64][68];
  int z = blockIdx.z;
  const unsigned short* WT = WT16 + (long long)z * 262144;
  const float* bias = (z == 0) ? bq : (z == 1) ? bk : bv;

  int row0 = blockIdx.y * 64;
  int col0 = blockIdx.x * 64;
  int t = (int)threadIdx.x, lane = t & 63, wave = t >> 6;
  int wm = wave >> 1, wn = wave & 1;

  f32x4 acc[2][2];
#pragma unroll
  for (int i = 0; i < 2; i++)
#pragma unroll
    for (int j = 0; j < 2; j++) acc[i][j] = (f32x4){0.f, 0.f, 0.f, 0.f};

  int r = t >> 2, kq = (t & 3) * 8;
  const float* Ap = x + (long long)(row0 + r) * 512 + kq;
  const unsigned short* Bp = WT + (long long)(col0 + r) * 512 + kq;

  for (int kb = 0; kb < 512; kb += 64) {
    float4 a0 = *(const float4*)(Ap + kb);
    float4 a1 = *(const float4*)(Ap + kb + 4);
    float4 a2 = *(const float4*)(Ap + kb + 32);
    float4 a3 = *(const float4*)(Ap + kb + 36);
    i32x4 b0 = *(const i32x4*)(Bp + kb);
    i32x4 b1 = *(const i32x4*)(Bp + kb + 32);
    __syncthreads();
    i32x4 pa0 = {packbf(a0.x, a0.y), packbf(a0.z, a0.w), packbf(a1.x, a1.y),
                 packbf(a1.z, a1.w)};
    i32x4 pa1 = {packbf(a2.x, a2.y), packbf(a2.z, a2.w), packbf(a3.x, a3.y),
                 packbf(a3.z, a3.w)};
    *(i32x4*)&Asl[r][kq] = pa0;
    *(i32x4*)&Asl[r][kq + 32] = pa1;
    *(i32x4*)&Bsl[r][kq] = b0;
    *(i32x4*)&Bsl[r][kq + 32] = b1;
    __syncthreads();

    int rr = lane & 15, ko = (lane >> 4) * 8;
#pragma unroll
    for (int k2 = 0; k2 < 2; k2++) {
      i32x4 af0 = *(i32x4*)&Asl[wm * 32 + rr][k2 * 32 + ko];
      i32x4 af1 = *(i32x4*)&Asl[wm * 32 + 16 + rr][k2 * 32 + ko];
      i32x4 bf0 = *(i32x4*)&Bsl[wn * 32 + rr][k2 * 32 + ko];
      i32x4 bf1 = *(i32x4*)&Bsl[wn * 32 + 16 + rr][k2 * 32 + ko];
      acc[0][0] = mfma_bf16(af0, bf0, acc[0][0]);
      acc[0][1] = mfma_bf16(af0, bf1, acc[0][1]);
      acc[1][0] = mfma_bf16(af1, bf0, acc[1][0]);
      acc[1][1] = mfma_bf16(af1, bf1, acc[1][1]);
    }
  }

  int rq = lane >> 4, rr = lane & 15;
#pragma unroll
  for (int fm = 0; fm < 2; fm++) {
#pragma unroll
    for (int fn = 0; fn < 2; fn++) {
      int col = col0 + wn * 32 + fn * 16 + rr;
      float bb = bias[col];
#pragma unroll
      for (int rl = 0; rl < 4; rl++) {
        int row = row0 + wm * 32 + fm * 16 + rq * 4 + rl;
        float v = acc[fm][fn][rl] + bb;
        if (z == 2) {
          V16[(long long)row * 512 + col] = f2bf(v);
        } else if (z == 1) {
          Kf[(long long)row * 512 + col] = v;
          K16[(long long)row * 512 + col] = f2bf(v);
        } else {
          Qf[(long long)row * 512 + col] = v;
        }
      }
    }
  }
}

// ---------------------------------------------------------------------------
// Out-projection (bf16 MFMA) — round-11 verbatim.  Grid (8, 64).
// ---------------------------------------------------------------------------
__global__ __launch_bounds__(256) void gemm_out_mfma(
    const unsigned short* __restrict__ A16,   // ctx16 [4096,512]
    const unsigned short* __restrict__ WoT,   // [512,512] bf16 (n,k)
    const float* __restrict__ bo, float* __restrict__ out) {
  __shared__ unsigned short Asl[64][68];
  __shared__ unsigned short Bsl[64][68];
  int row0 = blockIdx.y * 64;
  int col0 = blockIdx.x * 64;
  int t = (int)threadIdx.x, lane = t & 63, wave = t >> 6;
  int wm = wave >> 1, wn = wave & 1;

  f32x4 acc[2][2];
#pragma unroll
  for (int i = 0; i < 2; i++)
#pragma unroll
    for (int j = 0; j < 2; j++) acc[i][j] = (f32x4){0.f, 0.f, 0.f, 0.f};

  int r = t >> 2, kq = (t & 3) * 8;
  const unsigned short* Ap = A16 + (long long)(row0 + r) * 512 + kq;
  const unsigned short* Bp = WoT + (long long)(col0 + r) * 512 + kq;

  for (int kb = 0; kb < 512; kb += 64) {
    i32x4 a0 = *(const i32x4*)(Ap + kb);
    i32x4 a1 = *(const i32x4*)(Ap + kb + 32);
    i32x4 b0 = *(const i32x4*)(Bp + kb);
    i32x4 b1 = *(const i32x4*)(Bp + kb + 32);
    __syncthreads();
    *(i32x4*)&Asl[r][kq] = a0;
    *(i32x4*)&Asl[r][kq + 32] = a1;
    *(i32x4*)&Bsl[r][kq] = b0;
    *(i32x4*)&Bsl[r][kq + 32] = b1;
    __syncthreads();

    int rr = lane & 15, ko = (lane >> 4) * 8;
#pragma unroll
    for (int k2 = 0; k2 < 2; k2++) {
      i32x4 af0 = *(i32x4*)&Asl[wm * 32 + rr][k2 * 32 + ko];
      i32x4 af1 = *(i32x4*)&Asl[wm * 32 + 16 + rr][k2 * 32 + ko];
      i32x4 bf0 = *(i32x4*)&Bsl[wn * 32 + rr][k2 * 32 + ko];
      i32x4 bf1 = *(i32x4*)&Bsl[wn * 32 + 16 + rr][k2 * 32 + ko];
      acc[0][0] = mfma_bf16(af0, bf0, acc[0][0]);
      acc[0][1] = mfma_bf16(af0, bf1, acc[0][1]);
      acc[1][0] = mfma_bf16(af1, bf0, acc[1][0]);
      acc[1][1] = mfma_bf16(af1, bf1, acc[1][1]);
    }
  }

  int rq = lane >> 4, rr = lane & 15;
#pragma unroll
  for (int fm = 0; fm < 2; fm++) {
#pragma unroll
    for (int fn = 0; fn < 2; fn++) {
      int col = col0 + wn * 32 + fn * 16 + rr;
      float bb = bo[col];
#pragma unroll
      for (int rl = 0; rl < 4; rl++) {
        int row = row0 + wm * 32 + fm * 16 + rq * 4 + rl;
        out[(long long)row * 512 + col] = acc[fm][fn][rl] + bb;
      }
    }
  }
}

// ---------------------------------------------------------------------------
// sv = scl·0.125·R·K^T per head — round-11 verbatim.  Grid (16, 16, 32).
// ---------------------------------------------------------------------------
__global__ __launch_bounds__(256) void gemm_sfinal(
    const unsigned short* __restrict__ R16a,   // [4][1024,512]
    const unsigned short* __restrict__ K16a,   // [4][1024,512]
    const float* __restrict__ scla, unsigned short* __restrict__ sv16a) {
  __shared__ unsigned short Asl[64][68];
  __shared__ unsigned short Bsl[64][68];
  int z = blockIdx.z;
  int b = z >> 3, h = z & 7;
  const unsigned short* A16 = R16a + (long long)b * 524288;
  const unsigned short* Bm = K16a + (long long)b * 524288;
  const float* scl = scla + b * 1024;
  unsigned short* sv = sv16a + (long long)b * 8388608;
  int row0 = blockIdx.y * 64;
  int col0 = blockIdx.x * 64;
  int t = (int)threadIdx.x, lane = t & 63, wave = t >> 6;
  int wm = wave >> 1, wn = wave & 1;

  f32x4 acc[2][2];
#pragma unroll
  for (int i = 0; i < 2; i++)
#pragma unroll
    for (int j = 0; j < 2; j++) acc[i][j] = (f32x4){0.f, 0.f, 0.f, 0.f};

  int r = t >> 2, kq = (t & 3) * 8;
  const unsigned short* Ap = A16 + (long long)(row0 + r) * 512 + h * 64 + kq;
  const unsigned short* Bp = Bm + (long long)(col0 + r) * 512 + h * 64 + kq;

  for (int kb = 0; kb < 64; kb += 64) {
    i32x4 a0 = *(const i32x4*)(Ap + kb);
    i32x4 a1 = *(const i32x4*)(Ap + kb + 32);
    i32x4 b0 = *(const i32x4*)(Bp + kb);
    i32x4 b1 = *(const i32x4*)(Bp + kb + 32);
    __syncthreads();
    *(i32x4*)&Asl[r][kq] = a0;
    *(i32x4*)&Asl[r][kq + 32] = a1;
    *(i32x4*)&Bsl[r][kq] = b0;
    *(i32x4*)&Bsl[r][kq + 32] = b1;
    __syncthreads();

    int rr = lane & 15, ko = (lane >> 4) * 8;
#pragma unroll
    for (int k2 = 0; k2 < 2; k2++) {
      i32x4 af0 = *(i32x4*)&Asl[wm * 32 + rr][k2 * 32 + ko];
      i32x4 af1 = *(i32x4*)&Asl[wm * 32 + 16 + rr][k2 * 32 + ko];
      i32x4 bf0 = *(i32x4*)&Bsl[wn * 32 + rr][k2 * 32 + ko];
      i32x4 bf1 = *(i32x4*)&Bsl[wn * 32 + 16 + rr][k2 * 32 + ko];
      acc[0][0] = mfma_bf16(af0, bf0, acc[0][0]);
      acc[0][1] = mfma_bf16(af0, bf1, acc[0][1]);
      acc[1][0] = mfma_bf16(af1, bf0, acc[1][0]);
      acc[1][1] = mfma_bf16(af1, bf1, acc[1][1]);
    }
  }

  int rq = lane >> 4, rr = lane & 15;
#pragma unroll
  for (int fm = 0; fm < 2; fm++) {
#pragma unroll
    for (int fn = 0; fn < 2; fn++) {
      int col = col0 + wn * 32 + fn * 16 + rr;
#pragma unroll
      for (int rl = 0; rl < 4; rl++) {
        int row = row0 + wm * 32 + fm * 16 + rq * 4 + rl;
        sv[(long long)row * 8192 + h * 1024 + col] =
            f2bf(0.125f * scl[row] * acc[fm][fn][rl]);
      }
    }
  }
}

// ---------------------------------------------------------------------------
// Scores (fp32 compute, bf16 out) — round-11 verbatim.  Grid (8, 8, 32).
// ---------------------------------------------------------------------------
__global__ __launch_bounds__(256) void gemm_scores_bf16(
    const float* __restrict__ Qf, const float* __restrict__ Kf,
    unsigned short* __restrict__ u16a) {
  __shared__ float As[8][132];
  __shared__ float Bs[8][132];
  int z = blockIdx.z;
  int b = z >> 3, h = z & 7;
  const float* A = Qf + (long long)b * 524288 + h * 64;
  const float* B = Kf + (long long)b * 524288 + h * 64;
  unsigned short* C16 = u16a + (long long)b * 8388608 + h * 1024;

  int row0 = blockIdx.y * 128;
  int col0 = blockIdx.x * 128;
  int tid = (int)threadIdx.x;
  int tx = tid & 15, ty = tid >> 4;
  int arow = tid >> 1;
  int akc = (tid & 1) * 4;

  float acc[8][8];
#pragma unroll
  for (int i = 0; i < 8; i++)
#pragma unroll
    for (int j = 0; j < 8; j++) acc[i][j] = 0.f;

  const float* Aptr = A + (long long)(row0 + arow) * 512 + akc;
  const float* Bptr = B + (long long)(col0 + arow) * 512 + akc;

  for (int kb = 0; kb < 64; kb += 8) {
    float4 av = *(const float4*)(Aptr + kb);
    float4 bv = *(const float4*)(Bptr + kb);
    __syncthreads();
    As[akc + 0][arow] = av.x; As[akc + 1][arow] = av.y;
    As[akc + 2][arow] = av.z; As[akc + 3][arow] = av.w;
    Bs[akc + 0][arow] = bv.x; Bs[akc + 1][arow] = bv.y;
    Bs[akc + 2][arow] = bv.z; Bs[akc + 3][arow] = bv.w;
    __syncthreads();

#pragma unroll
    for (int k = 0; k < 8; k++) {
      float a[8], b2[8];
#pragma unroll
      for (int c = 0; c < 2; c++) {
        float4 q = *(float4*)&As[k][ty * 8 + c * 4];
        a[c * 4 + 0] = q.x; a[c * 4 + 1] = q.y;
        a[c * 4 + 2] = q.z; a[c * 4 + 3] = q.w;
      }
#pragma unroll
      for (int c = 0; c < 2; c++) {
        float4 q = *(float4*)&Bs[k][c * 64 + tx * 4];
        b2[c * 4 + 0] = q.x; b2[c * 4 + 1] = q.y;
        b2[c * 4 + 2] = q.z; b2[c * 4 + 3] = q.w;
      }
#pragma unroll
      for (int i = 0; i < 8; i++)
#pragma unroll
        for (int j = 0; j < 8; j++) acc[i][j] = fmaf(a[i], b2[j], acc[i][j]);
    }
  }

#pragma unroll
  for (int i = 0; i < 8; i++) {
    long long r = row0 + ty * 8 + i;
#pragma unroll
    for (int c = 0; c < 2; c++) {
      int col = col0 + c * 64 + tx * 4;
      unsigned int lo = (unsigned int)f2bf(0.125f * acc[i][c * 4 + 0]) |
                        ((unsigned int)f2bf(0.125f * acc[i][c * 4 + 1]) << 16);
      unsigned int hi = (unsigned int)f2bf(0.125f * acc[i][c * 4 + 2]) |
                        ((unsigned int)f2bf(0.125f * acc[i][c * 4 + 3]) << 16);
      uint2 o = {lo, hi};
      *(uint2*)&C16[r * 8192 + col] = o;
    }
  }
}

// ---------------------------------------------------------------------------
// bf16 transpose, z-batched — round-11 verbatim.
// ---------------------------------------------------------------------------
__global__ __launch_bounds__(256) void transpose16_kernel(
    const unsigned short* __restrict__ src, unsigned short* __restrict__ dst,
    int ldS, int ldD, long long zsS, long long zsD) {
  __shared__ unsigned short T[64][72];
  src += (long long)blockIdx.z * zsS;
  dst += (long long)blockIdx.z * zsD;
  int i0 = blockIdx.x * 64;
  int c0 = blockIdx.y * 64;
  int t = (int)threadIdx.x;
  int r = t >> 2, cq = (t & 3) * 16;
  i32x4 v0 = *(const i32x4*)&src[(long long)(i0 + r) * ldS + c0 + cq];
  i32x4 v1 = *(const i32x4*)&src[(long long)(i0 + r) * ldS + c0 + cq + 8];
  *(i32x4*)&T[r][cq] = v0;
  *(i32x4*)&T[r][cq + 8] = v1;
  __syncthreads();
  int c = t >> 2, iq = (t & 3) * 16;
  unsigned short tmp[16];
#pragma unroll
  for (int j = 0; j < 16; j++) tmp[j] = T[iq + j][c];
  *(i32x4*)&dst[(long long)(c0 + c) * ldD + i0 + iq] = *(i32x4*)&tmp[0];
  *(i32x4*)&dst[(long long)(c0 + c) * ldD + i0 + iq + 8] = *(i32x4*)&tmp[8];
}

// f32 -> bf16 transpose — round-11 verbatim.  Grid (16, 8, 4).
__global__ __launch_bounds__(256) void transpose_f32_bf16_kernel(
    const float* __restrict__ src, unsigned short* __restrict__ dst,
    int ldS, int ldD, long long zsS, long long zsD) {
  __shared__ unsigned short T[64][72];
  src += (long long)blockIdx.z * zsS;
  dst += (long long)blockIdx.z * zsD;
  int i0 = blockIdx.x * 64;
  int c0 = blockIdx.y * 64;
  int t = (int)threadIdx.x;
  int r = t >> 2, cq = (t & 3) * 16;
#pragma unroll
  for (int j = 0; j < 4; j++) {
    float4 v = *(const float4*)&src[(long long)(i0 + r) * ldS + c0 + cq + j * 4];
    T[r][cq + j * 4 + 0] = f2bf(v.x);
    T[r][cq + j * 4 + 1] = f2bf(v.y);
    T[r][cq + j * 4 + 2] = f2bf(v.z);
    T[r][cq + j * 4 + 3] = f2bf(v.w);
  }
  __syncthreads();
  int c = t >> 2, iq = (t & 3) * 16;
  unsigned short tmp[16];
#pragma unroll
  for (int j = 0; j < 16; j++) tmp[j] = T[iq + j][c];
  *(i32x4*)&dst[(long long)(c0 + c) * ldD + i0 + iq] = *(i32x4*)&tmp[0];
  *(i32x4*)&dst[(long long)(c0 + c) * ldD + i0 + iq + 8] = *(i32x4*)&tmp[8];
}

// ---------------------------------------------------------------------------
// G = u·u^T lower triangle (bf16 MFMA, 128x128, BK=32, padded LDS [128][40],
// split-K=8) — round-13 version (audited).  Grid (8, 8, 32): z = b*8+ks.
// ---------------------------------------------------------------------------
__global__ __launch_bounds__(256) void gemm_G128_bf16(
    const unsigned short* __restrict__ U16a, float* __restrict__ P) {
  __shared__ unsigned short Alds[128][40];
  __shared__ unsigned short Blds[128][40];
  int row0 = blockIdx.y * 128;
  int col0 = blockIdx.x * 128;
  if (col0 > row0) return;
  int z = blockIdx.z;
  int b = z >> 3, ks = z & 7;
  const unsigned short* U = U16a + (long long)b * 8388608;
  int t = (int)threadIdx.x, lane = t & 63, wave = t >> 6;
  int wm = wave >> 1, wn = wave & 1;

  f32x4 acc[4][4];
#pragma unroll
  for (int i = 0; i < 4; i++)
#pragma unroll
    for (int j = 0; j < 4; j++) acc[i][j] = (f32x4){0.f, 0.f, 0.f, 0.f};

  int ar = t >> 2;
  int aq = (t & 3) * 8;
  const unsigned short* Ap = U + (long long)(row0 + ar) * 8192 + ks * 1024 + aq;
  const unsigned short* Ap2 = Ap + 64LL * 8192;
  const unsigned short* Bp = U + (long long)(col0 + ar) * 8192 + ks * 1024 + aq;
  const unsigned short* Bp2 = Bp + 64LL * 8192;

  for (int kb = 0; kb < 1024; kb += 32) {
    i32x4 a0 = *(const i32x4*)(Ap + kb);
    i32x4 a1 = *(const i32x4*)(Ap2 + kb);
    i32x4 b0 = *(const i32x4*)(Bp + kb);
    i32x4 b1 = *(const i32x4*)(Bp2 + kb);
    __syncthreads();
    *(i32x4*)&Alds[ar][aq] = a0;
    *(i32x4*)&Alds[ar + 64][aq] = a1;
    *(i32x4*)&Blds[ar][aq] = b0;
    *(i32x4*)&Blds[ar + 64][aq] = b1;
    __syncthreads();

    int rr = lane & 15, ko = (lane >> 4) * 8;
    i32x4 af[4], bfv[4];
#pragma unroll
    for (int fm = 0; fm < 4; fm++)
      af[fm] = *(i32x4*)&Alds[wm * 64 + fm * 16 + rr][ko];
#pragma unroll
    for (int fn = 0; fn < 4; fn++)
      bfv[fn] = *(i32x4*)&Blds[wn * 64 + fn * 16 + rr][ko];
#pragma unroll
    for (int fm = 0; fm < 4; fm++)
#pragma unroll
      for (int fn = 0; fn < 4; fn++)
        acc[fm][fn] = mfma_bf16(af[fm], bfv[fn], acc[fm][fn]);
  }

  float* dst = P + (long long)z * 1048576;
  int rq = lane >> 4, rr = lane & 15;
#pragma unroll
  for (int fm = 0; fm < 4; fm++) {
#pragma unroll
    for (int fn = 0; fn < 4; fn++) {
      int col = col0 + wn * 64 + fn * 16 + rr;
#pragma unroll
      for (int r = 0; r < 4; r++) {
        int row = row0 + wm * 64 + fm * 16 + rq * 4 + r;
        dst[(long long)row * 1024 + col] = acc[fm][fn][r];
      }
    }
  }
}

// G16 = bf16(sum_{ks=0..7} P[b*8+ks]), mirrored.  Grid (1024, 4).
__global__ __launch_bounds__(256) void merge_mirror_G_kernel(
    const float* __restrict__ P, unsigned short* __restrict__ G16a) {
  int i = blockIdx.x;
  int b = blockIdx.y;
  int t = (int)threadIdx.x, j0 = t * 4;
  if (j0 > i) return;
  const float* Pb = P + (long long)(b * 8) * 1048576 + (long long)i * 1024;
  unsigned short* Gb = G16a + (long long)b * 1048576;
  float4 s = {0.f, 0.f, 0.f, 0.f};
#pragma unroll
  for (int z = 0; z < 8; z++) {
    float4 p = *(const float4*)&Pb[(long long)z * 1048576 + j0];
    s.x += p.x; s.y += p.y; s.z += p.z; s.w += p.w;
  }
  float v[4] = {s.x, s.y, s.z, s.w};
#pragma unroll
  for (int e = 0; e < 4; e++) {
    int j = j0 + e;
    if (j > i) break;
    unsigned short g = f2bf(v[e]);
    Gb[(long long)i * 1024 + j] = g;
    if (j < i) Gb[(long long)j * 1024 + i] = g;
  }
}

// ---------------------------------------------------------------------------
// M = C·G (bf16 MFMA, z-batched) — round-11 verbatim.
// ---------------------------------------------------------------------------
__global__ __launch_bounds__(256) void gemm_M_bf16(
    const unsigned short* __restrict__ Ca, const unsigned short* __restrict__ Ga,
    float* __restrict__ Ma) {
  int row0 = blockIdx.y * 64;
  int col0 = blockIdx.x * 64;
  if (col0 > row0) return;
  int b = blockIdx.z;
  const unsigned short* C = Ca + (long long)b * 1048576;
  const unsigned short* G = Ga + (long long)b * 1048576;
  float* M = Ma + (long long)b * 1048576;
  int Kend = row0 + 64;
  __shared__ unsigned short Asl[64][64];
  __shared__ unsigned short Bsl[64][64];
  int t = (int)threadIdx.x, lane = t & 63, wave = t >> 6;
  int wm = wave >> 1, wn = wave & 1;

  f32x4 acc[2][2];
#pragma unroll
  for (int i = 0; i < 2; i++)
#pragma unroll
    for (int j = 0; j < 2; j++) acc[i][j] = (f32x4){0.f, 0.f, 0.f, 0.f};

  int r = t >> 2, c0 = t & 3;
  int sw0 = ((c0 ^ (r & 7))) * 8;
  int sw1 = (((c0 + 4) ^ (r & 7))) * 8;
  const unsigned short* Ap = C + (long long)(row0 + r) * 1024 + c0 * 8;
  const unsigned short* Bp = G + (long long)(col0 + r) * 1024 + c0 * 8;

  for (int kb = 0; kb < Kend; kb += 64) {
    i32x4 a0 = *(const i32x4*)(Ap + kb);
    i32x4 a1 = *(const i32x4*)(Ap + kb + 32);
    i32x4 b0 = *(const i32x4*)(Bp + kb);
    i32x4 b1 = *(const i32x4*)(Bp + kb + 32);
    __syncthreads();
    *(i32x4*)&Asl[r][sw0] = a0;
    *(i32x4*)&Asl[r][sw1] = a1;
    *(i32x4*)&Bsl[r][sw0] = b0;
    *(i32x4*)&Bsl[r][sw1] = b1;
    __syncthreads();

    int rr = lane & 15, co = lane >> 4;
#pragma unroll
    for (int k2 = 0; k2 < 2; k2++) {
      int ch = ((k2 * 4 + co) ^ (rr & 7)) * 8;
      i32x4 af0 = *(i32x4*)&Asl[wm * 32 + rr][ch];
      i32x4 af1 = *(i32x4*)&Asl[wm * 32 + 16 + rr][ch];
      i32x4 bf0 = *(i32x4*)&Bsl[wn * 32 + rr][ch];
      i32x4 bf1 = *(i32x4*)&Bsl[wn * 32 + 16 + rr][ch];
      acc[0][0] = mfma_bf16(af0, bf0, acc[0][0]);
      acc[0][1] = mfma_bf16(af0, bf1, acc[0][1]);
      acc[1][0] = mfma_bf16(af1, bf0, acc[1][0]);
      acc[1][1] = mfma_bf16(af1, bf1, acc[1][1]);
    }
  }

  int rq = lane >> 4, rr = lane & 15;
#pragma unroll
  for (int fm = 0; fm < 2; fm++) {
#pragma unroll
    for (int fn = 0; fn < 2; fn++) {
      int j = col0 + wn * 32 + fn * 16 + rr;
#pragma unroll
      for (int rl = 0; rl < 4; rl++) {
        int i = row0 + wm * 32 + fm * 16 + rq * 4 + rl;
        M[(long long)i * 1024 + j] = acc[fm][fn][rl];
      }
    }
  }
}

// ---------------------------------------------------------------------------
// Fused scldot + b-update + causal softmax (it0/it1) — round-11 verbatim.
// ---------------------------------------------------------------------------
template <int INIT>
__global__ __launch_bounds__(256) void fused_scl_bupd_kernel(
    float* __restrict__ bHa, const float* __restrict__ Ma,
    unsigned short* __restrict__ cH16a) {
  __shared__ float red[4];
  int i = blockIdx.x;
  int b = blockIdx.y;
  float* bH = bHa + (long long)b * 1048576;
  const float* M = Ma + (long long)b * 1048576;
  unsigned short* cH16 = cH16a + (long long)b * 1048576;
  long long base = (long long)i * 1024;
  int t = (int)threadIdx.x, k0 = t * 4;
  float4 m = *(const float4*)&M[base + k0];
  uint2 pc = *(const uint2*)&cH16[base + k0];
  float c0 = bf2f(pc.x & 0xffffu), c1 = bf2f(pc.x >> 16);
  float c2 = bf2f(pc.y & 0xffffu), c3 = bf2f(pc.y >> 16);
  bool m0 = (k0 + 0) <= i, m1 = (k0 + 1) <= i, m2 = (k0 + 2) <= i,
       m3 = (k0 + 3) <= i;
  float acc = 0.f;
  if (m0) acc += c0 * m.x;
  if (m1) acc += c1 * m.y;
  if (m2) acc += c2 * m.z;
  if (m3) acc += c3 * m.w;
  float ssq = blockSum(acc, red);
  float sc = (ssq / (1.f + ssq)) / sqrtf(ssq + SQ_EPS);

  float4 x;
  if (INIT) x = (float4){0.f, 0.f, 0.f, 0.f};
  else x = *(const float4*)&bH[base + k0];
  if (m0) x.x += sc * m.x;
  if (m1) x.y += sc * m.y;
  if (m2) x.z += sc * m.z;
  if (m3) x.w += sc * m.w;
  *(float4*)&bH[base + k0] = x;
  float mx = -3.0e38f;
  if (m0) mx = fmaxf(mx, x.x);
  if (m1) mx = fmaxf(mx, x.y);
  if (m2) mx = fmaxf(mx, x.z);
  if (m3) mx = fmaxf(mx, x.w);
  mx = blockMax(mx, red);
  float e0 = m0 ? expf(x.x - mx) : 0.f;
  float e1 = m1 ? expf(x.y - mx) : 0.f;
  float e2 = m2 ? expf(x.z - mx) : 0.f;
  float e3 = m3 ? expf(x.w - mx) : 0.f;
  float zz = blockSum(e0 + e1 + e2 + e3, red);
  float inv = 1.f / zz;
  uint2 o = {(unsigned int)f2bf(e0 * inv) | ((unsigned int)f2bf(e1 * inv) << 16),
             (unsigned int)f2bf(e2 * inv) | ((unsigned int)f2bf(e3 * inv) << 16)};
  *(uint2*)&cH16[base + k0] = o;
}

// ||s_i||^2 -> scl (it2) — round-11 verbatim.  Grid (1024, 4).
__global__ __launch_bounds__(256) void scldot_kernel(
    const float* __restrict__ Ma, const unsigned short* __restrict__ Ca,
    float* __restrict__ scl) {
  __shared__ float red[4];
  int i = blockIdx.x;
  int b = blockIdx.y;
  const float* M = Ma + (long long)b * 1048576;
  const unsigned short* C = Ca + (long long)b * 1048576;
  int t = (int)threadIdx.x, j0 = t * 4;
  long long base = (long long)i * 1024;
  float4 m = *(const float4*)&M[base + j0];
  uint2 pc = *(const uint2*)&C[base + j0];
  float c0 = bf2f(pc.x & 0xffffu), c1 = bf2f(pc.x >> 16);
  float c2 = bf2f(pc.y & 0xffffu), c3 = bf2f(pc.y >> 16);
  float acc = 0.f;
  if (j0 + 0 <= i) acc += c0 * m.x;
  if (j0 + 1 <= i) acc += c1 * m.y;
  if (j0 + 2 <= i) acc += c2 * m.z;
  if (j0 + 3 <= i) acc += c3 * m.w;
  float ssq = blockSum(acc, red);
  if (t == 0) scl[b * 1024 + i] = (ssq / (1.f + ssq)) / sqrtf(ssq + SQ_EPS);
}

// it=0 coupling — round-11 verbatim.  Grid (1024, 4).
__global__ __launch_bounds__(256) void softmax_uniform_kernel(
    unsigned short* __restrict__ cH16a) {
  int i = blockIdx.x;
  int b = blockIdx.y;
  unsigned short* cH16 = cH16a + (long long)b * 1048576;
  int t = (int)threadIdx.x, k0 = t * 4;
  unsigned short c = f2bf(1.f / (float)(i + 1));
  unsigned short e0 = (k0 + 0) <= i ? c : (unsigned short)0;
  unsigned short e1 = (k0 + 1) <= i ? c : (unsigned short)0;
  unsigned short e2 = (k0 + 2) <= i ? c : (unsigned short)0;
  unsigned short e3 = (k0 + 3) <= i ? c : (unsigned short)0;
  uint2 o = {(unsigned int)e0 | ((unsigned int)e1 << 16),
             (unsigned int)e2 | ((unsigned int)e3 << 16)};
  *(uint2*)&cH16[(long long)i * 1024 + k0] = o;
}

// ---------------------------------------------------------------------------
// R = C·Q (causal) — round-11 verbatim.  Grid (4, 8, 4).
// ---------------------------------------------------------------------------
__global__ __launch_bounds__(256) void gemm_R_bf16(
    const unsigned short* __restrict__ Ca, const unsigned short* __restrict__ QTa,
    unsigned short* __restrict__ R16a) {
  __shared__ unsigned short Alds[128][32];
  __shared__ unsigned short Blds[128][32];
  int b = blockIdx.z;
  const unsigned short* Abf = Ca + (long long)b * 1048576;
  const unsigned short* BT = QTa + (long long)b * 524288;
  unsigned short* Cout = R16a + (long long)b * 524288;
  int rowblk = 7 - (int)blockIdx.y;
  int row0 = rowblk * 128;
  int col0 = blockIdx.x * 128;
  int t = (int)threadIdx.x, lane = t & 63, wave = t >> 6;
  int wm = wave >> 1, wn = wave & 1;
  int Kend = row0 + 128;

  f32x4 acc[4][4];
#pragma unroll
  for (int i = 0; i < 4; i++)
#pragma unroll
    for (int j = 0; j < 4; j++) acc[i][j] = (f32x4){0.f, 0.f, 0.f, 0.f};

  int ar = t >> 2;
  int aq = (t & 3) * 8;

  for (int kb = 0; kb < Kend; kb += 32) {
    i32x4 a0 = *(const i32x4*)&Abf[(long long)(row0 + ar) * 1024 + kb + aq];
    i32x4 a1 = *(const i32x4*)&Abf[(long long)(row0 + ar + 64) * 1024 + kb + aq];
    i32x4 b0 = *(const i32x4*)&BT[(long long)(col0 + ar) * 1024 + kb + aq];
    i32x4 b1 = *(const i32x4*)&BT[(long long)(col0 + ar + 64) * 1024 + kb + aq];
    __syncthreads();
    *(i32x4*)&Alds[ar][aq] = a0;
    *(i32x4*)&Alds[ar + 64][aq] = a1;
    *(i32x4*)&Blds[ar][aq] = b0;
    *(i32x4*)&Blds[ar + 64][aq] = b1;
    __syncthreads();

    int rr = lane & 15, koff = (lane >> 4) * 8;
    i32x4 af[4], bfv[4];
#pragma unroll
    for (int fm = 0; fm < 4; fm++)
      af[fm] = *(i32x4*)&Alds[wm * 64 + fm * 16 + rr][koff];
#pragma unroll
    for (int fn = 0; fn < 4; fn++)
      bfv[fn] = *(i32x4*)&Blds[wn * 64 + fn * 16 + rr][koff];
#pragma unroll
    for (int fm = 0; fm < 4; fm++)
#pragma unroll
      for (int fn = 0; fn < 4; fn++)
        acc[fm][fn] = mfma_bf16(af[fm], bfv[fn], acc[fm][fn]);
  }

  int rq = lane >> 4, rr = lane & 15;
#pragma unroll
  for (int fm = 0; fm < 4; fm++) {
#pragma unroll
    for (int fn = 0; fn < 4; fn++) {
      int col = col0 + wn * 64 + fn * 16 + rr;
#pragma unroll
      for (int r = 0; r < 4; r++) {
        int row = row0 + wm * 64 + fm * 16 + rq * 4 + r;
        Cout[(long long)row * 512 + col] = f2bf(acc[fm][fn][r]);
      }
    }
  }
}

// ---------------------------------------------------------------------------
// ctx (bf16 MFMA, bf16 out) — round-11 verbatim.  Grid (64, 8).
// ---------------------------------------------------------------------------
__global__ __launch_bounds__(256) void gemm_ctx_bf16(
    const unsigned short* __restrict__ w16,
    const unsigned short* __restrict__ VTa, unsigned short* __restrict__ ctx16) {
  int row0 = blockIdx.x * 64;
  int b = blockIdx.x >> 4;
  int h = blockIdx.y;
  const unsigned short* VT = VTa + (long long)b * 524288;
  __shared__ unsigned short Asl[64][68];
  __shared__ unsigned short Bsl[64][68];
  int t = (int)threadIdx.x, lane = t & 63, wave = t >> 6;

  f32x4 acc[4];
#pragma unroll
  for (int i = 0; i < 4; i++) acc[i] = (f32x4){0.f, 0.f, 0.f, 0.f};

  int r = t >> 2, kq = (t & 3) * 8;
  const unsigned short* Ap = w16 + (long long)(row0 + r) * 8192 + h * 1024 + kq;
  const unsigned short* Bp = VT + (long long)(h * 64 + r) * 1024 + kq;

  for (int kb = 0; kb < 1024; kb += 64) {
    i32x4 a0 = *(const i32x4*)(Ap + kb);
    i32x4 a1 = *(const i32x4*)(Ap + kb + 32);
    i32x4 b0 = *(const i32x4*)(Bp + kb);
    i32x4 b1 = *(const i32x4*)(Bp + kb + 32);
    __syncthreads();
    *(i32x4*)&Asl[r][kq] = a0;
    *(i32x4*)&Asl[r][kq + 32] = a1;
    *(i32x4*)&Bsl[r][kq] = b0;
    *(i32x4*)&Bsl[r][kq + 32] = b1;
    __syncthreads();

    int rr = lane & 15, ko = (lane >> 4) * 8;
#pragma unroll
    for (int k2 = 0; k2 < 2; k2++) {
      i32x4 af = *(i32x4*)&Asl[wave * 16 + rr][k2 * 32 + ko];
#pragma unroll
      for (int fn = 0; fn < 4; fn++) {
        i32x4 bf = *(i32x4*)&Bsl[fn * 16 + rr][k2 * 32 + ko];
        acc[fn] = mfma_bf16(af, bf, acc[fn]);
      }
    }
  }

  int rq = lane >> 4, rr = lane & 15;
#pragma unroll
  for (int fn = 0; fn < 4; fn++) {
#pragma unroll
    for (int rl = 0; rl < 4; rl++) {
      int i = row0 + wave * 16 + rq * 4 + rl;
      ctx16[(long long)i * 512 + h * 64 + fn * 16 + rr] = f2bf(acc[fn][rl]);
    }
  }
}

// ---------------------------------------------------------------------------
// Vertical routing — round-11 verbatim.  Grid 4096.
// ---------------------------------------------------------------------------
__global__ __launch_bounds__(256) void vertical_routing_kernel(
    const unsigned short* __restrict__ u16, float* __restrict__ vV) {
  __shared__ float Ur[8 * 1024];
  __shared__ float red[4];
  __shared__ float red8[32];
  int bq = blockIdx.x;
  int t = (int)threadIdx.x;
  const unsigned short* Ub = u16 + (long long)bq * 8192;
#pragma unroll
  for (int r = 0; r < 8; r++) {
    uint2 p = *(const uint2*)&Ub[(t + 256 * r) * 4];
    Ur[(t + 256 * r) * 4 + 0] = bf2f(p.x & 0xffffu);
    Ur[(t + 256 * r) * 4 + 1] = bf2f(p.x >> 16);
    Ur[(t + 256 * r) * 4 + 2] = bf2f(p.y & 0xffffu);
    Ur[(t + 256 * r) * 4 + 3] = bf2f(p.y >> 16);
  }
  __syncthreads();

  float bh[8] = {0.f, 0.f, 0.f, 0.f, 0.f, 0.f, 0.f, 0.f};
  int k0 = t * 4;
  float4 v4 = {0.f, 0.f, 0.f, 0.f};
  for (int it = 0; it < 3; ++it) {
    float m = bh[0];
#pragma unroll
    for (int h = 1; h < 8; h++) m = fmaxf(m, bh[h]);
    float c[8], zz = 0.f;
#pragma unroll
    for (int h = 0; h < 8; h++) {
      c[h] = expf(bh[h] - m);
      zz += c[h];
    }
    float inv = 1.f / zz;
    float4 s4 = {0.f, 0.f, 0.f, 0.f};
#pragma unroll
    for (int h = 0; h < 8; h++) {
      float4 u = *(float4*)&Ur[h * 1024 + k0];
      float ch = c[h] * inv;
      s4.x = fmaf(ch, u.x, s4.x); s4.y = fmaf(ch, u.y, s4.y);
      s4.z = fmaf(ch, u.z, s4.z); s4.w = fmaf(ch, u.w, s4.w);
    }
    float sq =
        blockSum(s4.x * s4.x + s4.y * s4.y + s4.z * s4.z + s4.w * s4.w, red);
    float sc = (sq / (1.f + sq)) / sqrtf(sq + SQ_EPS);
    v4.x = sc * s4.x; v4.y = sc * s4.y; v4.z = sc * s4.z; v4.w = sc * s4.w;
    if (it < 2) {
      float p[8];
#pragma unroll
      for (int h = 0; h < 8; h++) {
        float4 u = *(float4*)&Ur[h * 1024 + k0];
        p[h] = u.x * v4.x + u.y * v4.y + u.z * v4.z + u.w * v4.w;
      }
      __syncthreads();
#pragma unroll
      for (int h = 0; h < 8; h++) {
        float w = wredSum(p[h]);
        if ((t & 63) == 0) red8[(t >> 6) * 8 + h] = w;
      }
      __syncthreads();
#pragma unroll
      for (int h = 0; h < 8; h++)
        bh[h] += red8[h] + red8[8 + h] + red8[16 + h] + red8[24 + h];
    }
  }
  *(float4*)&vV[(long long)bq * 1024 + k0] = v4;
}

// enhanced softmax — round-11 verbatim.  Grid 32768.
__global__ __launch_bounds__(256) void enh_softmax_kernel(
    unsigned short* __restrict__ u16, const float* __restrict__ vV,
    const unsigned short* __restrict__ v16) {
  __shared__ float red[4];
  int idx = blockIdx.x;  // B*Q*H
  int h = idx & 7;
  int bq = idx >> 3;
  unsigned short* Urow = u16 + (long long)bq * 8192 + h * 1024;
  const float* va = vV + (long long)bq * 1024;
  const unsigned short* vb = v16 + (long long)bq * 8192 + h * 1024;
  int t = (int)threadIdx.x, k0 = t * 4;
  uint2 pu = *(const uint2*)&Urow[k0];
  float4 a = *(const float4*)&va[k0];
  uint2 pb = *(const uint2*)&vb[k0];
  float x0 = bf2f(pu.x & 0xffffu) + a.x + bf2f(pb.x & 0xffffu);
  float x1 = bf2f(pu.x >> 16) + a.y + bf2f(pb.x >> 16);
  float x2 = bf2f(pu.y & 0xffffu) + a.z + bf2f(pb.y & 0xffffu);
  float x3 = bf2f(pu.y >> 16) + a.w + bf2f(pb.y >> 16);
  float mx = blockMax(fmaxf(fmaxf(x0, x1), fmaxf(x2, x3)), red);
  float e0 = expf(x0 - mx), e1 = expf(x1 - mx), e2 = expf(x2 - mx),
        e3 = expf(x3 - mx);
  float zz = blockSum(e0 + e1 + e2 + e3, red);
  float inv = 1.f / zz;
  uint2 o = {(unsigned int)f2bf(e0 * inv) | ((unsigned int)f2bf(e1 * inv) << 16),
             (unsigned int)f2bf(e2 * inv) | ((unsigned int)f2bf(e3 * inv) << 16)};
  *(uint2*)&Urow[k0] = o;
}

// ---------------------------------------------------------------------------
extern "C" void kernel_launch(void* const* d_in, const int* in_sizes, int n_in,
                              void* d_out, int out_size, void* d_ws,
                              size_t ws_size, hipStream_t stream) {
  (void)in_sizes; (void)n_in; (void)out_size; (void)ws_size;
  const float* x = (const float*)d_in[0];
  const float* Wq = (const float*)d_in[1];
  const float* bq = (const float*)d_in[2];
  const float* Wk = (const float*)d_in[3];
  const float* bk = (const float*)d_in[4];
  const float* Wv = (const float*)d_in[5];
  const float* bv = (const float*)d_in[6];
  const float* Wo = (const float*)d_in[7];
  const float* bo = (const float*)d_in[8];
  float* out = (float*)d_out;
  float* ws = (float*)d_ws;

  unsigned short* u16a = (unsigned short*)(ws);              // 16M fl
  unsigned short* QT16 = (unsigned short*)(ws + 16777216);   // 1M fl
  unsigned short* K16 = (unsigned short*)(ws + 17825792);    // 1M fl
  // Win @ 18874368 .. 52428800 (32M fl), time-multiplexed:
  float* Qf = ws + 18874368;                                 // 2M
  float* Kf = ws + 20971520;                                 // 2M
  unsigned short* V16a = (unsigned short*)(ws + 23068672);   // 1M fl
  float* Pa = ws + 18874368;                                 // 32 x 1M fl
  unsigned short* sv16a = (unsigned short*)(ws + 18874368);  // 16M fl
  float* Mbufa = ws + 35651584;                              // 4M fl
  unsigned short* R16 = (unsigned short*)(ws + 35651584);    // 1M fl (after M)
  float* vVa = ws + 52428800;                                // 4M
  float* bHa = ws + 56623104;                                // 4M
  unsigned short* ctx16 = (unsigned short*)(ws + 56623104);  // overlays bHa
  unsigned short* cH16a = (unsigned short*)(ws + 60817408);  // 2M fl
  unsigned short* G16a = (unsigned short*)(ws + 62914560);   // 2M fl
  unsigned short* VT16a = (unsigned short*)(ws + 65011712);  // 1M fl
  unsigned short* WT16 = (unsigned short*)(ws + 66060288);   // 0.5M fl
  float* scl = ws + 66584576;                                // 4096
  // total 66,588,672 fl = 254.0 MiB

  // 1-4. prologue
  wtrans_kernel<<<dim3(8, 8, 4), 256, 0, stream>>>(Wq, Wk, Wv, Wo, WT16);
  gemm_qkv_mfma<<<dim3(8, 64, 3), 256, 0, stream>>>(x, WT16, bq, bk, bv, Qf,
                                                    Kf, K16, V16a);
  transpose16_kernel<<<dim3(16, 8, 4), 256, 0, stream>>>(V16a, VT16a, 512,
                                                         1024, 524288, 524288);
  transpose_f32_bf16_kernel<<<dim3(16, 8, 4), 256, 0, stream>>>(
      Qf, QT16, 512, 1024, 524288, 524288);

  // 5. scores (fp32) -> u16a, all batches
  gemm_scores_bf16<<<dim3(8, 8, 32), 256, 0, stream>>>(Qf, Kf, u16a);

  // 6. vertical routing, all batches
  vertical_routing_kernel<<<dim3(4096), 256, 0, stream>>>(u16a, vVa);

  // 7. G = u·u^T (lower triangle, 128^2 tile, BK=32, split-K=8); merge+mirror
  gemm_G128_bf16<<<dim3(8, 8, 32), 256, 0, stream>>>(u16a, Pa);
  merge_mirror_G_kernel<<<dim3(1024, 4), 256, 0, stream>>>(Pa, G16a);

  // 8. horizontal routing iterations (all batches per stage)
  softmax_uniform_kernel<<<dim3(1024, 4), 256, 0, stream>>>(cH16a);
  gemm_M_bf16<<<dim3(16, 16, 4), 256, 0, stream>>>(cH16a, G16a, Mbufa);
  fused_scl_bupd_kernel<1><<<dim3(1024, 4), 256, 0, stream>>>(bHa, Mbufa,
                                                              cH16a);
  gemm_M_bf16<<<dim3(16, 16, 4), 256, 0, stream>>>(cH16a, G16a, Mbufa);
  fused_scl_bupd_kernel<0><<<dim3(1024, 4), 256, 0, stream>>>(bHa, Mbufa,
                                                              cH16a);
  gemm_M_bf16<<<dim3(16, 16, 4), 256, 0, stream>>>(cH16a, G16a, Mbufa);
  scldot_kernel<<<dim3(1024, 4), 256, 0, stream>>>(Mbufa, cH16a, scl);

  // 9. factored final s: R = C·Q (causal), sv = scl·0.125·R·K^T
  gemm_R_bf16<<<dim3(4, 8, 4), 256, 0, stream>>>(cH16a, QT16, R16);
  gemm_sfinal<<<dim3(16, 16, 32), 256, 0, stream>>>(R16, K16, scl, sv16a);

  // 10. enhanced + softmax -> w into u16a
  enh_softmax_kernel<<<dim3(32768), 256, 0, stream>>>(u16a, vVa, sv16a);

  // 11. ctx = w x V (bf16 out, writes over dead bHa)
  gemm_ctx_bf16<<<dim3(64, 8), 256, 0, stream>>>(u16a, VT16a, ctx16);

  // 12. out = ctx16 x Wo + bo (bf16 MFMA, Wo^T at WT16 + 3*262144)
  gemm_out_mfma<<<dim3(8, 64), 256, 0, stream>>>(ctx16, WT16 + 786432, bo,
                                                 out);
}

// Round 15
// 384.729 us; speedup vs baseline: 1.2519x; 1.2519x over previous
//
#include <hip/hip_runtime.h>
#include <math.h>

// ---------------------------------------------------------------------------
// CapsuleRoutingSelfAttention — round 15: factored Gram matrix.
// G = u·u^T = (1/64)·Σ_h Q_h (K_h^T K_h) Q_h^T:
//   T_h = (1/64)·K_h^T·K_h (64x64; gemm_M mold), Y = Q·T (sfinal mold),
//   G = Y·Q^T (round-11 G128 mold, K=512, direct bf16 store) + tile-mirror.
// Scores remain fp32 (round-14 bisect: bf16 scores is an 18x absmax cliff).
// qkv now dual-writes Q16 bf16 (like K16) for the Y/YQ path.
//
// Workspace (float units), ~220 MiB (ws = 256 MiB):
//   u16a @0 (16M) | QT16 @16,777,216 (1M) | K16 @17,825,792 (1M)
//   KT16 @18,874,368 (1M) | T16 @19,922,944 (64K) | Y16 @20,971,520 (1M)
//   Q16 @22,020,096 (1M)
//   Win @23,068,672..39,845,888 (16M), time-multiplexed:
//     Qf (2M) @23,068,672 | Kf @25,165,824 (2M) | V16a @27,262,976 (1M)
//     sv16a bf16 (16M) @23,068,672 [sfinal -> enh]
//   Mbufa @39,845,888 (4M); R16 overlays @39,845,888 (1M, after M dead)
//   vVa @44,040,192 (4M) | bHa @48,234,496 (4M; ctx16 overlays)
//   cH16a @52,428,800 (2M) | G16a @54,525,952 (2M)
//   VT16a @56,623,104 (1M) | WT16 @57,671,680 (0.5M) | scl @58,195,968
// ---------------------------------------------------------------------------

#define SQ_EPS 1e-8f

typedef __attribute__((ext_vector_type(4))) int i32x4;    // 8 bf16
typedef __attribute__((ext_vector_type(4))) float f32x4;

__device__ __forceinline__ float bf2f(unsigned int u) {
  union { unsigned int i; float f; } x;
  x.i = u << 16;
  return x.f;
}
__device__ __forceinline__ unsigned short f2bf(float f) {
  union { float f; unsigned int i; } x;
  x.f = f;
  unsigned int r = x.i + 0x7fffu + ((x.i >> 16) & 1u);
  return (unsigned short)(r >> 16);
}
__device__ __forceinline__ int packbf(float a, float b) {
  return (int)((unsigned int)f2bf(a) | ((unsigned int)f2bf(b) << 16));
}

__device__ __forceinline__ f32x4 mfma_bf16(i32x4 a, i32x4 b, f32x4 c) {
  asm("v_mfma_f32_16x16x32_bf16 %0, %1, %2, %0" : "+v"(c) : "v"(a), "v"(b));
  return c;
}

__device__ __forceinline__ float wredSum(float v) {
#pragma unroll
  for (int off = 32; off > 0; off >>= 1) v += __shfl_xor(v, off);
  return v;
}
__device__ __forceinline__ float wredMax(float v) {
#pragma unroll
  for (int off = 32; off > 0; off >>= 1) v = fmaxf(v, __shfl_xor(v, off));
  return v;
}
__device__ __forceinline__ float blockSum(float v, volatile float* red) {
  v = wredSum(v);
  int wid = threadIdx.x >> 6;
  __syncthreads();
  if ((threadIdx.x & 63) == 0) red[wid] = v;
  __syncthreads();
  return red[0] + red[1] + red[2] + red[3];
}
__device__ __forceinline__ float blockMax(float v, volatile float* red) {
  v = wredMax(v);
  int wid = threadIdx.x >> 6;
  __syncthreads();
  if ((threadIdx.x & 63) == 0) red[wid] = v;
  __syncthreads();
  return fmaxf(fmaxf(red[0], red[1]), fmaxf(red[2], red[3]));
}

// ---------------------------------------------------------------------------
// W^T prep (Wq,Wk,Wv,Wo).  Grid (8, 8, 4).
// ---------------------------------------------------------------------------
__global__ __launch_bounds__(256) void wtrans_kernel(
    const float* __restrict__ Wq, const float* __restrict__ Wk,
    const float* __restrict__ Wv, const float* __restrict__ Wo,
    unsigned short* __restrict__ WT16) {
  __shared__ unsigned short T[64][72];
  int z = blockIdx.z;
  const float* src = (z == 0) ? Wq : (z == 1) ? Wk : (z == 2) ? Wv : Wo;
  unsigned short* dst = WT16 + (long long)z * 262144;
  int i0 = blockIdx.x * 64;
  int c0 = blockIdx.y * 64;
  int t = (int)threadIdx.x;
  int r = t >> 2, cq = (t & 3) * 16;
#pragma unroll
  for (int j = 0; j < 4; j++) {
    float4 v = *(const float4*)&src[(long long)(i0 + r) * 512 + c0 + cq + j * 4];
    T[r][cq + j * 4 + 0] = f2bf(v.x);
    T[r][cq + j * 4 + 1] = f2bf(v.y);
    T[r][cq + j * 4 + 2] = f2bf(v.z);
    T[r][cq + j * 4 + 3] = f2bf(v.w);
  }
  __syncthreads();
  int c = t >> 2, iq = (t & 3) * 16;
  unsigned short tmp[16];
#pragma unroll
  for (int j = 0; j < 16; j++) tmp[j] = T[iq + j][c];
  *(i32x4*)&dst[(long long)(c0 + c) * 512 + i0 + iq] = *(i32x4*)&tmp[0];
  *(i32x4*)&dst[(long long)(c0 + c) * 512 + i0 + iq + 8] = *(i32x4*)&tmp[8];
}

// ---------------------------------------------------------------------------
// QKV (bf16 MFMA): z=0 -> Qf f32 + Q16 bf16, z=1 -> Kf f32 + K16 bf16,
// z=2 -> V16 bf16.  Grid (8, 64, 3).
// ---------------------------------------------------------------------------
__global__ __launch_bounds__(256) void gemm_qkv_mfma(
    const float* __restrict__ x, const unsigned short* __restrict__ WT16,
    const float* __restrict__ bq, const float* __restrict__ bk,
    const float* __restrict__ bv, float* __restrict__ Qf,
    float* __restrict__ Kf, unsigned short* __restrict__ Q16,
    unsigned short* __restrict__ K16, unsigned short* __restrict__ V16) {
  __shared__ unsigned short Asl[64][68];
  __shared__ unsigned short Bsl[64][68];
  int z = blockIdx.z;
  const unsigned short* WT = WT16 + (long long)z * 262144;
  const float* bias = (z == 0) ? bq : (z == 1) ? bk : bv;

  int row0 = blockIdx.y * 64;
  int col0 = blockIdx.x * 64;
  int t = (int)threadIdx.x, lane = t & 63, wave = t >> 6;
  int wm = wave >> 1, wn = wave & 1;

  f32x4 acc[2][2];
#pragma unroll
  for (int i = 0; i < 2; i++)
#pragma unroll
    for (int j = 0; j < 2; j++) acc[i][j] = (f32x4){0.f, 0.f, 0.f, 0.f};

  int r = t >> 2, kq = (t & 3) * 8;
  const float* Ap = x + (long long)(row0 + r) * 512 + kq;
  const unsigned short* Bp = WT + (long long)(col0 + r) * 512 + kq;

  for (int kb = 0; kb < 512; kb += 64) {
    float4 a0 = *(const float4*)(Ap + kb);
    float4 a1 = *(const float4*)(Ap + kb + 4);
    float4 a2 = *(const float4*)(Ap + kb + 32);
    float4 a3 = *(const float4*)(Ap + kb + 36);
    i32x4 b0 = *(const i32x4*)(Bp + kb);
    i32x4 b1 = *(const i32x4*)(Bp + kb + 32);
    __syncthreads();
    i32x4 pa0 = {packbf(a0.x, a0.y), packbf(a0.z, a0.w), packbf(a1.x, a1.y),
                 packbf(a1.z, a1.w)};
    i32x4 pa1 = {packbf(a2.x, a2.y), packbf(a2.z, a2.w), packbf(a3.x, a3.y),
                 packbf(a3.z, a3.w)};
    *(i32x4*)&Asl[r][kq] = pa0;
    *(i32x4*)&Asl[r][kq + 32] = pa1;
    *(i32x4*)&Bsl[r][kq] = b0;
    *(i32x4*)&Bsl[r][kq + 32] = b1;
    __syncthreads();

    int rr = lane & 15, ko = (lane >> 4) * 8;
#pragma unroll
    for (int k2 = 0; k2 < 2; k2++) {
      i32x4 af0 = *(i32x4*)&Asl[wm * 32 + rr][k2 * 32 + ko];
      i32x4 af1 = *(i32x4*)&Asl[wm * 32 + 16 + rr][k2 * 32 + ko];
      i32x4 bf0 = *(i32x4*)&Bsl[wn * 32 + rr][k2 * 32 + ko];
      i32x4 bf1 = *(i32x4*)&Bsl[wn * 32 + 16 + rr][k2 * 32 + ko];
      acc[0][0] = mfma_bf16(af0, bf0, acc[0][0]);
      acc[0][1] = mfma_bf16(af0, bf1, acc[0][1]);
      acc[1][0] = mfma_bf16(af1, bf0, acc[1][0]);
      acc[1][1] = mfma_bf16(af1, bf1, acc[1][1]);
    }
  }

  int rq = lane >> 4, rr = lane & 15;
#pragma unroll
  for (int fm = 0; fm < 2; fm++) {
#pragma unroll
    for (int fn = 0; fn < 2; fn++) {
      int col = col0 + wn * 32 + fn * 16 + rr;
      float bb = bias[col];
#pragma unroll
      for (int rl = 0; rl < 4; rl++) {
        int row = row0 + wm * 32 + fm * 16 + rq * 4 + rl;
        float v = acc[fm][fn][rl] + bb;
        if (z == 2) {
          V16[(long long)row * 512 + col] = f2bf(v);
        } else if (z == 1) {
          Kf[(long long)row * 512 + col] = v;
          K16[(long long)row * 512 + col] = f2bf(v);
        } else {
          Qf[(long long)row * 512 + col] = v;
          Q16[(long long)row * 512 + col] = f2bf(v);
        }
      }
    }
  }
}

// ---------------------------------------------------------------------------
// Out-projection (bf16 MFMA).  Grid (8, 64).
// ---------------------------------------------------------------------------
__global__ __launch_bounds__(256) void gemm_out_mfma(
    const unsigned short* __restrict__ A16,
    const unsigned short* __restrict__ WoT,
    const float* __restrict__ bo, float* __restrict__ out) {
  __shared__ unsigned short Asl[64][68];
  __shared__ unsigned short Bsl[64][68];
  int row0 = blockIdx.y * 64;
  int col0 = blockIdx.x * 64;
  int t = (int)threadIdx.x, lane = t & 63, wave = t >> 6;
  int wm = wave >> 1, wn = wave & 1;

  f32x4 acc[2][2];
#pragma unroll
  for (int i = 0; i < 2; i++)
#pragma unroll
    for (int j = 0; j < 2; j++) acc[i][j] = (f32x4){0.f, 0.f, 0.f, 0.f};

  int r = t >> 2, kq = (t & 3) * 8;
  const unsigned short* Ap = A16 + (long long)(row0 + r) * 512 + kq;
  const unsigned short* Bp = WoT + (long long)(col0 + r) * 512 + kq;

  for (int kb = 0; kb < 512; kb += 64) {
    i32x4 a0 = *(const i32x4*)(Ap + kb);
    i32x4 a1 = *(const i32x4*)(Ap + kb + 32);
    i32x4 b0 = *(const i32x4*)(Bp + kb);
    i32x4 b1 = *(const i32x4*)(Bp + kb + 32);
    __syncthreads();
    *(i32x4*)&Asl[r][kq] = a0;
    *(i32x4*)&Asl[r][kq + 32] = a1;
    *(i32x4*)&Bsl[r][kq] = b0;
    *(i32x4*)&Bsl[r][kq + 32] = b1;
    __syncthreads();

    int rr = lane & 15, ko = (lane >> 4) * 8;
#pragma unroll
    for (int k2 = 0; k2 < 2; k2++) {
      i32x4 af0 = *(i32x4*)&Asl[wm * 32 + rr][k2 * 32 + ko];
      i32x4 af1 = *(i32x4*)&Asl[wm * 32 + 16 + rr][k2 * 32 + ko];
      i32x4 bf0 = *(i32x4*)&Bsl[wn * 32 + rr][k2 * 32 + ko];
      i32x4 bf1 = *(i32x4*)&Bsl[wn * 32 + 16 + rr][k2 * 32 + ko];
      acc[0][0] = mfma_bf16(af0, bf0, acc[0][0]);
      acc[0][1] = mfma_bf16(af0, bf1, acc[0][1]);
      acc[1][0] = mfma_bf16(af1, bf0, acc[1][0]);
      acc[1][1] = mfma_bf16(af1, bf1, acc[1][1]);
    }
  }

  int rq = lane >> 4, rr = lane & 15;
#pragma unroll
  for (int fm = 0; fm < 2; fm++) {
#pragma unroll
    for (int fn = 0; fn < 2; fn++) {
      int col = col0 + wn * 32 + fn * 16 + rr;
      float bb = bo[col];
#pragma unroll
      for (int rl = 0; rl < 4; rl++) {
        int row = row0 + wm * 32 + fm * 16 + rq * 4 + rl;
        out[(long long)row * 512 + col] = acc[fm][fn][rl] + bb;
      }
    }
  }
}

// ---------------------------------------------------------------------------
// sv = scl·0.125·R·K^T per head.  Grid (16, 16, 32).
// ---------------------------------------------------------------------------
__global__ __launch_bounds__(256) void gemm_sfinal(
    const unsigned short* __restrict__ R16a,
    const unsigned short* __restrict__ K16a,
    const float* __restrict__ scla, unsigned short* __restrict__ sv16a) {
  __shared__ unsigned short Asl[64][68];
  __shared__ unsigned short Bsl[64][68];
  int z = blockIdx.z;
  int b = z >> 3, h = z & 7;
  const unsigned short* A16 = R16a + (long long)b * 524288;
  const unsigned short* Bm = K16a + (long long)b * 524288;
  const float* scl = scla + b * 1024;
  unsigned short* sv = sv16a + (long long)b * 8388608;
  int row0 = blockIdx.y * 64;
  int col0 = blockIdx.x * 64;
  int t = (int)threadIdx.x, lane = t & 63, wave = t >> 6;
  int wm = wave >> 1, wn = wave & 1;

  f32x4 acc[2][2];
#pragma unroll
  for (int i = 0; i < 2; i++)
#pragma unroll
    for (int j = 0; j < 2; j++) acc[i][j] = (f32x4){0.f, 0.f, 0.f, 0.f};

  int r = t >> 2, kq = (t & 3) * 8;
  const unsigned short* Ap = A16 + (long long)(row0 + r) * 512 + h * 64 + kq;
  const unsigned short* Bp = Bm + (long long)(col0 + r) * 512 + h * 64 + kq;

  {
    i32x4 a0 = *(const i32x4*)(Ap);
    i32x4 a1 = *(const i32x4*)(Ap + 32);
    i32x4 b0 = *(const i32x4*)(Bp);
    i32x4 b1 = *(const i32x4*)(Bp + 32);
    __syncthreads();
    *(i32x4*)&Asl[r][kq] = a0;
    *(i32x4*)&Asl[r][kq + 32] = a1;
    *(i32x4*)&Bsl[r][kq] = b0;
    *(i32x4*)&Bsl[r][kq + 32] = b1;
    __syncthreads();

    int rr = lane & 15, ko = (lane >> 4) * 8;
#pragma unroll
    for (int k2 = 0; k2 < 2; k2++) {
      i32x4 af0 = *(i32x4*)&Asl[wm * 32 + rr][k2 * 32 + ko];
      i32x4 af1 = *(i32x4*)&Asl[wm * 32 + 16 + rr][k2 * 32 + ko];
      i32x4 bf0 = *(i32x4*)&Bsl[wn * 32 + rr][k2 * 32 + ko];
      i32x4 bf1 = *(i32x4*)&Bsl[wn * 32 + 16 + rr][k2 * 32 + ko];
      acc[0][0] = mfma_bf16(af0, bf0, acc[0][0]);
      acc[0][1] = mfma_bf16(af0, bf1, acc[0][1]);
      acc[1][0] = mfma_bf16(af1, bf0, acc[1][0]);
      acc[1][1] = mfma_bf16(af1, bf1, acc[1][1]);
    }
  }

  int rq = lane >> 4, rr = lane & 15;
#pragma unroll
  for (int fm = 0; fm < 2; fm++) {
#pragma unroll
    for (int fn = 0; fn < 2; fn++) {
      int col = col0 + wn * 32 + fn * 16 + rr;
#pragma unroll
      for (int rl = 0; rl < 4; rl++) {
        int row = row0 + wm * 32 + fm * 16 + rq * 4 + rl;
        sv[(long long)row * 8192 + h * 1024 + col] =
            f2bf(0.125f * scl[row] * acc[fm][fn][rl]);
      }
    }
  }
}

// ---------------------------------------------------------------------------
// Y = Q·T per head (sfinal mold, B = T16 row-major ldb=64).  Grid (1,16,32).
// ---------------------------------------------------------------------------
__global__ __launch_bounds__(256) void gemm_Y_bf16(
    const unsigned short* __restrict__ Q16a,   // [4][1024,512]
    const unsigned short* __restrict__ T16a,   // [32][64,64]
    unsigned short* __restrict__ Y16a) {       // [4][1024,512]
  __shared__ unsigned short Asl[64][68];
  __shared__ unsigned short Bsl[64][68];
  int z = blockIdx.z;
  int b = z >> 3, h = z & 7;
  const unsigned short* A16 = Q16a + (long long)b * 524288;
  const unsigned short* Tz = T16a + (long long)z * 4096;
  unsigned short* Y = Y16a + (long long)b * 524288;
  int row0 = blockIdx.y * 64;
  int t = (int)threadIdx.x, lane = t & 63, wave = t >> 6;
  int wm = wave >> 1, wn = wave & 1;

  f32x4 acc[2][2];
#pragma unroll
  for (int i = 0; i < 2; i++)
#pragma unroll
    for (int j = 0; j < 2; j++) acc[i][j] = (f32x4){0.f, 0.f, 0.f, 0.f};

  int r = t >> 2, kq = (t & 3) * 8;
  const unsigned short* Ap = A16 + (long long)(row0 + r) * 512 + h * 64 + kq;
  const unsigned short* Bp = Tz + (long long)r * 64 + kq;

  {
    i32x4 a0 = *(const i32x4*)(Ap);
    i32x4 a1 = *(const i32x4*)(Ap + 32);
    i32x4 b0 = *(const i32x4*)(Bp);
    i32x4 b1 = *(const i32x4*)(Bp + 32);
    __syncthreads();
    *(i32x4*)&Asl[r][kq] = a0;
    *(i32x4*)&Asl[r][kq + 32] = a1;
    *(i32x4*)&Bsl[r][kq] = b0;
    *(i32x4*)&Bsl[r][kq + 32] = b1;
    __syncthreads();

    int rr = lane & 15, ko = (lane >> 4) * 8;
#pragma unroll
    for (int k2 = 0; k2 < 2; k2++) {
      i32x4 af0 = *(i32x4*)&Asl[wm * 32 + rr][k2 * 32 + ko];
      i32x4 af1 = *(i32x4*)&Asl[wm * 32 + 16 + rr][k2 * 32 + ko];
      i32x4 bf0 = *(i32x4*)&Bsl[wn * 32 + rr][k2 * 32 + ko];
      i32x4 bf1 = *(i32x4*)&Bsl[wn * 32 + 16 + rr][k2 * 32 + ko];
      acc[0][0] = mfma_bf16(af0, bf0, acc[0][0]);
      acc[0][1] = mfma_bf16(af0, bf1, acc[0][1]);
      acc[1][0] = mfma_bf16(af1, bf0, acc[1][0]);
      acc[1][1] = mfma_bf16(af1, bf1, acc[1][1]);
    }
  }

  int rq = lane >> 4, rr = lane & 15;
#pragma unroll
  for (int fm = 0; fm < 2; fm++) {
#pragma unroll
    for (int fn = 0; fn < 2; fn++) {
      int col = wn * 32 + fn * 16 + rr;
#pragma unroll
      for (int rl = 0; rl < 4; rl++) {
        int row = row0 + wm * 32 + fm * 16 + rq * 4 + rl;
        Y[(long long)row * 512 + h * 64 + col] = f2bf(acc[fm][fn][rl]);
      }
    }
  }
}

// ---------------------------------------------------------------------------
// Scores (fp32 compute, bf16 out).  Grid (8, 8, 32).
// ---------------------------------------------------------------------------
__global__ __launch_bounds__(256) void gemm_scores_bf16(
    const float* __restrict__ Qf, const float* __restrict__ Kf,
    unsigned short* __restrict__ u16a) {
  __shared__ float As[8][132];
  __shared__ float Bs[8][132];
  int z = blockIdx.z;
  int b = z >> 3, h = z & 7;
  const float* A = Qf + (long long)b * 524288 + h * 64;
  const float* B = Kf + (long long)b * 524288 + h * 64;
  unsigned short* C16 = u16a + (long long)b * 8388608 + h * 1024;

  int row0 = blockIdx.y * 128;
  int col0 = blockIdx.x * 128;
  int tid = (int)threadIdx.x;
  int tx = tid & 15, ty = tid >> 4;
  int arow = tid >> 1;
  int akc = (tid & 1) * 4;

  float acc[8][8];
#pragma unroll
  for (int i = 0; i < 8; i++)
#pragma unroll
    for (int j = 0; j < 8; j++) acc[i][j] = 0.f;

  const float* Aptr = A + (long long)(row0 + arow) * 512 + akc;
  const float* Bptr = B + (long long)(col0 + arow) * 512 + akc;

  for (int kb = 0; kb < 64; kb += 8) {
    float4 av = *(const float4*)(Aptr + kb);
    float4 bv = *(const float4*)(Bptr + kb);
    __syncthreads();
    As[akc + 0][arow] = av.x; As[akc + 1][arow] = av.y;
    As[akc + 2][arow] = av.z; As[akc + 3][arow] = av.w;
    Bs[akc + 0][arow] = bv.x; Bs[akc + 1][arow] = bv.y;
    Bs[akc + 2][arow] = bv.z; Bs[akc + 3][arow] = bv.w;
    __syncthreads();

#pragma unroll
    for (int k = 0; k < 8; k++) {
      float a[8], b2[8];
#pragma unroll
      for (int c = 0; c < 2; c++) {
        float4 q = *(float4*)&As[k][ty * 8 + c * 4];
        a[c * 4 + 0] = q.x; a[c * 4 + 1] = q.y;
        a[c * 4 + 2] = q.z; a[c * 4 + 3] = q.w;
      }
#pragma unroll
      for (int c = 0; c < 2; c++) {
        float4 q = *(float4*)&Bs[k][c * 64 + tx * 4];
        b2[c * 4 + 0] = q.x; b2[c * 4 + 1] = q.y;
        b2[c * 4 + 2] = q.z; b2[c * 4 + 3] = q.w;
      }
#pragma unroll
      for (int i = 0; i < 8; i++)
#pragma unroll
        for (int j = 0; j < 8; j++) acc[i][j] = fmaf(a[i], b2[j], acc[i][j]);
    }
  }

#pragma unroll
  for (int i = 0; i < 8; i++) {
    long long r = row0 + ty * 8 + i;
#pragma unroll
    for (int c = 0; c < 2; c++) {
      int col = col0 + c * 64 + tx * 4;
      unsigned int lo = (unsigned int)f2bf(0.125f * acc[i][c * 4 + 0]) |
                        ((unsigned int)f2bf(0.125f * acc[i][c * 4 + 1]) << 16);
      unsigned int hi = (unsigned int)f2bf(0.125f * acc[i][c * 4 + 2]) |
                        ((unsigned int)f2bf(0.125f * acc[i][c * 4 + 3]) << 16);
      uint2 o = {lo, hi};
      *(uint2*)&C16[r * 8192 + col] = o;
    }
  }
}

// ---------------------------------------------------------------------------
// bf16 transpose, z-batched.
// ---------------------------------------------------------------------------
__global__ __launch_bounds__(256) void transpose16_kernel(
    const unsigned short* __restrict__ src, unsigned short* __restrict__ dst,
    int ldS, int ldD, long long zsS, long long zsD) {
  __shared__ unsigned short T[64][72];
  src += (long long)blockIdx.z * zsS;
  dst += (long long)blockIdx.z * zsD;
  int i0 = blockIdx.x * 64;
  int c0 = blockIdx.y * 64;
  int t = (int)threadIdx.x;
  int r = t >> 2, cq = (t & 3) * 16;
  i32x4 v0 = *(const i32x4*)&src[(long long)(i0 + r) * ldS + c0 + cq];
  i32x4 v1 = *(const i32x4*)&src[(long long)(i0 + r) * ldS + c0 + cq + 8];
  *(i32x4*)&T[r][cq] = v0;
  *(i32x4*)&T[r][cq + 8] = v1;
  __syncthreads();
  int c = t >> 2, iq = (t & 3) * 16;
  unsigned short tmp[16];
#pragma unroll
  for (int j = 0; j < 16; j++) tmp[j] = T[iq + j][c];
  *(i32x4*)&dst[(long long)(c0 + c) * ldD + i0 + iq] = *(i32x4*)&tmp[0];
  *(i32x4*)&dst[(long long)(c0 + c) * ldD + i0 + iq + 8] = *(i32x4*)&tmp[8];
}

// f32 -> bf16 transpose.  Grid (16, 8, 4).
__global__ __launch_bounds__(256) void transpose_f32_bf16_kernel(
    const float* __restrict__ src, unsigned short* __restrict__ dst,
    int ldS, int ldD, long long zsS, long long zsD) {
  __shared__ unsigned short T[64][72];
  src += (long long)blockIdx.z * zsS;
  dst += (long long)blockIdx.z * zsD;
  int i0 = blockIdx.x * 64;
  int c0 = blockIdx.y * 64;
  int t = (int)threadIdx.x;
  int r = t >> 2, cq = (t & 3) * 16;
#pragma unroll
  for (int j = 0; j < 4; j++) {
    float4 v = *(const float4*)&src[(long long)(i0 + r) * ldS + c0 + cq + j * 4];
    T[r][cq + j * 4 + 0] = f2bf(v.x);
    T[r][cq + j * 4 + 1] = f2bf(v.y);
    T[r][cq + j * 4 + 2] = f2bf(v.z);
    T[r][cq + j * 4 + 3] = f2bf(v.w);
  }
  __syncthreads();
  int c = t >> 2, iq = (t & 3) * 16;
  unsigned short tmp[16];
#pragma unroll
  for (int j = 0; j < 16; j++) tmp[j] = T[iq + j][c];
  *(i32x4*)&dst[(long long)(c0 + c) * ldD + i0 + iq] = *(i32x4*)&tmp[0];
  *(i32x4*)&dst[(long long)(c0 + c) * ldD + i0 + iq + 8] = *(i32x4*)&tmp[8];
}

// ---------------------------------------------------------------------------
// T_h = (1/64)·K_h^T·K_h (gemm_M mold, A=B=KT rows, Kend=1024).  Grid (32).
// ---------------------------------------------------------------------------
__global__ __launch_bounds__(256) void gemm_T_bf16(
    const unsigned short* __restrict__ KT16a,  // [4][512,1024]
    unsigned short* __restrict__ T16a) {       // [32][64,64]
  int z = blockIdx.x;
  int b = z >> 3, h = z & 7;
  const unsigned short* KT =
      KT16a + (long long)b * 524288 + (long long)h * 65536;
  __shared__ unsigned short Asl[64][64];
  __shared__ unsigned short Bsl[64][64];
  int t = (int)threadIdx.x, lane = t & 63, wave = t >> 6;
  int wm = wave >> 1, wn = wave & 1;

  f32x4 acc[2][2];
#pragma unroll
  for (int i = 0; i < 2; i++)
#pragma unroll
    for (int j = 0; j < 2; j++) acc[i][j] = (f32x4){0.f, 0.f, 0.f, 0.f};

  int r = t >> 2, c0 = t & 3;
  int sw0 = ((c0 ^ (r & 7))) * 8;
  int sw1 = (((c0 + 4) ^ (r & 7))) * 8;
  const unsigned short* Ap = KT + (long long)r * 1024 + c0 * 8;

  for (int kb = 0; kb < 1024; kb += 64) {
    i32x4 a0 = *(const i32x4*)(Ap + kb);
    i32x4 a1 = *(const i32x4*)(Ap + kb + 32);
    __syncthreads();
    *(i32x4*)&Asl[r][sw0] = a0;
    *(i32x4*)&Asl[r][sw1] = a1;
    *(i32x4*)&Bsl[r][sw0] = a0;
    *(i32x4*)&Bsl[r][sw1] = a1;
    __syncthreads();

    int rr = lane & 15, co = lane >> 4;
#pragma unroll
    for (int k2 = 0; k2 < 2; k2++) {
      int ch = ((k2 * 4 + co) ^ (rr & 7)) * 8;
      i32x4 af0 = *(i32x4*)&Asl[wm * 32 + rr][ch];
      i32x4 af1 = *(i32x4*)&Asl[wm * 32 + 16 + rr][ch];
      i32x4 bf0 = *(i32x4*)&Bsl[wn * 32 + rr][ch];
      i32x4 bf1 = *(i32x4*)&Bsl[wn * 32 + 16 + rr][ch];
      acc[0][0] = mfma_bf16(af0, bf0, acc[0][0]);
      acc[0][1] = mfma_bf16(af0, bf1, acc[0][1]);
      acc[1][0] = mfma_bf16(af1, bf0, acc[1][0]);
      acc[1][1] = mfma_bf16(af1, bf1, acc[1][1]);
    }
  }

  unsigned short* Tz = T16a + (long long)z * 4096;
  int rq = lane >> 4, rr = lane & 15;
#pragma unroll
  for (int fm = 0; fm < 2; fm++) {
#pragma unroll
    for (int fn = 0; fn < 2; fn++) {
      int j = wn * 32 + fn * 16 + rr;
#pragma unroll
      for (int rl = 0; rl < 4; rl++) {
        int i = wm * 32 + fm * 16 + rq * 4 + rl;
        Tz[i * 64 + j] = f2bf(0.015625f * acc[fm][fn][rl]);
      }
    }
  }
}

// ---------------------------------------------------------------------------
// G = Y·Q^T, lower-triangle 128-blocks (K=512, bf16 out).  Grid (8, 8, 4).
// ---------------------------------------------------------------------------
__global__ __launch_bounds__(256) void gemm_YQ_bf16(
    const unsigned short* __restrict__ Y16a,
    const unsigned short* __restrict__ Q16a,
    unsigned short* __restrict__ G16a) {
  __shared__ unsigned short Alds[128][72];
  __shared__ unsigned short Blds[128][72];
  int row0 = blockIdx.y * 128;
  int col0 = blockIdx.x * 128;
  if (col0 > row0) return;
  int b = blockIdx.z;
  const unsigned short* Y = Y16a + (long long)b * 524288;
  const unsigned short* Q = Q16a + (long long)b * 524288;
  unsigned short* G = G16a + (long long)b * 1048576;
  int t = (int)threadIdx.x, lane = t & 63, wave = t >> 6;
  int wm = wave >> 1, wn = wave & 1;

  f32x4 acc[4][4];
#pragma unroll
  for (int i = 0; i < 4; i++)
#pragma unroll
    for (int j = 0; j < 4; j++) acc[i][j] = (f32x4){0.f, 0.f, 0.f, 0.f};

  int ar = t >> 2;
  int aq = (t & 3) * 16;
  const unsigned short* Ap = Y + (long long)(row0 + ar) * 512 + aq;
  const unsigned short* Ap2 = Ap + 64LL * 512;
  const unsigned short* Bp = Q + (long long)(col0 + ar) * 512 + aq;
  const unsigned short* Bp2 = Bp + 64LL * 512;

  for (int kb = 0; kb < 512; kb += 64) {
    i32x4 a0 = *(const i32x4*)(Ap + kb);
    i32x4 a1 = *(const i32x4*)(Ap + kb + 8);
    i32x4 a2 = *(const i32x4*)(Ap2 + kb);
    i32x4 a3 = *(const i32x4*)(Ap2 + kb + 8);
    i32x4 b0 = *(const i32x4*)(Bp + kb);
    i32x4 b1 = *(const i32x4*)(Bp + kb + 8);
    i32x4 b2 = *(const i32x4*)(Bp2 + kb);
    i32x4 b3 = *(const i32x4*)(Bp2 + kb + 8);
    __syncthreads();
    *(i32x4*)&Alds[ar][aq] = a0;
    *(i32x4*)&Alds[ar][aq + 8] = a1;
    *(i32x4*)&Alds[ar + 64][aq] = a2;
    *(i32x4*)&Alds[ar + 64][aq + 8] = a3;
    *(i32x4*)&Blds[ar][aq] = b0;
    *(i32x4*)&Blds[ar][aq + 8] = b1;
    *(i32x4*)&Blds[ar + 64][aq] = b2;
    *(i32x4*)&Blds[ar + 64][aq + 8] = b3;
    __syncthreads();

    int rr = lane & 15, ko = (lane >> 4) * 8;
#pragma unroll
    for (int k2 = 0; k2 < 2; k2++) {
      i32x4 af[4], bfv[4];
#pragma unroll
      for (int fm = 0; fm < 4; fm++)
        af[fm] = *(i32x4*)&Alds[wm * 64 + fm * 16 + rr][k2 * 32 + ko];
#pragma unroll
      for (int fn = 0; fn < 4; fn++)
        bfv[fn] = *(i32x4*)&Blds[wn * 64 + fn * 16 + rr][k2 * 32 + ko];
#pragma unroll
      for (int fm = 0; fm < 4; fm++)
#pragma unroll
        for (int fn = 0; fn < 4; fn++)
          acc[fm][fn] = mfma_bf16(af[fm], bfv[fn], acc[fm][fn]);
    }
  }

  int rq = lane >> 4, rr = lane & 15;
#pragma unroll
  for (int fm = 0; fm < 4; fm++) {
#pragma unroll
    for (int fn = 0; fn < 4; fn++) {
      int col = col0 + wn * 64 + fn * 16 + rr;
#pragma unroll
      for (int r = 0; r < 4; r++) {
        int row = row0 + wm * 64 + fm * 16 + rq * 4 + r;
        G[(long long)row * 1024 + col] = f2bf(acc[fm][fn][r]);
      }
    }
  }
}

// Mirror lower 128-blocks to upper (transpose16 body).  Grid (16, 16, 4).
__global__ __launch_bounds__(256) void mirror_G_kernel(
    unsigned short* __restrict__ G16a) {
  int txl = blockIdx.x, tyl = blockIdx.y;
  if ((txl >> 1) >= (tyl >> 1)) return;
  unsigned short* G = G16a + (long long)blockIdx.z * 1048576;
  __shared__ unsigned short T[64][72];
  int i0 = tyl * 64;
  int c0 = txl * 64;
  int t = (int)threadIdx.x;
  int r = t >> 2, cq = (t & 3) * 16;
  i32x4 v0 = *(const i32x4*)&G[(long long)(i0 + r) * 1024 + c0 + cq];
  i32x4 v1 = *(const i32x4*)&G[(long long)(i0 + r) * 1024 + c0 + cq + 8];
  *(i32x4*)&T[r][cq] = v0;
  *(i32x4*)&T[r][cq + 8] = v1;
  __syncthreads();
  int c = t >> 2, iq = (t & 3) * 16;
  unsigned short tmp[16];
#pragma unroll
  for (int j = 0; j < 16; j++) tmp[j] = T[iq + j][c];
  *(i32x4*)&G[(long long)(c0 + c) * 1024 + i0 + iq] = *(i32x4*)&tmp[0];
  *(i32x4*)&G[(long long)(c0 + c) * 1024 + i0 + iq + 8] = *(i32x4*)&tmp[8];
}

// ---------------------------------------------------------------------------
// M = C·G (bf16 MFMA, z-batched).
// ---------------------------------------------------------------------------
__global__ __launch_bounds__(256) void gemm_M_bf16(
    const unsigned short* __restrict__ Ca, const unsigned short* __restrict__ Ga,
    float* __restrict__ Ma) {
  int row0 = blockIdx.y * 64;
  int col0 = blockIdx.x * 64;
  if (col0 > row0) return;
  int b = blockIdx.z;
  const unsigned short* C = Ca + (long long)b * 1048576;
  const unsigned short* G = Ga + (long long)b * 1048576;
  float* M = Ma + (long long)b * 1048576;
  int Kend = row0 + 64;
  __shared__ unsigned short Asl[64][64];
  __shared__ unsigned short Bsl[64][64];
  int t = (int)threadIdx.x, lane = t & 63, wave = t >> 6;
  int wm = wave >> 1, wn = wave & 1;

  f32x4 acc[2][2];
#pragma unroll
  for (int i = 0; i < 2; i++)
#pragma unroll
    for (int j = 0; j < 2; j++) acc[i][j] = (f32x4){0.f, 0.f, 0.f, 0.f};

  int r = t >> 2, c0 = t & 3;
  int sw0 = ((c0 ^ (r & 7))) * 8;
  int sw1 = (((c0 + 4) ^ (r & 7))) * 8;
  const unsigned short* Ap = C + (long long)(row0 + r) * 1024 + c0 * 8;
  const unsigned short* Bp = G + (long long)(col0 + r) * 1024 + c0 * 8;

  for (int kb = 0; kb < Kend; kb += 64) {
    i32x4 a0 = *(const i32x4*)(Ap + kb);
    i32x4 a1 = *(const i32x4*)(Ap + kb + 32);
    i32x4 b0 = *(const i32x4*)(Bp + kb);
    i32x4 b1 = *(const i32x4*)(Bp + kb + 32);
    __syncthreads();
    *(i32x4*)&Asl[r][sw0] = a0;
    *(i32x4*)&Asl[r][sw1] = a1;
    *(i32x4*)&Bsl[r][sw0] = b0;
    *(i32x4*)&Bsl[r][sw1] = b1;
    __syncthreads();

    int rr = lane & 15, co = lane >> 4;
#pragma unroll
    for (int k2 = 0; k2 < 2; k2++) {
      int ch = ((k2 * 4 + co) ^ (rr & 7)) * 8;
      i32x4 af0 = *(i32x4*)&Asl[wm * 32 + rr][ch];
      i32x4 af1 = *(i32x4*)&Asl[wm * 32 + 16 + rr][ch];
      i32x4 bf0 = *(i32x4*)&Bsl[wn * 32 + rr][ch];
      i32x4 bf1 = *(i32x4*)&Bsl[wn * 32 + 16 + rr][ch];
      acc[0][0] = mfma_bf16(af0, bf0, acc[0][0]);
      acc[0][1] = mfma_bf16(af0, bf1, acc[0][1]);
      acc[1][0] = mfma_bf16(af1, bf0, acc[1][0]);
      acc[1][1] = mfma_bf16(af1, bf1, acc[1][1]);
    }
  }

  int rq = lane >> 4, rr = lane & 15;
#pragma unroll
  for (int fm = 0; fm < 2; fm++) {
#pragma unroll
    for (int fn = 0; fn < 2; fn++) {
      int j = col0 + wn * 32 + fn * 16 + rr;
#pragma unroll
      for (int rl = 0; rl < 4; rl++) {
        int i = row0 + wm * 32 + fm * 16 + rq * 4 + rl;
        M[(long long)i * 1024 + j] = acc[fm][fn][rl];
      }
    }
  }
}

// ---------------------------------------------------------------------------
// Fused scldot + b-update + causal softmax (it0/it1).  Grid (1024, 4).
// ---------------------------------------------------------------------------
template <int INIT>
__global__ __launch_bounds__(256) void fused_scl_bupd_kernel(
    float* __restrict__ bHa, const float* __restrict__ Ma,
    unsigned short* __restrict__ cH16a) {
  __shared__ float red[4];
  int i = blockIdx.x;
  int b = blockIdx.y;
  float* bH = bHa + (long long)b * 1048576;
  const float* M = Ma + (long long)b * 1048576;
  unsigned short* cH16 = cH16a + (long long)b * 1048576;
  long long base = (long long)i * 1024;
  int t = (int)threadIdx.x, k0 = t * 4;
  float4 m = *(const float4*)&M[base + k0];
  uint2 pc = *(const uint2*)&cH16[base + k0];
  float c0 = bf2f(pc.x & 0xffffu), c1 = bf2f(pc.x >> 16);
  float c2 = bf2f(pc.y & 0xffffu), c3 = bf2f(pc.y >> 16);
  bool m0 = (k0 + 0) <= i, m1 = (k0 + 1) <= i, m2 = (k0 + 2) <= i,
       m3 = (k0 + 3) <= i;
  float acc = 0.f;
  if (m0) acc += c0 * m.x;
  if (m1) acc += c1 * m.y;
  if (m2) acc += c2 * m.z;
  if (m3) acc += c3 * m.w;
  float ssq = blockSum(acc, red);
  float sc = (ssq / (1.f + ssq)) / sqrtf(ssq + SQ_EPS);

  float4 x;
  if (INIT) x = (float4){0.f, 0.f, 0.f, 0.f};
  else x = *(const float4*)&bH[base + k0];
  if (m0) x.x += sc * m.x;
  if (m1) x.y += sc * m.y;
  if (m2) x.z += sc * m.z;
  if (m3) x.w += sc * m.w;
  *(float4*)&bH[base + k0] = x;
  float mx = -3.0e38f;
  if (m0) mx = fmaxf(mx, x.x);
  if (m1) mx = fmaxf(mx, x.y);
  if (m2) mx = fmaxf(mx, x.z);
  if (m3) mx = fmaxf(mx, x.w);
  mx = blockMax(mx, red);
  float e0 = m0 ? expf(x.x - mx) : 0.f;
  float e1 = m1 ? expf(x.y - mx) : 0.f;
  float e2 = m2 ? expf(x.z - mx) : 0.f;
  float e3 = m3 ? expf(x.w - mx) : 0.f;
  float zz = blockSum(e0 + e1 + e2 + e3, red);
  float inv = 1.f / zz;
  uint2 o = {(unsigned int)f2bf(e0 * inv) | ((unsigned int)f2bf(e1 * inv) << 16),
             (unsigned int)f2bf(e2 * inv) | ((unsigned int)f2bf(e3 * inv) << 16)};
  *(uint2*)&cH16[base + k0] = o;
}

// ||s_i||^2 -> scl (it2).  Grid (1024, 4).
__global__ __launch_bounds__(256) void scldot_kernel(
    const float* __restrict__ Ma, const unsigned short* __restrict__ Ca,
    float* __restrict__ scl) {
  __shared__ float red[4];
  int i = blockIdx.x;
  int b = blockIdx.y;
  const float* M = Ma + (long long)b * 1048576;
  const unsigned short* C = Ca + (long long)b * 1048576;
  int t = (int)threadIdx.x, j0 = t * 4;
  long long base = (long long)i * 1024;
  float4 m = *(const float4*)&M[base + j0];
  uint2 pc = *(const uint2*)&C[base + j0];
  float c0 = bf2f(pc.x & 0xffffu), c1 = bf2f(pc.x >> 16);
  float c2 = bf2f(pc.y & 0xffffu), c3 = bf2f(pc.y >> 16);
  float acc = 0.f;
  if (j0 + 0 <= i) acc += c0 * m.x;
  if (j0 + 1 <= i) acc += c1 * m.y;
  if (j0 + 2 <= i) acc += c2 * m.z;
  if (j0 + 3 <= i) acc += c3 * m.w;
  float ssq = blockSum(acc, red);
  if (t == 0) scl[b * 1024 + i] = (ssq / (1.f + ssq)) / sqrtf(ssq + SQ_EPS);
}

// it=0 coupling.  Grid (1024, 4).
__global__ __launch_bounds__(256) void softmax_uniform_kernel(
    unsigned short* __restrict__ cH16a) {
  int i = blockIdx.x;
  int b = blockIdx.y;
  unsigned short* cH16 = cH16a + (long long)b * 1048576;
  int t = (int)threadIdx.x, k0 = t * 4;
  unsigned short c = f2bf(1.f / (float)(i + 1));
  unsigned short e0 = (k0 + 0) <= i ? c : (unsigned short)0;
  unsigned short e1 = (k0 + 1) <= i ? c : (unsigned short)0;
  unsigned short e2 = (k0 + 2) <= i ? c : (unsigned short)0;
  unsigned short e3 = (k0 + 3) <= i ? c : (unsigned short)0;
  uint2 o = {(unsigned int)e0 | ((unsigned int)e1 << 16),
             (unsigned int)e2 | ((unsigned int)e3 << 16)};
  *(uint2*)&cH16[(long long)i * 1024 + k0] = o;
}

// ---------------------------------------------------------------------------
// R = C·Q (causal).  Grid (4, 8, 4).
// ---------------------------------------------------------------------------
__global__ __launch_bounds__(256) void gemm_R_bf16(
    const unsigned short* __restrict__ Ca, const unsigned short* __restrict__ QTa,
    unsigned short* __restrict__ R16a) {
  __shared__ unsigned short Alds[128][32];
  __shared__ unsigned short Blds[128][32];
  int b = blockIdx.z;
  const unsigned short* Abf = Ca + (long long)b * 1048576;
  const unsigned short* BT = QTa + (long long)b * 524288;
  unsigned short* Cout = R16a + (long long)b * 524288;
  int rowblk = 7 - (int)blockIdx.y;
  int row0 = rowblk * 128;
  int col0 = blockIdx.x * 128;
  int t = (int)threadIdx.x, lane = t & 63, wave = t >> 6;
  int wm = wave >> 1, wn = wave & 1;
  int Kend = row0 + 128;

  f32x4 acc[4][4];
#pragma unroll
  for (int i = 0; i < 4; i++)
#pragma unroll
    for (int j = 0; j < 4; j++) acc[i][j] = (f32x4){0.f, 0.f, 0.f, 0.f};

  int ar = t >> 2;
  int aq = (t & 3) * 8;

  for (int kb = 0; kb < Kend; kb += 32) {
    i32x4 a0 = *(const i32x4*)&Abf[(long long)(row0 + ar) * 1024 + kb + aq];
    i32x4 a1 = *(const i32x4*)&Abf[(long long)(row0 + ar + 64) * 1024 + kb + aq];
    i32x4 b0 = *(const i32x4*)&BT[(long long)(col0 + ar) * 1024 + kb + aq];
    i32x4 b1 = *(const i32x4*)&BT[(long long)(col0 + ar + 64) * 1024 + kb + aq];
    __syncthreads();
    *(i32x4*)&Alds[ar][aq] = a0;
    *(i32x4*)&Alds[ar + 64][aq] = a1;
    *(i32x4*)&Blds[ar][aq] = b0;
    *(i32x4*)&Blds[ar + 64][aq] = b1;
    __syncthreads();

    int rr = lane & 15, koff = (lane >> 4) * 8;
    i32x4 af[4], bfv[4];
#pragma unroll
    for (int fm = 0; fm < 4; fm++)
      af[fm] = *(i32x4*)&Alds[wm * 64 + fm * 16 + rr][koff];
#pragma unroll
    for (int fn = 0; fn < 4; fn++)
      bfv[fn] = *(i32x4*)&Blds[wn * 64 + fn * 16 + rr][koff];
#pragma unroll
    for (int fm = 0; fm < 4; fm++)
#pragma unroll
      for (int fn = 0; fn < 4; fn++)
        acc[fm][fn] = mfma_bf16(af[fm], bfv[fn], acc[fm][fn]);
  }

  int rq = lane >> 4, rr = lane & 15;
#pragma unroll
  for (int fm = 0; fm < 4; fm++) {
#pragma unroll
    for (int fn = 0; fn < 4; fn++) {
      int col = col0 + wn * 64 + fn * 16 + rr;
#pragma unroll
      for (int r = 0; r < 4; r++) {
        int row = row0 + wm * 64 + fm * 16 + rq * 4 + r;
        Cout[(long long)row * 512 + col] = f2bf(acc[fm][fn][r]);
      }
    }
  }
}

// ---------------------------------------------------------------------------
// ctx (bf16 MFMA, bf16 out).  Grid (64, 8).
// ---------------------------------------------------------------------------
__global__ __launch_bounds__(256) void gemm_ctx_bf16(
    const unsigned short* __restrict__ w16,
    const unsigned short* __restrict__ VTa, unsigned short* __restrict__ ctx16) {
  int row0 = blockIdx.x * 64;
  int b = blockIdx.x >> 4;
  int h = blockIdx.y;
  const unsigned short* VT = VTa + (long long)b * 524288;
  __shared__ unsigned short Asl[64][68];
  __shared__ unsigned short Bsl[64][68];
  int t = (int)threadIdx.x, lane = t & 63, wave = t >> 6;

  f32x4 acc[4];
#pragma unroll
  for (int i = 0; i < 4; i++) acc[i] = (f32x4){0.f, 0.f, 0.f, 0.f};

  int r = t >> 2, kq = (t & 3) * 8;
  const unsigned short* Ap = w16 + (long long)(row0 + r) * 8192 + h * 1024 + kq;
  const unsigned short* Bp = VT + (long long)(h * 64 + r) * 1024 + kq;

  for (int kb = 0; kb < 1024; kb += 64) {
    i32x4 a0 = *(const i32x4*)(Ap + kb);
    i32x4 a1 = *(const i32x4*)(Ap + kb + 32);
    i32x4 b0 = *(const i32x4*)(Bp + kb);
    i32x4 b1 = *(const i32x4*)(Bp + kb + 32);
    __syncthreads();
    *(i32x4*)&Asl[r][kq] = a0;
    *(i32x4*)&Asl[r][kq + 32] = a1;
    *(i32x4*)&Bsl[r][kq] = b0;
    *(i32x4*)&Bsl[r][kq + 32] = b1;
    __syncthreads();

    int rr = lane & 15, ko = (lane >> 4) * 8;
#pragma unroll
    for (int k2 = 0; k2 < 2; k2++) {
      i32x4 af = *(i32x4*)&Asl[wave * 16 + rr][k2 * 32 + ko];
#pragma unroll
      for (int fn = 0; fn < 4; fn++) {
        i32x4 bf = *(i32x4*)&Bsl[fn * 16 + rr][k2 * 32 + ko];
        acc[fn] = mfma_bf16(af, bf, acc[fn]);
      }
    }
  }

  int rq = lane >> 4, rr = lane & 15;
#pragma unroll
  for (int fn = 0; fn < 4; fn++) {
#pragma unroll
    for (int rl = 0; rl < 4; rl++) {
      int i = row0 + wave * 16 + rq * 4 + rl;
      ctx16[(long long)i * 512 + h * 64 + fn * 16 + rr] = f2bf(acc[fn][rl]);
    }
  }
}

// ---------------------------------------------------------------------------
// Vertical routing.  Grid 4096.
// ---------------------------------------------------------------------------
__global__ __launch_bounds__(256) void vertical_routing_kernel(
    const unsigned short* __restrict__ u16, float* __restrict__ vV) {
  __shared__ float Ur[8 * 1024];
  __shared__ float red[4];
  __shared__ float red8[32];
  int bq = blockIdx.x;
  int t = (int)threadIdx.x;
  const unsigned short* Ub = u16 + (long long)bq * 8192;
#pragma unroll
  for (int r = 0; r < 8; r++) {
    uint2 p = *(const uint2*)&Ub[(t + 256 * r) * 4];
    Ur[(t + 256 * r) * 4 + 0] = bf2f(p.x & 0xffffu);
    Ur[(t + 256 * r) * 4 + 1] = bf2f(p.x >> 16);
    Ur[(t + 256 * r) * 4 + 2] = bf2f(p.y & 0xffffu);
    Ur[(t + 256 * r) * 4 + 3] = bf2f(p.y >> 16);
  }
  __syncthreads();

  float bh[8] = {0.f, 0.f, 0.f, 0.f, 0.f, 0.f, 0.f, 0.f};
  int k0 = t * 4;
  float4 v4 = {0.f, 0.f, 0.f, 0.f};
  for (int it = 0; it < 3; ++it) {
    float m = bh[0];
#pragma unroll
    for (int h = 1; h < 8; h++) m = fmaxf(m, bh[h]);
    float c[8], zz = 0.f;
#pragma unroll
    for (int h = 0; h < 8; h++) {
      c[h] = expf(bh[h] - m);
      zz += c[h];
    }
    float inv = 1.f / zz;
    float4 s4 = {0.f, 0.f, 0.f, 0.f};
#pragma unroll
    for (int h = 0; h < 8; h++) {
      float4 u = *(float4*)&Ur[h * 1024 + k0];
      float ch = c[h] * inv;
      s4.x = fmaf(ch, u.x, s4.x); s4.y = fmaf(ch, u.y, s4.y);
      s4.z = fmaf(ch, u.z, s4.z); s4.w = fmaf(ch, u.w, s4.w);
    }
    float sq =
        blockSum(s4.x * s4.x + s4.y * s4.y + s4.z * s4.z + s4.w * s4.w, red);
    float sc = (sq / (1.f + sq)) / sqrtf(sq + SQ_EPS);
    v4.x = sc * s4.x; v4.y = sc * s4.y; v4.z = sc * s4.z; v4.w = sc * s4.w;
    if (it < 2) {
      float p[8];
#pragma unroll
      for (int h = 0; h < 8; h++) {
        float4 u = *(float4*)&Ur[h * 1024 + k0];
        p[h] = u.x * v4.x + u.y * v4.y + u.z * v4.z + u.w * v4.w;
      }
      __syncthreads();
#pragma unroll
      for (int h = 0; h < 8; h++) {
        float w = wredSum(p[h]);
        if ((t & 63) == 0) red8[(t >> 6) * 8 + h] = w;
      }
      __syncthreads();
#pragma unroll
      for (int h = 0; h < 8; h++)
        bh[h] += red8[h] + red8[8 + h] + red8[16 + h] + red8[24 + h];
    }
  }
  *(float4*)&vV[(long long)bq * 1024 + k0] = v4;
}

// enhanced softmax.  Grid 32768.
__global__ __launch_bounds__(256) void enh_softmax_kernel(
    unsigned short* __restrict__ u16, const float* __restrict__ vV,
    const unsigned short* __restrict__ v16) {
  __shared__ float red[4];
  int idx = blockIdx.x;
  int h = idx & 7;
  int bq = idx >> 3;
  unsigned short* Urow = u16 + (long long)bq * 8192 + h * 1024;
  const float* va = vV + (long long)bq * 1024;
  const unsigned short* vb = v16 + (long long)bq * 8192 + h * 1024;
  int t = (int)threadIdx.x, k0 = t * 4;
  uint2 pu = *(const uint2*)&Urow[k0];
  float4 a = *(const float4*)&va[k0];
  uint2 pb = *(const uint2*)&vb[k0];
  float x0 = bf2f(pu.x & 0xffffu) + a.x + bf2f(pb.x & 0xffffu);
  float x1 = bf2f(pu.x >> 16) + a.y + bf2f(pb.x >> 16);
  float x2 = bf2f(pu.y & 0xffffu) + a.z + bf2f(pb.y & 0xffffu);
  float x3 = bf2f(pu.y >> 16) + a.w + bf2f(pb.y >> 16);
  float mx = blockMax(fmaxf(fmaxf(x0, x1), fmaxf(x2, x3)), red);
  float e0 = expf(x0 - mx), e1 = expf(x1 - mx), e2 = expf(x2 - mx),
        e3 = expf(x3 - mx);
  float zz = blockSum(e0 + e1 + e2 + e3, red);
  float inv = 1.f / zz;
  uint2 o = {(unsigned int)f2bf(e0 * inv) | ((unsigned int)f2bf(e1 * inv) << 16),
             (unsigned int)f2bf(e2 * inv) | ((unsigned int)f2bf(e3 * inv) << 16)};
  *(uint2*)&Urow[k0] = o;
}

// ---------------------------------------------------------------------------
extern "C" void kernel_launch(void* const* d_in, const int* in_sizes, int n_in,
                              void* d_out, int out_size, void* d_ws,
                              size_t ws_size, hipStream_t stream) {
  (void)in_sizes; (void)n_in; (void)out_size; (void)ws_size;
  const float* x = (const float*)d_in[0];
  const float* Wq = (const float*)d_in[1];
  const float* bq = (const float*)d_in[2];
  const float* Wk = (const float*)d_in[3];
  const float* bk = (const float*)d_in[4];
  const float* Wv = (const float*)d_in[5];
  const float* bv = (const float*)d_in[6];
  const float* Wo = (const float*)d_in[7];
  const float* bo = (const float*)d_in[8];
  float* out = (float*)d_out;
  float* ws = (float*)d_ws;

  unsigned short* u16a = (unsigned short*)(ws);              // 16M fl
  unsigned short* QT16 = (unsigned short*)(ws + 16777216);   // 1M fl
  unsigned short* K16 = (unsigned short*)(ws + 17825792);    // 1M fl
  unsigned short* KT16 = (unsigned short*)(ws + 18874368);   // 1M fl
  unsigned short* T16 = (unsigned short*)(ws + 19922944);    // 64K fl
  unsigned short* Y16 = (unsigned short*)(ws + 20971520);    // 1M fl
  unsigned short* Q16 = (unsigned short*)(ws + 22020096);    // 1M fl
  // Win @ 23068672 .. 39845888 (16M fl), time-multiplexed:
  float* Qf = ws + 23068672;                                 // 2M
  float* Kf = ws + 25165824;                                 // 2M
  unsigned short* V16a = (unsigned short*)(ws + 27262976);   // 1M fl
  unsigned short* sv16a = (unsigned short*)(ws + 23068672);  // 16M fl
  float* Mbufa = ws + 39845888;                              // 4M fl
  unsigned short* R16 = (unsigned short*)(ws + 39845888);    // 1M fl (after M)
  float* vVa = ws + 44040192;                                // 4M
  float* bHa = ws + 48234496;                                // 4M
  unsigned short* ctx16 = (unsigned short*)(ws + 48234496);  // overlays bHa
  unsigned short* cH16a = (unsigned short*)(ws + 52428800);  // 2M fl
  unsigned short* G16a = (unsigned short*)(ws + 54525952);   // 2M fl
  unsigned short* VT16a = (unsigned short*)(ws + 56623104);  // 1M fl
  unsigned short* WT16 = (unsigned short*)(ws + 57671680);   // 0.5M fl
  float* scl = ws + 58195968;                                // 4096
  // total 58,200,064 fl = 222 MiB

  // 1-4. prologue
  wtrans_kernel<<<dim3(8, 8, 4), 256, 0, stream>>>(Wq, Wk, Wv, Wo, WT16);
  gemm_qkv_mfma<<<dim3(8, 64, 3), 256, 0, stream>>>(x, WT16, bq, bk, bv, Qf,
                                                    Kf, Q16, K16, V16a);
  transpose16_kernel<<<dim3(16, 8, 4), 256, 0, stream>>>(V16a, VT16a, 512,
                                                         1024, 524288, 524288);
  transpose_f32_bf16_kernel<<<dim3(16, 8, 4), 256, 0, stream>>>(
      Qf, QT16, 512, 1024, 524288, 524288);
  transpose_f32_bf16_kernel<<<dim3(16, 8, 4), 256, 0, stream>>>(
      Kf, KT16, 512, 1024, 524288, 524288);

  // 5. scores (fp32) -> u16a, all batches
  gemm_scores_bf16<<<dim3(8, 8, 32), 256, 0, stream>>>(Qf, Kf, u16a);

  // 6. vertical routing, all batches
  vertical_routing_kernel<<<dim3(4096), 256, 0, stream>>>(u16a, vVa);

  // 7. factored Gram: T = (1/64)K^T K; Y = Q·T; G = Y·Q^T (+mirror)
  gemm_T_bf16<<<dim3(32), 256, 0, stream>>>(KT16, T16);
  gemm_Y_bf16<<<dim3(1, 16, 32), 256, 0, stream>>>(Q16, T16, Y16);
  gemm_YQ_bf16<<<dim3(8, 8, 4), 256, 0, stream>>>(Y16, Q16, G16a);
  mirror_G_kernel<<<dim3(16, 16, 4), 256, 0, stream>>>(G16a);

  // 8. horizontal routing iterations (all batches per stage)
  softmax_uniform_kernel<<<dim3(1024, 4), 256, 0, stream>>>(cH16a);
  gemm_M_bf16<<<dim3(16, 16, 4), 256, 0, stream>>>(cH16a, G16a, Mbufa);
  fused_scl_bupd_kernel<1><<<dim3(1024, 4), 256, 0, stream>>>(bHa, Mbufa,
                                                              cH16a);
  gemm_M_bf16<<<dim3(16, 16, 4), 256, 0, stream>>>(cH16a, G16a, Mbufa);
  fused_scl_bupd_kernel<0><<<dim3(1024, 4), 256, 0, stream>>>(bHa, Mbufa,
                                                              cH16a);
  gemm_M_bf16<<<dim3(16, 16, 4), 256, 0, stream>>>(cH16a, G16a, Mbufa);
  scldot_kernel<<<dim3(1024, 4), 256, 0, stream>>>(Mbufa, cH16a, scl);

  // 9. factored final s: R = C·Q (causal), sv = scl·0.125·R·K^T
  gemm_R_bf16<<<dim3(4, 8, 4), 256, 0, stream>>>(cH16a, QT16, R16);
  gemm_sfinal<<<dim3(16, 16, 32), 256, 0, stream>>>(R16, K16, scl, sv16a);

  // 10. enhanced + softmax -> w into u16a
  enh_softmax_kernel<<<dim3(32768), 256, 0, stream>>>(u16a, vVa, sv16a);

  // 11. ctx = w x V (bf16 out, writes over dead bHa)
  gemm_ctx_bf16<<<dim3(64, 8), 256, 0, stream>>>(u16a, VT16a, ctx16);

  // 12. out = ctx16 x Wo + bo (bf16 MFMA, Wo^T at WT16 + 3*262144)
  gemm_out_mfma<<<dim3(8, 64), 256, 0, stream>>>(ctx16, WT16 + 786432, bo,
                                                 out);
}

// Round 18
// 384.097 us; speedup vs baseline: 1.2540x; 1.0016x over previous
//
#include <hip/hip_runtime.h>
#include <math.h>

// ---------------------------------------------------------------------------
// CapsuleRoutingSelfAttention — round 18: revert to round 15 (best green,
// 384.7 us / absmax 5.92e-3).  Rounds 16/17 proved the scores kernel is
// accuracy-pinned to fp32: any bf16-decomposed MFMA scores (3- or 4-term
// split) flips ~0.4% of u values across a bf16 rounding boundary and the
// routing chain amplifies that chaotically to ~2.7e-2 (>> 9.6e-3 threshold).
//
// Structure: bf16 MFMA for qkv/G(T,Y,YQ)/M/R/sfinal/ctx/out; fp32 VALU for
// scores; factored Gram G=(1/64)SUM_h Q_h(K_h^T K_h)Q_h^T; s=0.125*(C*Q)*K^T;
// all stages batched across B=4.
// ---------------------------------------------------------------------------

#define SQ_EPS 1e-8f

typedef __attribute__((ext_vector_type(4))) int i32x4;    // 8 bf16
typedef __attribute__((ext_vector_type(4))) float f32x4;

__device__ __forceinline__ float bf2f(unsigned int u) {
  union { unsigned int i; float f; } x;
  x.i = u << 16;
  return x.f;
}
__device__ __forceinline__ unsigned short f2bf(float f) {
  union { float f; unsigned int i; } x;
  x.f = f;
  unsigned int r = x.i + 0x7fffu + ((x.i >> 16) & 1u);
  return (unsigned short)(r >> 16);
}
__device__ __forceinline__ int packbf(float a, float b) {
  return (int)((unsigned int)f2bf(a) | ((unsigned int)f2bf(b) << 16));
}

__device__ __forceinline__ f32x4 mfma_bf16(i32x4 a, i32x4 b, f32x4 c) {
  asm("v_mfma_f32_16x16x32_bf16 %0, %1, %2, %0" : "+v"(c) : "v"(a), "v"(b));
  return c;
}

__device__ __forceinline__ float wredSum(float v) {
#pragma unroll
  for (int off = 32; off > 0; off >>= 1) v += __shfl_xor(v, off);
  return v;
}
__device__ __forceinline__ float wredMax(float v) {
#pragma unroll
  for (int off = 32; off > 0; off >>= 1) v = fmaxf(v, __shfl_xor(v, off));
  return v;
}
__device__ __forceinline__ float blockSum(float v, volatile float* red) {
  v = wredSum(v);
  int wid = threadIdx.x >> 6;
  __syncthreads();
  if ((threadIdx.x & 63) == 0) red[wid] = v;
  __syncthreads();
  return red[0] + red[1] + red[2] + red[3];
}
__device__ __forceinline__ float blockMax(float v, volatile float* red) {
  v = wredMax(v);
  int wid = threadIdx.x >> 6;
  __syncthreads();
  if ((threadIdx.x & 63) == 0) red[wid] = v;
  __syncthreads();
  return fmaxf(fmaxf(red[0], red[1]), fmaxf(red[2], red[3]));
}

// ---------------------------------------------------------------------------
// W^T prep (Wq,Wk,Wv,Wo).  Grid (8, 8, 4).
// ---------------------------------------------------------------------------
__global__ __launch_bounds__(256) void wtrans_kernel(
    const float* __restrict__ Wq, const float* __restrict__ Wk,
    const float* __restrict__ Wv, const float* __restrict__ Wo,
    unsigned short* __restrict__ WT16) {
  __shared__ unsigned short T[64][72];
  int z = blockIdx.z;
  const float* src = (z == 0) ? Wq : (z == 1) ? Wk : (z == 2) ? Wv : Wo;
  unsigned short* dst = WT16 + (long long)z * 262144;
  int i0 = blockIdx.x * 64;
  int c0 = blockIdx.y * 64;
  int t = (int)threadIdx.x;
  int r = t >> 2, cq = (t & 3) * 16;
#pragma unroll
  for (int j = 0; j < 4; j++) {
    float4 v = *(const float4*)&src[(long long)(i0 + r) * 512 + c0 + cq + j * 4];
    T[r][cq + j * 4 + 0] = f2bf(v.x);
    T[r][cq + j * 4 + 1] = f2bf(v.y);
    T[r][cq + j * 4 + 2] = f2bf(v.z);
    T[r][cq + j * 4 + 3] = f2bf(v.w);
  }
  __syncthreads();
  int c = t >> 2, iq = (t & 3) * 16;
  unsigned short tmp[16];
#pragma unroll
  for (int j = 0; j < 16; j++) tmp[j] = T[iq + j][c];
  *(i32x4*)&dst[(long long)(c0 + c) * 512 + i0 + iq] = *(i32x4*)&tmp[0];
  *(i32x4*)&dst[(long long)(c0 + c) * 512 + i0 + iq + 8] = *(i32x4*)&tmp[8];
}

// ---------------------------------------------------------------------------
// QKV (bf16 MFMA): z=0 -> Qf f32 + Q16 bf16, z=1 -> Kf f32 + K16 bf16,
// z=2 -> V16 bf16.  Grid (8, 64, 3).
// ---------------------------------------------------------------------------
__global__ __launch_bounds__(256) void gemm_qkv_mfma(
    const float* __restrict__ x, const unsigned short* __restrict__ WT16,
    const float* __restrict__ bq, const float* __restrict__ bk,
    const float* __restrict__ bv, float* __restrict__ Qf,
    float* __restrict__ Kf, unsigned short* __restrict__ Q16,
    unsigned short* __restrict__ K16, unsigned short* __restrict__ V16) {
  __shared__ unsigned short Asl[64][68];
  __shared__ unsigned short Bsl[64][68];
  int z = blockIdx.z;
  const unsigned short* WT = WT16 + (long long)z * 262144;
  const float* bias = (z == 0) ? bq : (z == 1) ? bk : bv;

  int row0 = blockIdx.y * 64;
  int col0 = blockIdx.x * 64;
  int t = (int)threadIdx.x, lane = t & 63, wave = t >> 6;
  int wm = wave >> 1, wn = wave & 1;

  f32x4 acc[2][2];
#pragma unroll
  for (int i = 0; i < 2; i++)
#pragma unroll
    for (int j = 0; j < 2; j++) acc[i][j] = (f32x4){0.f, 0.f, 0.f, 0.f};

  int r = t >> 2, kq = (t & 3) * 8;
  const float* Ap = x + (long long)(row0 + r) * 512 + kq;
  const unsigned short* Bp = WT + (long long)(col0 + r) * 512 + kq;

  for (int kb = 0; kb < 512; kb += 64) {
    float4 a0 = *(const float4*)(Ap + kb);
    float4 a1 = *(const float4*)(Ap + kb + 4);
    float4 a2 = *(const float4*)(Ap + kb + 32);
    float4 a3 = *(const float4*)(Ap + kb + 36);
    i32x4 b0 = *(const i32x4*)(Bp + kb);
    i32x4 b1 = *(const i32x4*)(Bp + kb + 32);
    __syncthreads();
    i32x4 pa0 = {packbf(a0.x, a0.y), packbf(a0.z, a0.w), packbf(a1.x, a1.y),
                 packbf(a1.z, a1.w)};
    i32x4 pa1 = {packbf(a2.x, a2.y), packbf(a2.z, a2.w), packbf(a3.x, a3.y),
                 packbf(a3.z, a3.w)};
    *(i32x4*)&Asl[r][kq] = pa0;
    *(i32x4*)&Asl[r][kq + 32] = pa1;
    *(i32x4*)&Bsl[r][kq] = b0;
    *(i32x4*)&Bsl[r][kq + 32] = b1;
    __syncthreads();

    int rr = lane & 15, ko = (lane >> 4) * 8;
#pragma unroll
    for (int k2 = 0; k2 < 2; k2++) {
      i32x4 af0 = *(i32x4*)&Asl[wm * 32 + rr][k2 * 32 + ko];
      i32x4 af1 = *(i32x4*)&Asl[wm * 32 + 16 + rr][k2 * 32 + ko];
      i32x4 bf0 = *(i32x4*)&Bsl[wn * 32 + rr][k2 * 32 + ko];
      i32x4 bf1 = *(i32x4*)&Bsl[wn * 32 + 16 + rr][k2 * 32 + ko];
      acc[0][0] = mfma_bf16(af0, bf0, acc[0][0]);
      acc[0][1] = mfma_bf16(af0, bf1, acc[0][1]);
      acc[1][0] = mfma_bf16(af1, bf0, acc[1][0]);
      acc[1][1] = mfma_bf16(af1, bf1, acc[1][1]);
    }
  }

  int rq = lane >> 4, rr = lane & 15;
#pragma unroll
  for (int fm = 0; fm < 2; fm++) {
#pragma unroll
    for (int fn = 0; fn < 2; fn++) {
      int col = col0 + wn * 32 + fn * 16 + rr;
      float bb = bias[col];
#pragma unroll
      for (int rl = 0; rl < 4; rl++) {
        int row = row0 + wm * 32 + fm * 16 + rq * 4 + rl;
        float v = acc[fm][fn][rl] + bb;
        long long idx = (long long)row * 512 + col;
        if (z == 2) {
          V16[idx] = f2bf(v);
        } else if (z == 1) {
          Kf[idx] = v;
          K16[idx] = f2bf(v);
        } else {
          Qf[idx] = v;
          Q16[idx] = f2bf(v);
        }
      }
    }
  }
}

// ---------------------------------------------------------------------------
// Out-projection (bf16 MFMA).  Grid (8, 64).
// ---------------------------------------------------------------------------
__global__ __launch_bounds__(256) void gemm_out_mfma(
    const unsigned short* __restrict__ A16,
    const unsigned short* __restrict__ WoT,
    const float* __restrict__ bo, float* __restrict__ out) {
  __shared__ unsigned short Asl[64][68];
  __shared__ unsigned short Bsl[64][68];
  int row0 = blockIdx.y * 64;
  int col0 = blockIdx.x * 64;
  int t = (int)threadIdx.x, lane = t & 63, wave = t >> 6;
  int wm = wave >> 1, wn = wave & 1;

  f32x4 acc[2][2];
#pragma unroll
  for (int i = 0; i < 2; i++)
#pragma unroll
    for (int j = 0; j < 2; j++) acc[i][j] = (f32x4){0.f, 0.f, 0.f, 0.f};

  int r = t >> 2, kq = (t & 3) * 8;
  const unsigned short* Ap = A16 + (long long)(row0 + r) * 512 + kq;
  const unsigned short* Bp = WoT + (long long)(col0 + r) * 512 + kq;

  for (int kb = 0; kb < 512; kb += 64) {
    i32x4 a0 = *(const i32x4*)(Ap + kb);
    i32x4 a1 = *(const i32x4*)(Ap + kb + 32);
    i32x4 b0 = *(const i32x4*)(Bp + kb);
    i32x4 b1 = *(const i32x4*)(Bp + kb + 32);
    __syncthreads();
    *(i32x4*)&Asl[r][kq] = a0;
    *(i32x4*)&Asl[r][kq + 32] = a1;
    *(i32x4*)&Bsl[r][kq] = b0;
    *(i32x4*)&Bsl[r][kq + 32] = b1;
    __syncthreads();

    int rr = lane & 15, ko = (lane >> 4) * 8;
#pragma unroll
    for (int k2 = 0; k2 < 2; k2++) {
      i32x4 af0 = *(i32x4*)&Asl[wm * 32 + rr][k2 * 32 + ko];
      i32x4 af1 = *(i32x4*)&Asl[wm * 32 + 16 + rr][k2 * 32 + ko];
      i32x4 bf0 = *(i32x4*)&Bsl[wn * 32 + rr][k2 * 32 + ko];
      i32x4 bf1 = *(i32x4*)&Bsl[wn * 32 + 16 + rr][k2 * 32 + ko];
      acc[0][0] = mfma_bf16(af0, bf0, acc[0][0]);
      acc[0][1] = mfma_bf16(af0, bf1, acc[0][1]);
      acc[1][0] = mfma_bf16(af1, bf0, acc[1][0]);
      acc[1][1] = mfma_bf16(af1, bf1, acc[1][1]);
    }
  }

  int rq = lane >> 4, rr = lane & 15;
#pragma unroll
  for (int fm = 0; fm < 2; fm++) {
#pragma unroll
    for (int fn = 0; fn < 2; fn++) {
      int col = col0 + wn * 32 + fn * 16 + rr;
      float bb = bo[col];
#pragma unroll
      for (int rl = 0; rl < 4; rl++) {
        int row = row0 + wm * 32 + fm * 16 + rq * 4 + rl;
        out[(long long)row * 512 + col] = acc[fm][fn][rl] + bb;
      }
    }
  }
}

// ---------------------------------------------------------------------------
// sv = scl·0.125·R·K^T per head.  Grid (16, 16, 32).
// ---------------------------------------------------------------------------
__global__ __launch_bounds__(256) void gemm_sfinal(
    const unsigned short* __restrict__ R16a,
    const unsigned short* __restrict__ K16a,
    const float* __restrict__ scla, unsigned short* __restrict__ sv16a) {
  __shared__ unsigned short Asl[64][68];
  __shared__ unsigned short Bsl[64][68];
  int z = blockIdx.z;
  int b = z >> 3, h = z & 7;
  const unsigned short* A16 = R16a + (long long)b * 524288;
  const unsigned short* Bm = K16a + (long long)b * 524288;
  const float* scl = scla + b * 1024;
  unsigned short* sv = sv16a + (long long)b * 8388608;
  int row0 = blockIdx.y * 64;
  int col0 = blockIdx.x * 64;
  int t = (int)threadIdx.x, lane = t & 63, wave = t >> 6;
  int wm = wave >> 1, wn = wave & 1;

  f32x4 acc[2][2];
#pragma unroll
  for (int i = 0; i < 2; i++)
#pragma unroll
    for (int j = 0; j < 2; j++) acc[i][j] = (f32x4){0.f, 0.f, 0.f, 0.f};

  int r = t >> 2, kq = (t & 3) * 8;
  const unsigned short* Ap = A16 + (long long)(row0 + r) * 512 + h * 64 + kq;
  const unsigned short* Bp = Bm + (long long)(col0 + r) * 512 + h * 64 + kq;

  {
    i32x4 a0 = *(const i32x4*)(Ap);
    i32x4 a1 = *(const i32x4*)(Ap + 32);
    i32x4 b0 = *(const i32x4*)(Bp);
    i32x4 b1 = *(const i32x4*)(Bp + 32);
    __syncthreads();
    *(i32x4*)&Asl[r][kq] = a0;
    *(i32x4*)&Asl[r][kq + 32] = a1;
    *(i32x4*)&Bsl[r][kq] = b0;
    *(i32x4*)&Bsl[r][kq + 32] = b1;
    __syncthreads();

    int rr = lane & 15, ko = (lane >> 4) * 8;
#pragma unroll
    for (int k2 = 0; k2 < 2; k2++) {
      i32x4 af0 = *(i32x4*)&Asl[wm * 32 + rr][k2 * 32 + ko];
      i32x4 af1 = *(i32x4*)&Asl[wm * 32 + 16 + rr][k2 * 32 + ko];
      i32x4 bf0 = *(i32x4*)&Bsl[wn * 32 + rr][k2 * 32 + ko];
      i32x4 bf1 = *(i32x4*)&Bsl[wn * 32 + 16 + rr][k2 * 32 + ko];
      acc[0][0] = mfma_bf16(af0, bf0, acc[0][0]);
      acc[0][1] = mfma_bf16(af0, bf1, acc[0][1]);
      acc[1][0] = mfma_bf16(af1, bf0, acc[1][0]);
      acc[1][1] = mfma_bf16(af1, bf1, acc[1][1]);
    }
  }

  int rq = lane >> 4, rr = lane & 15;
#pragma unroll
  for (int fm = 0; fm < 2; fm++) {
#pragma unroll
    for (int fn = 0; fn < 2; fn++) {
      int col = col0 + wn * 32 + fn * 16 + rr;
#pragma unroll
      for (int rl = 0; rl < 4; rl++) {
        int row = row0 + wm * 32 + fm * 16 + rq * 4 + rl;
        sv[(long long)row * 8192 + h * 1024 + col] =
            f2bf(0.125f * scl[row] * acc[fm][fn][rl]);
      }
    }
  }
}

// ---------------------------------------------------------------------------
// Y = Q·T per head (B = T16 row-major ldb=64).  Grid (1, 16, 32).
// ---------------------------------------------------------------------------
__global__ __launch_bounds__(256) void gemm_Y_bf16(
    const unsigned short* __restrict__ Q16a,
    const unsigned short* __restrict__ T16a,
    unsigned short* __restrict__ Y16a) {
  __shared__ unsigned short Asl[64][68];
  __shared__ unsigned short Bsl[64][68];
  int z = blockIdx.z;
  int b = z >> 3, h = z & 7;
  const unsigned short* A16 = Q16a + (long long)b * 524288;
  const unsigned short* Tz = T16a + (long long)z * 4096;
  unsigned short* Y = Y16a + (long long)b * 524288;
  int row0 = blockIdx.y * 64;
  int t = (int)threadIdx.x, lane = t & 63, wave = t >> 6;
  int wm = wave >> 1, wn = wave & 1;

  f32x4 acc[2][2];
#pragma unroll
  for (int i = 0; i < 2; i++)
#pragma unroll
    for (int j = 0; j < 2; j++) acc[i][j] = (f32x4){0.f, 0.f, 0.f, 0.f};

  int r = t >> 2, kq = (t & 3) * 8;
  const unsigned short* Ap = A16 + (long long)(row0 + r) * 512 + h * 64 + kq;
  const unsigned short* Bp = Tz + (long long)r * 64 + kq;

  {
    i32x4 a0 = *(const i32x4*)(Ap);
    i32x4 a1 = *(const i32x4*)(Ap + 32);
    i32x4 b0 = *(const i32x4*)(Bp);
    i32x4 b1 = *(const i32x4*)(Bp + 32);
    __syncthreads();
    *(i32x4*)&Asl[r][kq] = a0;
    *(i32x4*)&Asl[r][kq + 32] = a1;
    *(i32x4*)&Bsl[r][kq] = b0;
    *(i32x4*)&Bsl[r][kq + 32] = b1;
    __syncthreads();

    int rr = lane & 15, ko = (lane >> 4) * 8;
#pragma unroll
    for (int k2 = 0; k2 < 2; k2++) {
      i32x4 af0 = *(i32x4*)&Asl[wm * 32 + rr][k2 * 32 + ko];
      i32x4 af1 = *(i32x4*)&Asl[wm * 32 + 16 + rr][k2 * 32 + ko];
      i32x4 bf0 = *(i32x4*)&Bsl[wn * 32 + rr][k2 * 32 + ko];
      i32x4 bf1 = *(i32x4*)&Bsl[wn * 32 + 16 + rr][k2 * 32 + ko];
      acc[0][0] = mfma_bf16(af0, bf0, acc[0][0]);
      acc[0][1] = mfma_bf16(af0, bf1, acc[0][1]);
      acc[1][0] = mfma_bf16(af1, bf0, acc[1][0]);
      acc[1][1] = mfma_bf16(af1, bf1, acc[1][1]);
    }
  }

  int rq = lane >> 4, rr = lane & 15;
#pragma unroll
  for (int fm = 0; fm < 2; fm++) {
#pragma unroll
    for (int fn = 0; fn < 2; fn++) {
      int col = wn * 32 + fn * 16 + rr;
#pragma unroll
      for (int rl = 0; rl < 4; rl++) {
        int row = row0 + wm * 32 + fm * 16 + rq * 4 + rl;
        Y[(long long)row * 512 + h * 64 + col] = f2bf(acc[fm][fn][rl]);
      }
    }
  }
}

// ---------------------------------------------------------------------------
// Scores (fp32 compute, bf16 out) — accuracy-pinned fp32.  Grid (8, 8, 32).
// ---------------------------------------------------------------------------
__global__ __launch_bounds__(256) void gemm_scores_bf16(
    const float* __restrict__ Qf, const float* __restrict__ Kf,
    unsigned short* __restrict__ u16a) {
  __shared__ float As[8][132];
  __shared__ float Bs[8][132];
  int z = blockIdx.z;
  int b = z >> 3, h = z & 7;
  const float* A = Qf + (long long)b * 524288 + h * 64;
  const float* B = Kf + (long long)b * 524288 + h * 64;
  unsigned short* C16 = u16a + (long long)b * 8388608 + h * 1024;

  int row0 = blockIdx.y * 128;
  int col0 = blockIdx.x * 128;
  int tid = (int)threadIdx.x;
  int tx = tid & 15, ty = tid >> 4;
  int arow = tid >> 1;
  int akc = (tid & 1) * 4;

  float acc[8][8];
#pragma unroll
  for (int i = 0; i < 8; i++)
#pragma unroll
    for (int j = 0; j < 8; j++) acc[i][j] = 0.f;

  const float* Aptr = A + (long long)(row0 + arow) * 512 + akc;
  const float* Bptr = B + (long long)(col0 + arow) * 512 + akc;

  for (int kb = 0; kb < 64; kb += 8) {
    float4 av = *(const float4*)(Aptr + kb);
    float4 bv = *(const float4*)(Bptr + kb);
    __syncthreads();
    As[akc + 0][arow] = av.x; As[akc + 1][arow] = av.y;
    As[akc + 2][arow] = av.z; As[akc + 3][arow] = av.w;
    Bs[akc + 0][arow] = bv.x; Bs[akc + 1][arow] = bv.y;
    Bs[akc + 2][arow] = bv.z; Bs[akc + 3][arow] = bv.w;
    __syncthreads();

#pragma unroll
    for (int k = 0; k < 8; k++) {
      float a[8], b2[8];
#pragma unroll
      for (int c = 0; c < 2; c++) {
        float4 q = *(float4*)&As[k][ty * 8 + c * 4];
        a[c * 4 + 0] = q.x; a[c * 4 + 1] = q.y;
        a[c * 4 + 2] = q.z; a[c * 4 + 3] = q.w;
      }
#pragma unroll
      for (int c = 0; c < 2; c++) {
        float4 q = *(float4*)&Bs[k][c * 64 + tx * 4];
        b2[c * 4 + 0] = q.x; b2[c * 4 + 1] = q.y;
        b2[c * 4 + 2] = q.z; b2[c * 4 + 3] = q.w;
      }
#pragma unroll
      for (int i = 0; i < 8; i++)
#pragma unroll
        for (int j = 0; j < 8; j++) acc[i][j] = fmaf(a[i], b2[j], acc[i][j]);
    }
  }

#pragma unroll
  for (int i = 0; i < 8; i++) {
    long long r = row0 + ty * 8 + i;
#pragma unroll
    for (int c = 0; c < 2; c++) {
      int col = col0 + c * 64 + tx * 4;
      unsigned int lo = (unsigned int)f2bf(0.125f * acc[i][c * 4 + 0]) |
                        ((unsigned int)f2bf(0.125f * acc[i][c * 4 + 1]) << 16);
      unsigned int hi = (unsigned int)f2bf(0.125f * acc[i][c * 4 + 2]) |
                        ((unsigned int)f2bf(0.125f * acc[i][c * 4 + 3]) << 16);
      uint2 o = {lo, hi};
      *(uint2*)&C16[r * 8192 + col] = o;
    }
  }
}

// ---------------------------------------------------------------------------
// bf16 transpose, z-batched.
// ---------------------------------------------------------------------------
__global__ __launch_bounds__(256) void transpose16_kernel(
    const unsigned short* __restrict__ src, unsigned short* __restrict__ dst,
    int ldS, int ldD, long long zsS, long long zsD) {
  __shared__ unsigned short T[64][72];
  src += (long long)blockIdx.z * zsS;
  dst += (long long)blockIdx.z * zsD;
  int i0 = blockIdx.x * 64;
  int c0 = blockIdx.y * 64;
  int t = (int)threadIdx.x;
  int r = t >> 2, cq = (t & 3) * 16;
  i32x4 v0 = *(const i32x4*)&src[(long long)(i0 + r) * ldS + c0 + cq];
  i32x4 v1 = *(const i32x4*)&src[(long long)(i0 + r) * ldS + c0 + cq + 8];
  *(i32x4*)&T[r][cq] = v0;
  *(i32x4*)&T[r][cq + 8] = v1;
  __syncthreads();
  int c = t >> 2, iq = (t & 3) * 16;
  unsigned short tmp[16];
#pragma unroll
  for (int j = 0; j < 16; j++) tmp[j] = T[iq + j][c];
  *(i32x4*)&dst[(long long)(c0 + c) * ldD + i0 + iq] = *(i32x4*)&tmp[0];
  *(i32x4*)&dst[(long long)(c0 + c) * ldD + i0 + iq + 8] = *(i32x4*)&tmp[8];
}

// f32 -> bf16 transpose.  Grid (16, 8, 4).
__global__ __launch_bounds__(256) void transpose_f32_bf16_kernel(
    const float* __restrict__ src, unsigned short* __restrict__ dst,
    int ldS, int ldD, long long zsS, long long zsD) {
  __shared__ unsigned short T[64][72];
  src += (long long)blockIdx.z * zsS;
  dst += (long long)blockIdx.z * zsD;
  int i0 = blockIdx.x * 64;
  int c0 = blockIdx.y * 64;
  int t = (int)threadIdx.x;
  int r = t >> 2, cq = (t & 3) * 16;
#pragma unroll
  for (int j = 0; j < 4; j++) {
    float4 v = *(const float4*)&src[(long long)(i0 + r) * ldS + c0 + cq + j * 4];
    T[r][cq + j * 4 + 0] = f2bf(v.x);
    T[r][cq + j * 4 + 1] = f2bf(v.y);
    T[r][cq + j * 4 + 2] = f2bf(v.z);
    T[r][cq + j * 4 + 3] = f2bf(v.w);
  }
  __syncthreads();
  int c = t >> 2, iq = (t & 3) * 16;
  unsigned short tmp[16];
#pragma unroll
  for (int j = 0; j < 16; j++) tmp[j] = T[iq + j][c];
  *(i32x4*)&dst[(long long)(c0 + c) * ldD + i0 + iq] = *(i32x4*)&tmp[0];
  *(i32x4*)&dst[(long long)(c0 + c) * ldD + i0 + iq + 8] = *(i32x4*)&tmp[8];
}

// ---------------------------------------------------------------------------
// T_h = (1/64)·K_h^T·K_h (A=B=KT rows, Kend=1024).  Grid (32).
// ---------------------------------------------------------------------------
__global__ __launch_bounds__(256) void gemm_T_bf16(
    const unsigned short* __restrict__ KT16a,
    unsigned short* __restrict__ T16a) {
  int z = blockIdx.x;
  int b = z >> 3, h = z & 7;
  const unsigned short* KT =
      KT16a + (long long)b * 524288 + (long long)h * 65536;
  __shared__ unsigned short Asl[64][64];
  __shared__ unsigned short Bsl[64][64];
  int t = (int)threadIdx.x, lane = t & 63, wave = t >> 6;
  int wm = wave >> 1, wn = wave & 1;

  f32x4 acc[2][2];
#pragma unroll
  for (int i = 0; i < 2; i++)
#pragma unroll
    for (int j = 0; j < 2; j++) acc[i][j] = (f32x4){0.f, 0.f, 0.f, 0.f};

  int r = t >> 2, c0 = t & 3;
  int sw0 = ((c0 ^ (r & 7))) * 8;
  int sw1 = (((c0 + 4) ^ (r & 7))) * 8;
  const unsigned short* Ap = KT + (long long)r * 1024 + c0 * 8;

  for (int kb = 0; kb < 1024; kb += 64) {
    i32x4 a0 = *(const i32x4*)(Ap + kb);
    i32x4 a1 = *(const i32x4*)(Ap + kb + 32);
    __syncthreads();
    *(i32x4*)&Asl[r][sw0] = a0;
    *(i32x4*)&Asl[r][sw1] = a1;
    *(i32x4*)&Bsl[r][sw0] = a0;
    *(i32x4*)&Bsl[r][sw1] = a1;
    __syncthreads();

    int rr = lane & 15, co = lane >> 4;
#pragma unroll
    for (int k2 = 0; k2 < 2; k2++) {
      int ch = ((k2 * 4 + co) ^ (rr & 7)) * 8;
      i32x4 af0 = *(i32x4*)&Asl[wm * 32 + rr][ch];
      i32x4 af1 = *(i32x4*)&Asl[wm * 32 + 16 + rr][ch];
      i32x4 bf0 = *(i32x4*)&Bsl[wn * 32 + rr][ch];
      i32x4 bf1 = *(i32x4*)&Bsl[wn * 32 + 16 + rr][ch];
      acc[0][0] = mfma_bf16(af0, bf0, acc[0][0]);
      acc[0][1] = mfma_bf16(af0, bf1, acc[0][1]);
      acc[1][0] = mfma_bf16(af1, bf0, acc[1][0]);
      acc[1][1] = mfma_bf16(af1, bf1, acc[1][1]);
    }
  }

  unsigned short* Tz = T16a + (long long)z * 4096;
  int rq = lane >> 4, rr = lane & 15;
#pragma unroll
  for (int fm = 0; fm < 2; fm++) {
#pragma unroll
    for (int fn = 0; fn < 2; fn++) {
      int j = wn * 32 + fn * 16 + rr;
#pragma unroll
      for (int rl = 0; rl < 4; rl++) {
        int i = wm * 32 + fm * 16 + rq * 4 + rl;
        Tz[i * 64 + j] = f2bf(0.015625f * acc[fm][fn][rl]);
      }
    }
  }
}

// ---------------------------------------------------------------------------
// G = Y·Q^T, lower-triangle 128-blocks (K=512, bf16 out).  Grid (8, 8, 4).
// ---------------------------------------------------------------------------
__global__ __launch_bounds__(256) void gemm_YQ_bf16(
    const unsigned short* __restrict__ Y16a,
    const unsigned short* __restrict__ Q16a,
    unsigned short* __restrict__ G16a) {
  __shared__ unsigned short Alds[128][72];
  __shared__ unsigned short Blds[128][72];
  int row0 = blockIdx.y * 128;
  int col0 = blockIdx.x * 128;
  if (col0 > row0) return;
  int b = blockIdx.z;
  const unsigned short* Y = Y16a + (long long)b * 524288;
  const unsigned short* Q = Q16a + (long long)b * 524288;
  unsigned short* G = G16a + (long long)b * 1048576;
  int t = (int)threadIdx.x, lane = t & 63, wave = t >> 6;
  int wm = wave >> 1, wn = wave & 1;

  f32x4 acc[4][4];
#pragma unroll
  for (int i = 0; i < 4; i++)
#pragma unroll
    for (int j = 0; j < 4; j++) acc[i][j] = (f32x4){0.f, 0.f, 0.f, 0.f};

  int ar = t >> 2;
  int aq = (t & 3) * 16;
  const unsigned short* Ap = Y + (long long)(row0 + ar) * 512 + aq;
  const unsigned short* Ap2 = Ap + 64LL * 512;
  const unsigned short* Bp = Q + (long long)(col0 + ar) * 512 + aq;
  const unsigned short* Bp2 = Bp + 64LL * 512;

  for (int kb = 0; kb < 512; kb += 64) {
    i32x4 a0 = *(const i32x4*)(Ap + kb);
    i32x4 a1 = *(const i32x4*)(Ap + kb + 8);
    i32x4 a2 = *(const i32x4*)(Ap2 + kb);
    i32x4 a3 = *(const i32x4*)(Ap2 + kb + 8);
    i32x4 b0 = *(const i32x4*)(Bp + kb);
    i32x4 b1 = *(const i32x4*)(Bp + kb + 8);
    i32x4 b2 = *(const i32x4*)(Bp2 + kb);
    i32x4 b3 = *(const i32x4*)(Bp2 + kb + 8);
    __syncthreads();
    *(i32x4*)&Alds[ar][aq] = a0;
    *(i32x4*)&Alds[ar][aq + 8] = a1;
    *(i32x4*)&Alds[ar + 64][aq] = a2;
    *(i32x4*)&Alds[ar + 64][aq + 8] = a3;
    *(i32x4*)&Blds[ar][aq] = b0;
    *(i32x4*)&Blds[ar][aq + 8] = b1;
    *(i32x4*)&Blds[ar + 64][aq] = b2;
    *(i32x4*)&Blds[ar + 64][aq + 8] = b3;
    __syncthreads();

    int rr = lane & 15, ko = (lane >> 4) * 8;
#pragma unroll
    for (int k2 = 0; k2 < 2; k2++) {
      i32x4 af[4], bfv[4];
#pragma unroll
      for (int fm = 0; fm < 4; fm++)
        af[fm] = *(i32x4*)&Alds[wm * 64 + fm * 16 + rr][k2 * 32 + ko];
#pragma unroll
      for (int fn = 0; fn < 4; fn++)
        bfv[fn] = *(i32x4*)&Blds[wn * 64 + fn * 16 + rr][k2 * 32 + ko];
#pragma unroll
      for (int fm = 0; fm < 4; fm++)
#pragma unroll
        for (int fn = 0; fn < 4; fn++)
          acc[fm][fn] = mfma_bf16(af[fm], bfv[fn], acc[fm][fn]);
    }
  }

  int rq = lane >> 4, rr = lane & 15;
#pragma unroll
  for (int fm = 0; fm < 4; fm++) {
#pragma unroll
    for (int fn = 0; fn < 4; fn++) {
      int col = col0 + wn * 64 + fn * 16 + rr;
#pragma unroll
      for (int r = 0; r < 4; r++) {
        int row = row0 + wm * 64 + fm * 16 + rq * 4 + r;
        G[(long long)row * 1024 + col] = f2bf(acc[fm][fn][r]);
      }
    }
  }
}

// Mirror lower 128-blocks to upper (transpose16 body).  Grid (16, 16, 4).
__global__ __launch_bounds__(256) void mirror_G_kernel(
    unsigned short* __restrict__ G16a) {
  int txl = blockIdx.x, tyl = blockIdx.y;
  if ((txl >> 1) >= (tyl >> 1)) return;
  unsigned short* G = G16a + (long long)blockIdx.z * 1048576;
  __shared__ unsigned short T[64][72];
  int i0 = tyl * 64;
  int c0 = txl * 64;
  int t = (int)threadIdx.x;
  int r = t >> 2, cq = (t & 3) * 16;
  i32x4 v0 = *(const i32x4*)&G[(long long)(i0 + r) * 1024 + c0 + cq];
  i32x4 v1 = *(const i32x4*)&G[(long long)(i0 + r) * 1024 + c0 + cq + 8];
  *(i32x4*)&T[r][cq] = v0;
  *(i32x4*)&T[r][cq + 8] = v1;
  __syncthreads();
  int c = t >> 2, iq = (t & 3) * 16;
  unsigned short tmp[16];
#pragma unroll
  for (int j = 0; j < 16; j++) tmp[j] = T[iq + j][c];
  *(i32x4*)&G[(long long)(c0 + c) * 1024 + i0 + iq] = *(i32x4*)&tmp[0];
  *(i32x4*)&G[(long long)(c0 + c) * 1024 + i0 + iq + 8] = *(i32x4*)&tmp[8];
}

// ---------------------------------------------------------------------------
// M = C·G (bf16 MFMA, z-batched).
// ---------------------------------------------------------------------------
__global__ __launch_bounds__(256) void gemm_M_bf16(
    const unsigned short* __restrict__ Ca, const unsigned short* __restrict__ Ga,
    float* __restrict__ Ma) {
  int row0 = blockIdx.y * 64;
  int col0 = blockIdx.x * 64;
  if (col0 > row0) return;
  int b = blockIdx.z;
  const unsigned short* C = Ca + (long long)b * 1048576;
  const unsigned short* G = Ga + (long long)b * 1048576;
  float* M = Ma + (long long)b * 1048576;
  int Kend = row0 + 64;
  __shared__ unsigned short Asl[64][64];
  __shared__ unsigned short Bsl[64][64];
  int t = (int)threadIdx.x, lane = t & 63, wave = t >> 6;
  int wm = wave >> 1, wn = wave & 1;

  f32x4 acc[2][2];
#pragma unroll
  for (int i = 0; i < 2; i++)
#pragma unroll
    for (int j = 0; j < 2; j++) acc[i][j] = (f32x4){0.f, 0.f, 0.f, 0.f};

  int r = t >> 2, c0 = t & 3;
  int sw0 = ((c0 ^ (r & 7))) * 8;
  int sw1 = (((c0 + 4) ^ (r & 7))) * 8;
  const unsigned short* Ap = C + (long long)(row0 + r) * 1024 + c0 * 8;
  const unsigned short* Bp = G + (long long)(col0 + r) * 1024 + c0 * 8;

  for (int kb = 0; kb < Kend; kb += 64) {
    i32x4 a0 = *(const i32x4*)(Ap + kb);
    i32x4 a1 = *(const i32x4*)(Ap + kb + 32);
    i32x4 b0 = *(const i32x4*)(Bp + kb);
    i32x4 b1 = *(const i32x4*)(Bp + kb + 32);
    __syncthreads();
    *(i32x4*)&Asl[r][sw0] = a0;
    *(i32x4*)&Asl[r][sw1] = a1;
    *(i32x4*)&Bsl[r][sw0] = b0;
    *(i32x4*)&Bsl[r][sw1] = b1;
    __syncthreads();

    int rr = lane & 15, co = lane >> 4;
#pragma unroll
    for (int k2 = 0; k2 < 2; k2++) {
      int ch = ((k2 * 4 + co) ^ (rr & 7)) * 8;
      i32x4 af0 = *(i32x4*)&Asl[wm * 32 + rr][ch];
      i32x4 af1 = *(i32x4*)&Asl[wm * 32 + 16 + rr][ch];
      i32x4 bf0 = *(i32x4*)&Bsl[wn * 32 + rr][ch];
      i32x4 bf1 = *(i32x4*)&Bsl[wn * 32 + 16 + rr][ch];
      acc[0][0] = mfma_bf16(af0, bf0, acc[0][0]);
      acc[0][1] = mfma_bf16(af0, bf1, acc[0][1]);
      acc[1][0] = mfma_bf16(af1, bf0, acc[1][0]);
      acc[1][1] = mfma_bf16(af1, bf1, acc[1][1]);
    }
  }

  int rq = lane >> 4, rr = lane & 15;
#pragma unroll
  for (int fm = 0; fm < 2; fm++) {
#pragma unroll
    for (int fn = 0; fn < 2; fn++) {
      int j = col0 + wn * 32 + fn * 16 + rr;
#pragma unroll
      for (int rl = 0; rl < 4; rl++) {
        int i = row0 + wm * 32 + fm * 16 + rq * 4 + rl;
        M[(long long)i * 1024 + j] = acc[fm][fn][rl];
      }
    }
  }
}

// ---------------------------------------------------------------------------
// Fused scldot + b-update + causal softmax (it0/it1).  Grid (1024, 4).
// ---------------------------------------------------------------------------
template <int INIT>
__global__ __launch_bounds__(256) void fused_scl_bupd_kernel(
    float* __restrict__ bHa, const float* __restrict__ Ma,
    unsigned short* __restrict__ cH16a) {
  __shared__ float red[4];
  int i = blockIdx.x;
  int b = blockIdx.y;
  float* bH = bHa + (long long)b * 1048576;
  const float* M = Ma + (long long)b * 1048576;
  unsigned short* cH16 = cH16a + (long long)b * 1048576;
  long long base = (long long)i * 1024;
  int t = (int)threadIdx.x, k0 = t * 4;
  float4 m = *(const float4*)&M[base + k0];
  uint2 pc = *(const uint2*)&cH16[base + k0];
  float c0 = bf2f(pc.x & 0xffffu), c1 = bf2f(pc.x >> 16);
  float c2 = bf2f(pc.y & 0xffffu), c3 = bf2f(pc.y >> 16);
  bool m0 = (k0 + 0) <= i, m1 = (k0 + 1) <= i, m2 = (k0 + 2) <= i,
       m3 = (k0 + 3) <= i;
  float acc = 0.f;
  if (m0) acc += c0 * m.x;
  if (m1) acc += c1 * m.y;
  if (m2) acc += c2 * m.z;
  if (m3) acc += c3 * m.w;
  float ssq = blockSum(acc, red);
  float sc = (ssq / (1.f + ssq)) / sqrtf(ssq + SQ_EPS);

  float4 x;
  if (INIT) x = (float4){0.f, 0.f, 0.f, 0.f};
  else x = *(const float4*)&bH[base + k0];
  if (m0) x.x += sc * m.x;
  if (m1) x.y += sc * m.y;
  if (m2) x.z += sc * m.z;
  if (m3) x.w += sc * m.w;
  *(float4*)&bH[base + k0] = x;
  float mx = -3.0e38f;
  if (m0) mx = fmaxf(mx, x.x);
  if (m1) mx = fmaxf(mx, x.y);
  if (m2) mx = fmaxf(mx, x.z);
  if (m3) mx = fmaxf(mx, x.w);
  mx = blockMax(mx, red);
  float e0 = m0 ? expf(x.x - mx) : 0.f;
  float e1 = m1 ? expf(x.y - mx) : 0.f;
  float e2 = m2 ? expf(x.z - mx) : 0.f;
  float e3 = m3 ? expf(x.w - mx) : 0.f;
  float zz = blockSum(e0 + e1 + e2 + e3, red);
  float inv = 1.f / zz;
  uint2 o = {(unsigned int)f2bf(e0 * inv) | ((unsigned int)f2bf(e1 * inv) << 16),
             (unsigned int)f2bf(e2 * inv) | ((unsigned int)f2bf(e3 * inv) << 16)};
  *(uint2*)&cH16[base + k0] = o;
}

// ||s_i||^2 -> scl (it2).  Grid (1024, 4).
__global__ __launch_bounds__(256) void scldot_kernel(
    const float* __restrict__ Ma, const unsigned short* __restrict__ Ca,
    float* __restrict__ scl) {
  __shared__ float red[4];
  int i = blockIdx.x;
  int b = blockIdx.y;
  const float* M = Ma + (long long)b * 1048576;
  const unsigned short* C = Ca + (long long)b * 1048576;
  int t = (int)threadIdx.x, j0 = t * 4;
  long long base = (long long)i * 1024;
  float4 m = *(const float4*)&M[base + j0];
  uint2 pc = *(const uint2*)&C[base + j0];
  float c0 = bf2f(pc.x & 0xffffu), c1 = bf2f(pc.x >> 16);
  float c2 = bf2f(pc.y & 0xffffu), c3 = bf2f(pc.y >> 16);
  float acc = 0.f;
  if (j0 + 0 <= i) acc += c0 * m.x;
  if (j0 + 1 <= i) acc += c1 * m.y;
  if (j0 + 2 <= i) acc += c2 * m.z;
  if (j0 + 3 <= i) acc += c3 * m.w;
  float ssq = blockSum(acc, red);
  if (t == 0) scl[b * 1024 + i] = (ssq / (1.f + ssq)) / sqrtf(ssq + SQ_EPS);
}

// it=0 coupling.  Grid (1024, 4).
__global__ __launch_bounds__(256) void softmax_uniform_kernel(
    unsigned short* __restrict__ cH16a) {
  int i = blockIdx.x;
  int b = blockIdx.y;
  unsigned short* cH16 = cH16a + (long long)b * 1048576;
  int t = (int)threadIdx.x, k0 = t * 4;
  unsigned short c = f2bf(1.f / (float)(i + 1));
  unsigned short e0 = (k0 + 0) <= i ? c : (unsigned short)0;
  unsigned short e1 = (k0 + 1) <= i ? c : (unsigned short)0;
  unsigned short e2 = (k0 + 2) <= i ? c : (unsigned short)0;
  unsigned short e3 = (k0 + 3) <= i ? c : (unsigned short)0;
  uint2 o = {(unsigned int)e0 | ((unsigned int)e1 << 16),
             (unsigned int)e2 | ((unsigned int)e3 << 16)};
  *(uint2*)&cH16[(long long)i * 1024 + k0] = o;
}

// ---------------------------------------------------------------------------
// R = C·Q (causal).  Grid (4, 8, 4).
// ---------------------------------------------------------------------------
__global__ __launch_bounds__(256) void gemm_R_bf16(
    const unsigned short* __restrict__ Ca, const unsigned short* __restrict__ QTa,
    unsigned short* __restrict__ R16a) {
  __shared__ unsigned short Alds[128][32];
  __shared__ unsigned short Blds[128][32];
  int b = blockIdx.z;
  const unsigned short* Abf = Ca + (long long)b * 1048576;
  const unsigned short* BT = QTa + (long long)b * 524288;
  unsigned short* Cout = R16a + (long long)b * 524288;
  int rowblk = 7 - (int)blockIdx.y;
  int row0 = rowblk * 128;
  int col0 = blockIdx.x * 128;
  int t = (int)threadIdx.x, lane = t & 63, wave = t >> 6;
  int wm = wave >> 1, wn = wave & 1;
  int Kend = row0 + 128;

  f32x4 acc[4][4];
#pragma unroll
  for (int i = 0; i < 4; i++)
#pragma unroll
    for (int j = 0; j < 4; j++) acc[i][j] = (f32x4){0.f, 0.f, 0.f, 0.f};

  int ar = t >> 2;
  int aq = (t & 3) * 8;

  for (int kb = 0; kb < Kend; kb += 32) {
    i32x4 a0 = *(const i32x4*)&Abf[(long long)(row0 + ar) * 1024 + kb + aq];
    i32x4 a1 = *(const i32x4*)&Abf[(long long)(row0 + ar + 64) * 1024 + kb + aq];
    i32x4 b0 = *(const i32x4*)&BT[(long long)(col0 + ar) * 1024 + kb + aq];
    i32x4 b1 = *(const i32x4*)&BT[(long long)(col0 + ar + 64) * 1024 + kb + aq];
    __syncthreads();
    *(i32x4*)&Alds[ar][aq] = a0;
    *(i32x4*)&Alds[ar + 64][aq] = a1;
    *(i32x4*)&Blds[ar][aq] = b0;
    *(i32x4*)&Blds[ar + 64][aq] = b1;
    __syncthreads();

    int rr = lane & 15, koff = (lane >> 4) * 8;
    i32x4 af[4], bfv[4];
#pragma unroll
    for (int fm = 0; fm < 4; fm++)
      af[fm] = *(i32x4*)&Alds[wm * 64 + fm * 16 + rr][koff];
#pragma unroll
    for (int fn = 0; fn < 4; fn++)
      bfv[fn] = *(i32x4*)&Blds[wn * 64 + fn * 16 + rr][koff];
#pragma unroll
    for (int fm = 0; fm < 4; fm++)
#pragma unroll
      for (int fn = 0; fn < 4; fn++)
        acc[fm][fn] = mfma_bf16(af[fm], bfv[fn], acc[fm][fn]);
  }

  int rq = lane >> 4, rr = lane & 15;
#pragma unroll
  for (int fm = 0; fm < 4; fm++) {
#pragma unroll
    for (int fn = 0; fn < 4; fn++) {
      int col = col0 + wn * 64 + fn * 16 + rr;
#pragma unroll
      for (int r = 0; r < 4; r++) {
        int row = row0 + wm * 64 + fm * 16 + rq * 4 + r;
        Cout[(long long)row * 512 + col] = f2bf(acc[fm][fn][r]);
      }
    }
  }
}

// ---------------------------------------------------------------------------
// ctx (bf16 MFMA, bf16 out).  Grid (64, 8).
// ---------------------------------------------------------------------------
__global__ __launch_bounds__(256) void gemm_ctx_bf16(
    const unsigned short* __restrict__ w16,
    const unsigned short* __restrict__ VTa, unsigned short* __restrict__ ctx16) {
  int row0 = blockIdx.x * 64;
  int b = blockIdx.x >> 4;
  int h = blockIdx.y;
  const unsigned short* VT = VTa + (long long)b * 524288;
  __shared__ unsigned short Asl[64][68];
  __shared__ unsigned short Bsl[64][68];
  int t = (int)threadIdx.x, lane = t & 63, wave = t >> 6;

  f32x4 acc[4];
#pragma unroll
  for (int i = 0; i < 4; i++) acc[i] = (f32x4){0.f, 0.f, 0.f, 0.f};

  int r = t >> 2, kq = (t & 3) * 8;
  const unsigned short* Ap = w16 + (long long)(row0 + r) * 8192 + h * 1024 + kq;
  const unsigned short* Bp = VT + (long long)(h * 64 + r) * 1024 + kq;

  for (int kb = 0; kb < 1024; kb += 64) {
    i32x4 a0 = *(const i32x4*)(Ap + kb);
    i32x4 a1 = *(const i32x4*)(Ap + kb + 32);
    i32x4 b0 = *(const i32x4*)(Bp + kb);
    i32x4 b1 = *(const i32x4*)(Bp + kb + 32);
    __syncthreads();
    *(i32x4*)&Asl[r][kq] = a0;
    *(i32x4*)&Asl[r][kq + 32] = a1;
    *(i32x4*)&Bsl[r][kq] = b0;
    *(i32x4*)&Bsl[r][kq + 32] = b1;
    __syncthreads();

    int rr = lane & 15, ko = (lane >> 4) * 8;
#pragma unroll
    for (int k2 = 0; k2 < 2; k2++) {
      i32x4 af = *(i32x4*)&Asl[wave * 16 + rr][k2 * 32 + ko];
#pragma unroll
      for (int fn = 0; fn < 4; fn++) {
        i32x4 bf = *(i32x4*)&Bsl[fn * 16 + rr][k2 * 32 + ko];
        acc[fn] = mfma_bf16(af, bf, acc[fn]);
      }
    }
  }

  int rq = lane >> 4, rr = lane & 15;
#pragma unroll
  for (int fn = 0; fn < 4; fn++) {
#pragma unroll
    for (int rl = 0; rl < 4; rl++) {
      int i = row0 + wave * 16 + rq * 4 + rl;
      ctx16[(long long)i * 512 + h * 64 + fn * 16 + rr] = f2bf(acc[fn][rl]);
    }
  }
}

// ---------------------------------------------------------------------------
// Vertical routing.  Grid 4096.
// ---------------------------------------------------------------------------
__global__ __launch_bounds__(256) void vertical_routing_kernel(
    const unsigned short* __restrict__ u16, float* __restrict__ vV) {
  __shared__ float Ur[8 * 1024];
  __shared__ float red[4];
  __shared__ float red8[32];
  int bq = blockIdx.x;
  int t = (int)threadIdx.x;
  const unsigned short* Ub = u16 + (long long)bq * 8192;
#pragma unroll
  for (int r = 0; r < 8; r++) {
    uint2 p = *(const uint2*)&Ub[(t + 256 * r) * 4];
    Ur[(t + 256 * r) * 4 + 0] = bf2f(p.x & 0xffffu);
    Ur[(t + 256 * r) * 4 + 1] = bf2f(p.x >> 16);
    Ur[(t + 256 * r) * 4 + 2] = bf2f(p.y & 0xffffu);
    Ur[(t + 256 * r) * 4 + 3] = bf2f(p.y >> 16);
  }
  __syncthreads();

  float bh[8] = {0.f, 0.f, 0.f, 0.f, 0.f, 0.f, 0.f, 0.f};
  int k0 = t * 4;
  float4 v4 = {0.f, 0.f, 0.f, 0.f};
  for (int it = 0; it < 3; ++it) {
    float m = bh[0];
#pragma unroll
    for (int h = 1; h < 8; h++) m = fmaxf(m, bh[h]);
    float c[8], zz = 0.f;
#pragma unroll
    for (int h = 0; h < 8; h++) {
      c[h] = expf(bh[h] - m);
      zz += c[h];
    }
    float inv = 1.f / zz;
    float4 s4 = {0.f, 0.f, 0.f, 0.f};
#pragma unroll
    for (int h = 0; h < 8; h++) {
      float4 u = *(float4*)&Ur[h * 1024 + k0];
      float ch = c[h] * inv;
      s4.x = fmaf(ch, u.x, s4.x); s4.y = fmaf(ch, u.y, s4.y);
      s4.z = fmaf(ch, u.z, s4.z); s4.w = fmaf(ch, u.w, s4.w);
    }
    float sq =
        blockSum(s4.x * s4.x + s4.y * s4.y + s4.z * s4.z + s4.w * s4.w, red);
    float sc = (sq / (1.f + sq)) / sqrtf(sq + SQ_EPS);
    v4.x = sc * s4.x; v4.y = sc * s4.y; v4.z = sc * s4.z; v4.w = sc * s4.w;
    if (it < 2) {
      float p[8];
#pragma unroll
      for (int h = 0; h < 8; h++) {
        float4 u = *(float4*)&Ur[h * 1024 + k0];
        p[h] = u.x * v4.x + u.y * v4.y + u.z * v4.z + u.w * v4.w;
      }
      __syncthreads();
#pragma unroll
      for (int h = 0; h < 8; h++) {
        float w = wredSum(p[h]);
        if ((t & 63) == 0) red8[(t >> 6) * 8 + h] = w;
      }
      __syncthreads();
#pragma unroll
      for (int h = 0; h < 8; h++)
        bh[h] += red8[h] + red8[8 + h] + red8[16 + h] + red8[24 + h];
    }
  }
  *(float4*)&vV[(long long)bq * 1024 + k0] = v4;
}

// enhanced softmax.  Grid 32768.
__global__ __launch_bounds__(256) void enh_softmax_kernel(
    unsigned short* __restrict__ u16, const float* __restrict__ vV,
    const unsigned short* __restrict__ v16) {
  __shared__ float red[4];
  int idx = blockIdx.x;
  int h = idx & 7;
  int bq = idx >> 3;
  unsigned short* Urow = u16 + (long long)bq * 8192 + h * 1024;
  const float* va = vV + (long long)bq * 1024;
  const unsigned short* vb = v16 + (long long)bq * 8192 + h * 1024;
  int t = (int)threadIdx.x, k0 = t * 4;
  uint2 pu = *(const uint2*)&Urow[k0];
  float4 a = *(const float4*)&va[k0];
  uint2 pb = *(const uint2*)&vb[k0];
  float x0 = bf2f(pu.x & 0xffffu) + a.x + bf2f(pb.x & 0xffffu);
  float x1 = bf2f(pu.x >> 16) + a.y + bf2f(pb.x >> 16);
  float x2 = bf2f(pu.y & 0xffffu) + a.z + bf2f(pb.y & 0xffffu);
  float x3 = bf2f(pu.y >> 16) + a.w + bf2f(pb.y >> 16);
  float mx = blockMax(fmaxf(fmaxf(x0, x1), fmaxf(x2, x3)), red);
  float e0 = expf(x0 - mx), e1 = expf(x1 - mx), e2 = expf(x2 - mx),
        e3 = expf(x3 - mx);
  float zz = blockSum(e0 + e1 + e2 + e3, red);
  float inv = 1.f / zz;
  uint2 o = {(unsigned int)f2bf(e0 * inv) | ((unsigned int)f2bf(e1 * inv) << 16),
             (unsigned int)f2bf(e2 * inv) | ((unsigned int)f2bf(e3 * inv) << 16)};
  *(uint2*)&Urow[k0] = o;
}

// ---------------------------------------------------------------------------
extern "C" void kernel_launch(void* const* d_in, const int* in_sizes, int n_in,
                              void* d_out, int out_size, void* d_ws,
                              size_t ws_size, hipStream_t stream) {
  (void)in_sizes; (void)n_in; (void)out_size; (void)ws_size;
  const float* x = (const float*)d_in[0];
  const float* Wq = (const float*)d_in[1];
  const float* bq = (const float*)d_in[2];
  const float* Wk = (const float*)d_in[3];
  const float* bk = (const float*)d_in[4];
  const float* Wv = (const float*)d_in[5];
  const float* bv = (const float*)d_in[6];
  const float* Wo = (const float*)d_in[7];
  const float* bo = (const float*)d_in[8];
  float* out = (float*)d_out;
  float* ws = (float*)d_ws;

  unsigned short* u16a = (unsigned short*)(ws);              // 16M fl
  unsigned short* QT16 = (unsigned short*)(ws + 16777216);   // 1M fl
  unsigned short* K16 = (unsigned short*)(ws + 17825792);    // 1M fl
  unsigned short* KT16 = (unsigned short*)(ws + 18874368);   // 1M fl
  unsigned short* T16 = (unsigned short*)(ws + 19922944);    // 64K fl slot
  unsigned short* Y16 = (unsigned short*)(ws + 20971520);    // 1M fl
  unsigned short* Q16 = (unsigned short*)(ws + 22020096);    // 1M fl
  // Win @ 23068672 .. 39845888 (16M fl), time-multiplexed:
  float* Qf = ws + 23068672;                                 // 2M
  float* Kf = ws + 25165824;                                 // 2M
  unsigned short* V16a = (unsigned short*)(ws + 27262976);   // 1M fl
  unsigned short* sv16a = (unsigned short*)(ws + 23068672);  // 16M fl
  float* Mbufa = ws + 39845888;                              // 4M fl
  unsigned short* R16 = (unsigned short*)(ws + 39845888);    // 1M fl (after M)
  float* vVa = ws + 44040192;                                // 4M
  float* bHa = ws + 48234496;                                // 4M
  unsigned short* ctx16 = (unsigned short*)(ws + 48234496);  // overlays bHa
  unsigned short* cH16a = (unsigned short*)(ws + 52428800);  // 2M fl
  unsigned short* G16a = (unsigned short*)(ws + 54525952);   // 2M fl
  unsigned short* VT16a = (unsigned short*)(ws + 56623104);  // 1M fl
  unsigned short* WT16 = (unsigned short*)(ws + 57671680);   // 0.5M fl
  float* scl = ws + 58195968;                                // 4096
  // total 58,200,064 fl = 222 MiB

  // 1-4. prologue
  wtrans_kernel<<<dim3(8, 8, 4), 256, 0, stream>>>(Wq, Wk, Wv, Wo, WT16);
  gemm_qkv_mfma<<<dim3(8, 64, 3), 256, 0, stream>>>(x, WT16, bq, bk, bv, Qf,
                                                    Kf, Q16, K16, V16a);
  transpose16_kernel<<<dim3(16, 8, 4), 256, 0, stream>>>(V16a, VT16a, 512,
                                                         1024, 524288, 524288);
  transpose_f32_bf16_kernel<<<dim3(16, 8, 4), 256, 0, stream>>>(
      Qf, QT16, 512, 1024, 524288, 524288);
  transpose_f32_bf16_kernel<<<dim3(16, 8, 4), 256, 0, stream>>>(
      Kf, KT16, 512, 1024, 524288, 524288);

  // 5. scores (fp32, accuracy-pinned) -> u16a, all batches
  gemm_scores_bf16<<<dim3(8, 8, 32), 256, 0, stream>>>(Qf, Kf, u16a);

  // 6. vertical routing, all batches
  vertical_routing_kernel<<<dim3(4096), 256, 0, stream>>>(u16a, vVa);

  // 7. factored Gram: T = (1/64)K^T K; Y = Q·T; G = Y·Q^T (+mirror)
  gemm_T_bf16<<<dim3(32), 256, 0, stream>>>(KT16, T16);
  gemm_Y_bf16<<<dim3(1, 16, 32), 256, 0, stream>>>(Q16, T16, Y16);
  gemm_YQ_bf16<<<dim3(8, 8, 4), 256, 0, stream>>>(Y16, Q16, G16a);
  mirror_G_kernel<<<dim3(16, 16, 4), 256, 0, stream>>>(G16a);

  // 8. horizontal routing iterations (all batches per stage)
  softmax_uniform_kernel<<<dim3(1024, 4), 256, 0, stream>>>(cH16a);
  gemm_M_bf16<<<dim3(16, 16, 4), 256, 0, stream>>>(cH16a, G16a, Mbufa);
  fused_scl_bupd_kernel<1><<<dim3(1024, 4), 256, 0, stream>>>(bHa, Mbufa,
                                                              cH16a);
  gemm_M_bf16<<<dim3(16, 16, 4), 256, 0, stream>>>(cH16a, G16a, Mbufa);
  fused_scl_bupd_kernel<0><<<dim3(1024, 4), 256, 0, stream>>>(bHa, Mbufa,
                                                              cH16a);
  gemm_M_bf16<<<dim3(16, 16, 4), 256, 0, stream>>>(cH16a, G16a, Mbufa);
  scldot_kernel<<<dim3(1024, 4), 256, 0, stream>>>(Mbufa, cH16a, scl);

  // 9. factored final s: R = C·Q (causal), sv = scl·0.125·R·K^T
  gemm_R_bf16<<<dim3(4, 8, 4), 256, 0, stream>>>(cH16a, QT16, R16);
  gemm_sfinal<<<dim3(16, 16, 32), 256, 0, stream>>>(R16, K16, scl, sv16a);

  // 10. enhanced + softmax -> w into u16a
  enh_softmax_kernel<<<dim3(32768), 256, 0, stream>>>(u16a, vVa, sv16a);

  // 11. ctx = w x V (bf16 out, writes over dead bHa)
  gemm_ctx_bf16<<<dim3(64, 8), 256, 0, stream>>>(u16a, VT16a, ctx16);

  // 12. out = ctx16 x Wo + bo (bf16 MFMA, Wo^T at WT16 + 3*262144)
  gemm_out_mfma<<<dim3(8, 64), 256, 0, stream>>>(ctx16, WT16 + 786432, bo,
                                                 out);
}

// Round 19
// 374.027 us; speedup vs baseline: 1.2878x; 1.0269x over previous
//
#include <hip/hip_runtime.h>
#include <math.h>

// ---------------------------------------------------------------------------
// CapsuleRoutingSelfAttention — round 19: double-buffered fp32 scores.
// Same fp32 math, bit-identical per-output fmaf order (k = 0..63 sequential);
// K-stage 8->16, two LDS buffers, ONE barrier per stage (was 2x8), global
// loads + LDS writes overlapped with the 1024-FMA compute.  Everything else
// is round-18 verbatim (green at 384.1 us / 5.86e-3).
// ---------------------------------------------------------------------------

#define SQ_EPS 1e-8f

typedef __attribute__((ext_vector_type(4))) int i32x4;    // 8 bf16
typedef __attribute__((ext_vector_type(4))) float f32x4;

__device__ __forceinline__ float bf2f(unsigned int u) {
  union { unsigned int i; float f; } x;
  x.i = u << 16;
  return x.f;
}
__device__ __forceinline__ unsigned short f2bf(float f) {
  union { float f; unsigned int i; } x;
  x.f = f;
  unsigned int r = x.i + 0x7fffu + ((x.i >> 16) & 1u);
  return (unsigned short)(r >> 16);
}
__device__ __forceinline__ int packbf(float a, float b) {
  return (int)((unsigned int)f2bf(a) | ((unsigned int)f2bf(b) << 16));
}

__device__ __forceinline__ f32x4 mfma_bf16(i32x4 a, i32x4 b, f32x4 c) {
  asm("v_mfma_f32_16x16x32_bf16 %0, %1, %2, %0" : "+v"(c) : "v"(a), "v"(b));
  return c;
}

__device__ __forceinline__ float wredSum(float v) {
#pragma unroll
  for (int off = 32; off > 0; off >>= 1) v += __shfl_xor(v, off);
  return v;
}
__device__ __forceinline__ float wredMax(float v) {
#pragma unroll
  for (int off = 32; off > 0; off >>= 1) v = fmaxf(v, __shfl_xor(v, off));
  return v;
}
__device__ __forceinline__ float blockSum(float v, volatile float* red) {
  v = wredSum(v);
  int wid = threadIdx.x >> 6;
  __syncthreads();
  if ((threadIdx.x & 63) == 0) red[wid] = v;
  __syncthreads();
  return red[0] + red[1] + red[2] + red[3];
}
__device__ __forceinline__ float blockMax(float v, volatile float* red) {
  v = wredMax(v);
  int wid = threadIdx.x >> 6;
  __syncthreads();
  if ((threadIdx.x & 63) == 0) red[wid] = v;
  __syncthreads();
  return fmaxf(fmaxf(red[0], red[1]), fmaxf(red[2], red[3]));
}

// ---------------------------------------------------------------------------
// W^T prep (Wq,Wk,Wv,Wo).  Grid (8, 8, 4).
// ---------------------------------------------------------------------------
__global__ __launch_bounds__(256) void wtrans_kernel(
    const float* __restrict__ Wq, const float* __restrict__ Wk,
    const float* __restrict__ Wv, const float* __restrict__ Wo,
    unsigned short* __restrict__ WT16) {
  __shared__ unsigned short T[64][72];
  int z = blockIdx.z;
  const float* src = (z == 0) ? Wq : (z == 1) ? Wk : (z == 2) ? Wv : Wo;
  unsigned short* dst = WT16 + (long long)z * 262144;
  int i0 = blockIdx.x * 64;
  int c0 = blockIdx.y * 64;
  int t = (int)threadIdx.x;
  int r = t >> 2, cq = (t & 3) * 16;
#pragma unroll
  for (int j = 0; j < 4; j++) {
    float4 v = *(const float4*)&src[(long long)(i0 + r) * 512 + c0 + cq + j * 4];
    T[r][cq + j * 4 + 0] = f2bf(v.x);
    T[r][cq + j * 4 + 1] = f2bf(v.y);
    T[r][cq + j * 4 + 2] = f2bf(v.z);
    T[r][cq + j * 4 + 3] = f2bf(v.w);
  }
  __syncthreads();
  int c = t >> 2, iq = (t & 3) * 16;
  unsigned short tmp[16];
#pragma unroll
  for (int j = 0; j < 16; j++) tmp[j] = T[iq + j][c];
  *(i32x4*)&dst[(long long)(c0 + c) * 512 + i0 + iq] = *(i32x4*)&tmp[0];
  *(i32x4*)&dst[(long long)(c0 + c) * 512 + i0 + iq + 8] = *(i32x4*)&tmp[8];
}

// ---------------------------------------------------------------------------
// QKV (bf16 MFMA): z=0 -> Qf f32 + Q16 bf16, z=1 -> Kf f32 + K16 bf16,
// z=2 -> V16 bf16.  Grid (8, 64, 3).
// ---------------------------------------------------------------------------
__global__ __launch_bounds__(256) void gemm_qkv_mfma(
    const float* __restrict__ x, const unsigned short* __restrict__ WT16,
    const float* __restrict__ bq, const float* __restrict__ bk,
    const float* __restrict__ bv, float* __restrict__ Qf,
    float* __restrict__ Kf, unsigned short* __restrict__ Q16,
    unsigned short* __restrict__ K16, unsigned short* __restrict__ V16) {
  __shared__ unsigned short Asl[64][68];
  __shared__ unsigned short Bsl[64][68];
  int z = blockIdx.z;
  const unsigned short* WT = WT16 + (long long)z * 262144;
  const float* bias = (z == 0) ? bq : (z == 1) ? bk : bv;

  int row0 = blockIdx.y * 64;
  int col0 = blockIdx.x * 64;
  int t = (int)threadIdx.x, lane = t & 63, wave = t >> 6;
  int wm = wave >> 1, wn = wave & 1;

  f32x4 acc[2][2];
#pragma unroll
  for (int i = 0; i < 2; i++)
#pragma unroll
    for (int j = 0; j < 2; j++) acc[i][j] = (f32x4){0.f, 0.f, 0.f, 0.f};

  int r = t >> 2, kq = (t & 3) * 8;
  const float* Ap = x + (long long)(row0 + r) * 512 + kq;
  const unsigned short* Bp = WT + (long long)(col0 + r) * 512 + kq;

  for (int kb = 0; kb < 512; kb += 64) {
    float4 a0 = *(const float4*)(Ap + kb);
    float4 a1 = *(const float4*)(Ap + kb + 4);
    float4 a2 = *(const float4*)(Ap + kb + 32);
    float4 a3 = *(const float4*)(Ap + kb + 36);
    i32x4 b0 = *(const i32x4*)(Bp + kb);
    i32x4 b1 = *(const i32x4*)(Bp + kb + 32);
    __syncthreads();
    i32x4 pa0 = {packbf(a0.x, a0.y), packbf(a0.z, a0.w), packbf(a1.x, a1.y),
                 packbf(a1.z, a1.w)};
    i32x4 pa1 = {packbf(a2.x, a2.y), packbf(a2.z, a2.w), packbf(a3.x, a3.y),
                 packbf(a3.z, a3.w)};
    *(i32x4*)&Asl[r][kq] = pa0;
    *(i32x4*)&Asl[r][kq + 32] = pa1;
    *(i32x4*)&Bsl[r][kq] = b0;
    *(i32x4*)&Bsl[r][kq + 32] = b1;
    __syncthreads();

    int rr = lane & 15, ko = (lane >> 4) * 8;
#pragma unroll
    for (int k2 = 0; k2 < 2; k2++) {
      i32x4 af0 = *(i32x4*)&Asl[wm * 32 + rr][k2 * 32 + ko];
      i32x4 af1 = *(i32x4*)&Asl[wm * 32 + 16 + rr][k2 * 32 + ko];
      i32x4 bf0 = *(i32x4*)&Bsl[wn * 32 + rr][k2 * 32 + ko];
      i32x4 bf1 = *(i32x4*)&Bsl[wn * 32 + 16 + rr][k2 * 32 + ko];
      acc[0][0] = mfma_bf16(af0, bf0, acc[0][0]);
      acc[0][1] = mfma_bf16(af0, bf1, acc[0][1]);
      acc[1][0] = mfma_bf16(af1, bf0, acc[1][0]);
      acc[1][1] = mfma_bf16(af1, bf1, acc[1][1]);
    }
  }

  int rq = lane >> 4, rr = lane & 15;
#pragma unroll
  for (int fm = 0; fm < 2; fm++) {
#pragma unroll
    for (int fn = 0; fn < 2; fn++) {
      int col = col0 + wn * 32 + fn * 16 + rr;
      float bb = bias[col];
#pragma unroll
      for (int rl = 0; rl < 4; rl++) {
        int row = row0 + wm * 32 + fm * 16 + rq * 4 + rl;
        float v = acc[fm][fn][rl] + bb;
        long long idx = (long long)row * 512 + col;
        if (z == 2) {
          V16[idx] = f2bf(v);
        } else if (z == 1) {
          Kf[idx] = v;
          K16[idx] = f2bf(v);
        } else {
          Qf[idx] = v;
          Q16[idx] = f2bf(v);
        }
      }
    }
  }
}

// ---------------------------------------------------------------------------
// Out-projection (bf16 MFMA).  Grid (8, 64).
// ---------------------------------------------------------------------------
__global__ __launch_bounds__(256) void gemm_out_mfma(
    const unsigned short* __restrict__ A16,
    const unsigned short* __restrict__ WoT,
    const float* __restrict__ bo, float* __restrict__ out) {
  __shared__ unsigned short Asl[64][68];
  __shared__ unsigned short Bsl[64][68];
  int row0 = blockIdx.y * 64;
  int col0 = blockIdx.x * 64;
  int t = (int)threadIdx.x, lane = t & 63, wave = t >> 6;
  int wm = wave >> 1, wn = wave & 1;

  f32x4 acc[2][2];
#pragma unroll
  for (int i = 0; i < 2; i++)
#pragma unroll
    for (int j = 0; j < 2; j++) acc[i][j] = (f32x4){0.f, 0.f, 0.f, 0.f};

  int r = t >> 2, kq = (t & 3) * 8;
  const unsigned short* Ap = A16 + (long long)(row0 + r) * 512 + kq;
  const unsigned short* Bp = WoT + (long long)(col0 + r) * 512 + kq;

  for (int kb = 0; kb < 512; kb += 64) {
    i32x4 a0 = *(const i32x4*)(Ap + kb);
    i32x4 a1 = *(const i32x4*)(Ap + kb + 32);
    i32x4 b0 = *(const i32x4*)(Bp + kb);
    i32x4 b1 = *(const i32x4*)(Bp + kb + 32);
    __syncthreads();
    *(i32x4*)&Asl[r][kq] = a0;
    *(i32x4*)&Asl[r][kq + 32] = a1;
    *(i32x4*)&Bsl[r][kq] = b0;
    *(i32x4*)&Bsl[r][kq + 32] = b1;
    __syncthreads();

    int rr = lane & 15, ko = (lane >> 4) * 8;
#pragma unroll
    for (int k2 = 0; k2 < 2; k2++) {
      i32x4 af0 = *(i32x4*)&Asl[wm * 32 + rr][k2 * 32 + ko];
      i32x4 af1 = *(i32x4*)&Asl[wm * 32 + 16 + rr][k2 * 32 + ko];
      i32x4 bf0 = *(i32x4*)&Bsl[wn * 32 + rr][k2 * 32 + ko];
      i32x4 bf1 = *(i32x4*)&Bsl[wn * 32 + 16 + rr][k2 * 32 + ko];
      acc[0][0] = mfma_bf16(af0, bf0, acc[0][0]);
      acc[0][1] = mfma_bf16(af0, bf1, acc[0][1]);
      acc[1][0] = mfma_bf16(af1, bf0, acc[1][0]);
      acc[1][1] = mfma_bf16(af1, bf1, acc[1][1]);
    }
  }

  int rq = lane >> 4, rr = lane & 15;
#pragma unroll
  for (int fm = 0; fm < 2; fm++) {
#pragma unroll
    for (int fn = 0; fn < 2; fn++) {
      int col = col0 + wn * 32 + fn * 16 + rr;
      float bb = bo[col];
#pragma unroll
      for (int rl = 0; rl < 4; rl++) {
        int row = row0 + wm * 32 + fm * 16 + rq * 4 + rl;
        out[(long long)row * 512 + col] = acc[fm][fn][rl] + bb;
      }
    }
  }
}

// ---------------------------------------------------------------------------
// sv = scl·0.125·R·K^T per head.  Grid (16, 16, 32).
// ---------------------------------------------------------------------------
__global__ __launch_bounds__(256) void gemm_sfinal(
    const unsigned short* __restrict__ R16a,
    const unsigned short* __restrict__ K16a,
    const float* __restrict__ scla, unsigned short* __restrict__ sv16a) {
  __shared__ unsigned short Asl[64][68];
  __shared__ unsigned short Bsl[64][68];
  int z = blockIdx.z;
  int b = z >> 3, h = z & 7;
  const unsigned short* A16 = R16a + (long long)b * 524288;
  const unsigned short* Bm = K16a + (long long)b * 524288;
  const float* scl = scla + b * 1024;
  unsigned short* sv = sv16a + (long long)b * 8388608;
  int row0 = blockIdx.y * 64;
  int col0 = blockIdx.x * 64;
  int t = (int)threadIdx.x, lane = t & 63, wave = t >> 6;
  int wm = wave >> 1, wn = wave & 1;

  f32x4 acc[2][2];
#pragma unroll
  for (int i = 0; i < 2; i++)
#pragma unroll
    for (int j = 0; j < 2; j++) acc[i][j] = (f32x4){0.f, 0.f, 0.f, 0.f};

  int r = t >> 2, kq = (t & 3) * 8;
  const unsigned short* Ap = A16 + (long long)(row0 + r) * 512 + h * 64 + kq;
  const unsigned short* Bp = Bm + (long long)(col0 + r) * 512 + h * 64 + kq;

  {
    i32x4 a0 = *(const i32x4*)(Ap);
    i32x4 a1 = *(const i32x4*)(Ap + 32);
    i32x4 b0 = *(const i32x4*)(Bp);
    i32x4 b1 = *(const i32x4*)(Bp + 32);
    __syncthreads();
    *(i32x4*)&Asl[r][kq] = a0;
    *(i32x4*)&Asl[r][kq + 32] = a1;
    *(i32x4*)&Bsl[r][kq] = b0;
    *(i32x4*)&Bsl[r][kq + 32] = b1;
    __syncthreads();

    int rr = lane & 15, ko = (lane >> 4) * 8;
#pragma unroll
    for (int k2 = 0; k2 < 2; k2++) {
      i32x4 af0 = *(i32x4*)&Asl[wm * 32 + rr][k2 * 32 + ko];
      i32x4 af1 = *(i32x4*)&Asl[wm * 32 + 16 + rr][k2 * 32 + ko];
      i32x4 bf0 = *(i32x4*)&Bsl[wn * 32 + rr][k2 * 32 + ko];
      i32x4 bf1 = *(i32x4*)&Bsl[wn * 32 + 16 + rr][k2 * 32 + ko];
      acc[0][0] = mfma_bf16(af0, bf0, acc[0][0]);
      acc[0][1] = mfma_bf16(af0, bf1, acc[0][1]);
      acc[1][0] = mfma_bf16(af1, bf0, acc[1][0]);
      acc[1][1] = mfma_bf16(af1, bf1, acc[1][1]);
    }
  }

  int rq = lane >> 4, rr = lane & 15;
#pragma unroll
  for (int fm = 0; fm < 2; fm++) {
#pragma unroll
    for (int fn = 0; fn < 2; fn++) {
      int col = col0 + wn * 32 + fn * 16 + rr;
#pragma unroll
      for (int rl = 0; rl < 4; rl++) {
        int row = row0 + wm * 32 + fm * 16 + rq * 4 + rl;
        sv[(long long)row * 8192 + h * 1024 + col] =
            f2bf(0.125f * scl[row] * acc[fm][fn][rl]);
      }
    }
  }
}

// ---------------------------------------------------------------------------
// Y = Q·T per head (B = T16 row-major ldb=64).  Grid (1, 16, 32).
// ---------------------------------------------------------------------------
__global__ __launch_bounds__(256) void gemm_Y_bf16(
    const unsigned short* __restrict__ Q16a,
    const unsigned short* __restrict__ T16a,
    unsigned short* __restrict__ Y16a) {
  __shared__ unsigned short Asl[64][68];
  __shared__ unsigned short Bsl[64][68];
  int z = blockIdx.z;
  int b = z >> 3, h = z & 7;
  const unsigned short* A16 = Q16a + (long long)b * 524288;
  const unsigned short* Tz = T16a + (long long)z * 4096;
  unsigned short* Y = Y16a + (long long)b * 524288;
  int row0 = blockIdx.y * 64;
  int t = (int)threadIdx.x, lane = t & 63, wave = t >> 6;
  int wm = wave >> 1, wn = wave & 1;

  f32x4 acc[2][2];
#pragma unroll
  for (int i = 0; i < 2; i++)
#pragma unroll
    for (int j = 0; j < 2; j++) acc[i][j] = (f32x4){0.f, 0.f, 0.f, 0.f};

  int r = t >> 2, kq = (t & 3) * 8;
  const unsigned short* Ap = A16 + (long long)(row0 + r) * 512 + h * 64 + kq;
  const unsigned short* Bp = Tz + (long long)r * 64 + kq;

  {
    i32x4 a0 = *(const i32x4*)(Ap);
    i32x4 a1 = *(const i32x4*)(Ap + 32);
    i32x4 b0 = *(const i32x4*)(Bp);
    i32x4 b1 = *(const i32x4*)(Bp + 32);
    __syncthreads();
    *(i32x4*)&Asl[r][kq] = a0;
    *(i32x4*)&Asl[r][kq + 32] = a1;
    *(i32x4*)&Bsl[r][kq] = b0;
    *(i32x4*)&Bsl[r][kq + 32] = b1;
    __syncthreads();

    int rr = lane & 15, ko = (lane >> 4) * 8;
#pragma unroll
    for (int k2 = 0; k2 < 2; k2++) {
      i32x4 af0 = *(i32x4*)&Asl[wm * 32 + rr][k2 * 32 + ko];
      i32x4 af1 = *(i32x4*)&Asl[wm * 32 + 16 + rr][k2 * 32 + ko];
      i32x4 bf0 = *(i32x4*)&Bsl[wn * 32 + rr][k2 * 32 + ko];
      i32x4 bf1 = *(i32x4*)&Bsl[wn * 32 + 16 + rr][k2 * 32 + ko];
      acc[0][0] = mfma_bf16(af0, bf0, acc[0][0]);
      acc[0][1] = mfma_bf16(af0, bf1, acc[0][1]);
      acc[1][0] = mfma_bf16(af1, bf0, acc[1][0]);
      acc[1][1] = mfma_bf16(af1, bf1, acc[1][1]);
    }
  }

  int rq = lane >> 4, rr = lane & 15;
#pragma unroll
  for (int fm = 0; fm < 2; fm++) {
#pragma unroll
    for (int fn = 0; fn < 2; fn++) {
      int col = wn * 32 + fn * 16 + rr;
#pragma unroll
      for (int rl = 0; rl < 4; rl++) {
        int row = row0 + wm * 32 + fm * 16 + rq * 4 + rl;
        Y[(long long)row * 512 + h * 64 + col] = f2bf(acc[fm][fn][rl]);
      }
    }
  }
}

// ---------------------------------------------------------------------------
// Scores (fp32, accuracy-pinned) — double-buffered, K-stage 16, one barrier
// per stage.  Per-output fmaf order (k=0..63 sequential) is bit-identical to
// the round-18 kernel.  Grid (8, 8, 32).
// ---------------------------------------------------------------------------
__global__ __launch_bounds__(256) void gemm_scores_bf16(
    const float* __restrict__ Qf, const float* __restrict__ Kf,
    unsigned short* __restrict__ u16a) {
  __shared__ float As[2][16][132];
  __shared__ float Bs[2][16][132];
  int z = blockIdx.z;
  int b = z >> 3, h = z & 7;
  const float* A = Qf + (long long)b * 524288 + h * 64;
  const float* B = Kf + (long long)b * 524288 + h * 64;
  unsigned short* C16 = u16a + (long long)b * 8388608 + h * 1024;

  int row0 = blockIdx.y * 128;
  int col0 = blockIdx.x * 128;
  int tid = (int)threadIdx.x;
  int tx = tid & 15, ty = tid >> 4;
  int arow = tid >> 1;
  int akc = (tid & 1) * 8;

  float acc[8][8];
#pragma unroll
  for (int i = 0; i < 8; i++)
#pragma unroll
    for (int j = 0; j < 8; j++) acc[i][j] = 0.f;

  const float* Aptr = A + (long long)(row0 + arow) * 512 + akc;
  const float* Bptr = B + (long long)(col0 + arow) * 512 + akc;

  // prolog: stage 0 -> buf 0
  {
    float4 av0 = *(const float4*)(Aptr);
    float4 av1 = *(const float4*)(Aptr + 4);
    float4 bv0 = *(const float4*)(Bptr);
    float4 bv1 = *(const float4*)(Bptr + 4);
    As[0][akc + 0][arow] = av0.x; As[0][akc + 1][arow] = av0.y;
    As[0][akc + 2][arow] = av0.z; As[0][akc + 3][arow] = av0.w;
    As[0][akc + 4][arow] = av1.x; As[0][akc + 5][arow] = av1.y;
    As[0][akc + 6][arow] = av1.z; As[0][akc + 7][arow] = av1.w;
    Bs[0][akc + 0][arow] = bv0.x; Bs[0][akc + 1][arow] = bv0.y;
    Bs[0][akc + 2][arow] = bv0.z; Bs[0][akc + 3][arow] = bv0.w;
    Bs[0][akc + 4][arow] = bv1.x; Bs[0][akc + 5][arow] = bv1.y;
    Bs[0][akc + 6][arow] = bv1.z; Bs[0][akc + 7][arow] = bv1.w;
  }
  __syncthreads();

#pragma unroll
  for (int s = 0; s < 4; ++s) {
    const int cur = s & 1;
    float4 nav0, nav1, nbv0, nbv1;
    if (s < 3) {
      int kb = (s + 1) * 16;
      nav0 = *(const float4*)(Aptr + kb);
      nav1 = *(const float4*)(Aptr + kb + 4);
      nbv0 = *(const float4*)(Bptr + kb);
      nbv1 = *(const float4*)(Bptr + kb + 4);
    }
#pragma unroll
    for (int k = 0; k < 16; k++) {
      float a[8], b2[8];
#pragma unroll
      for (int c = 0; c < 2; c++) {
        float4 q = *(float4*)&As[cur][k][ty * 8 + c * 4];
        a[c * 4 + 0] = q.x; a[c * 4 + 1] = q.y;
        a[c * 4 + 2] = q.z; a[c * 4 + 3] = q.w;
      }
#pragma unroll
      for (int c = 0; c < 2; c++) {
        float4 q = *(float4*)&Bs[cur][k][c * 64 + tx * 4];
        b2[c * 4 + 0] = q.x; b2[c * 4 + 1] = q.y;
        b2[c * 4 + 2] = q.z; b2[c * 4 + 3] = q.w;
      }
#pragma unroll
      for (int i = 0; i < 8; i++)
#pragma unroll
        for (int j = 0; j < 8; j++) acc[i][j] = fmaf(a[i], b2[j], acc[i][j]);
    }
    if (s < 3) {
      const int nxt = cur ^ 1;
      As[nxt][akc + 0][arow] = nav0.x; As[nxt][akc + 1][arow] = nav0.y;
      As[nxt][akc + 2][arow] = nav0.z; As[nxt][akc + 3][arow] = nav0.w;
      As[nxt][akc + 4][arow] = nav1.x; As[nxt][akc + 5][arow] = nav1.y;
      As[nxt][akc + 6][arow] = nav1.z; As[nxt][akc + 7][arow] = nav1.w;
      Bs[nxt][akc + 0][arow] = nbv0.x; Bs[nxt][akc + 1][arow] = nbv0.y;
      Bs[nxt][akc + 2][arow] = nbv0.z; Bs[nxt][akc + 3][arow] = nbv0.w;
      Bs[nxt][akc + 4][arow] = nbv1.x; Bs[nxt][akc + 5][arow] = nbv1.y;
      Bs[nxt][akc + 6][arow] = nbv1.z; Bs[nxt][akc + 7][arow] = nbv1.w;
      __syncthreads();
    }
  }

#pragma unroll
  for (int i = 0; i < 8; i++) {
    long long r = row0 + ty * 8 + i;
#pragma unroll
    for (int c = 0; c < 2; c++) {
      int col = col0 + c * 64 + tx * 4;
      unsigned int lo = (unsigned int)f2bf(0.125f * acc[i][c * 4 + 0]) |
                        ((unsigned int)f2bf(0.125f * acc[i][c * 4 + 1]) << 16);
      unsigned int hi = (unsigned int)f2bf(0.125f * acc[i][c * 4 + 2]) |
                        ((unsigned int)f2bf(0.125f * acc[i][c * 4 + 3]) << 16);
      uint2 o = {lo, hi};
      *(uint2*)&C16[r * 8192 + col] = o;
    }
  }
}

// ---------------------------------------------------------------------------
// bf16 transpose, z-batched.
// ---------------------------------------------------------------------------
__global__ __launch_bounds__(256) void transpose16_kernel(
    const unsigned short* __restrict__ src, unsigned short* __restrict__ dst,
    int ldS, int ldD, long long zsS, long long zsD) {
  __shared__ unsigned short T[64][72];
  src += (long long)blockIdx.z * zsS;
  dst += (long long)blockIdx.z * zsD;
  int i0 = blockIdx.x * 64;
  int c0 = blockIdx.y * 64;
  int t = (int)threadIdx.x;
  int r = t >> 2, cq = (t & 3) * 16;
  i32x4 v0 = *(const i32x4*)&src[(long long)(i0 + r) * ldS + c0 + cq];
  i32x4 v1 = *(const i32x4*)&src[(long long)(i0 + r) * ldS + c0 + cq + 8];
  *(i32x4*)&T[r][cq] = v0;
  *(i32x4*)&T[r][cq + 8] = v1;
  __syncthreads();
  int c = t >> 2, iq = (t & 3) * 16;
  unsigned short tmp[16];
#pragma unroll
  for (int j = 0; j < 16; j++) tmp[j] = T[iq + j][c];
  *(i32x4*)&dst[(long long)(c0 + c) * ldD + i0 + iq] = *(i32x4*)&tmp[0];
  *(i32x4*)&dst[(long long)(c0 + c) * ldD + i0 + iq + 8] = *(i32x4*)&tmp[8];
}

// f32 -> bf16 transpose.  Grid (16, 8, 4).
__global__ __launch_bounds__(256) void transpose_f32_bf16_kernel(
    const float* __restrict__ src, unsigned short* __restrict__ dst,
    int ldS, int ldD, long long zsS, long long zsD) {
  __shared__ unsigned short T[64][72];
  src += (long long)blockIdx.z * zsS;
  dst += (long long)blockIdx.z * zsD;
  int i0 = blockIdx.x * 64;
  int c0 = blockIdx.y * 64;
  int t = (int)threadIdx.x;
  int r = t >> 2, cq = (t & 3) * 16;
#pragma unroll
  for (int j = 0; j < 4; j++) {
    float4 v = *(const float4*)&src[(long long)(i0 + r) * ldS + c0 + cq + j * 4];
    T[r][cq + j * 4 + 0] = f2bf(v.x);
    T[r][cq + j * 4 + 1] = f2bf(v.y);
    T[r][cq + j * 4 + 2] = f2bf(v.z);
    T[r][cq + j * 4 + 3] = f2bf(v.w);
  }
  __syncthreads();
  int c = t >> 2, iq = (t & 3) * 16;
  unsigned short tmp[16];
#pragma unroll
  for (int j = 0; j < 16; j++) tmp[j] = T[iq + j][c];
  *(i32x4*)&dst[(long long)(c0 + c) * ldD + i0 + iq] = *(i32x4*)&tmp[0];
  *(i32x4*)&dst[(long long)(c0 + c) * ldD + i0 + iq + 8] = *(i32x4*)&tmp[8];
}

// ---------------------------------------------------------------------------
// T_h = (1/64)·K_h^T·K_h (A=B=KT rows, Kend=1024).  Grid (32).
// ---------------------------------------------------------------------------
__global__ __launch_bounds__(256) void gemm_T_bf16(
    const unsigned short* __restrict__ KT16a,
    unsigned short* __restrict__ T16a) {
  int z = blockIdx.x;
  int b = z >> 3, h = z & 7;
  const unsigned short* KT =
      KT16a + (long long)b * 524288 + (long long)h * 65536;
  __shared__ unsigned short Asl[64][64];
  __shared__ unsigned short Bsl[64][64];
  int t = (int)threadIdx.x, lane = t & 63, wave = t >> 6;
  int wm = wave >> 1, wn = wave & 1;

  f32x4 acc[2][2];
#pragma unroll
  for (int i = 0; i < 2; i++)
#pragma unroll
    for (int j = 0; j < 2; j++) acc[i][j] = (f32x4){0.f, 0.f, 0.f, 0.f};

  int r = t >> 2, c0 = t & 3;
  int sw0 = ((c0 ^ (r & 7))) * 8;
  int sw1 = (((c0 + 4) ^ (r & 7))) * 8;
  const unsigned short* Ap = KT + (long long)r * 1024 + c0 * 8;

  for (int kb = 0; kb < 1024; kb += 64) {
    i32x4 a0 = *(const i32x4*)(Ap + kb);
    i32x4 a1 = *(const i32x4*)(Ap + kb + 32);
    __syncthreads();
    *(i32x4*)&Asl[r][sw0] = a0;
    *(i32x4*)&Asl[r][sw1] = a1;
    *(i32x4*)&Bsl[r][sw0] = a0;
    *(i32x4*)&Bsl[r][sw1] = a1;
    __syncthreads();

    int rr = lane & 15, co = lane >> 4;
#pragma unroll
    for (int k2 = 0; k2 < 2; k2++) {
      int ch = ((k2 * 4 + co) ^ (rr & 7)) * 8;
      i32x4 af0 = *(i32x4*)&Asl[wm * 32 + rr][ch];
      i32x4 af1 = *(i32x4*)&Asl[wm * 32 + 16 + rr][ch];
      i32x4 bf0 = *(i32x4*)&Bsl[wn * 32 + rr][ch];
      i32x4 bf1 = *(i32x4*)&Bsl[wn * 32 + 16 + rr][ch];
      acc[0][0] = mfma_bf16(af0, bf0, acc[0][0]);
      acc[0][1] = mfma_bf16(af0, bf1, acc[0][1]);
      acc[1][0] = mfma_bf16(af1, bf0, acc[1][0]);
      acc[1][1] = mfma_bf16(af1, bf1, acc[1][1]);
    }
  }

  unsigned short* Tz = T16a + (long long)z * 4096;
  int rq = lane >> 4, rr = lane & 15;
#pragma unroll
  for (int fm = 0; fm < 2; fm++) {
#pragma unroll
    for (int fn = 0; fn < 2; fn++) {
      int j = wn * 32 + fn * 16 + rr;
#pragma unroll
      for (int rl = 0; rl < 4; rl++) {
        int i = wm * 32 + fm * 16 + rq * 4 + rl;
        Tz[i * 64 + j] = f2bf(0.015625f * acc[fm][fn][rl]);
      }
    }
  }
}

// ---------------------------------------------------------------------------
// G = Y·Q^T, lower-triangle 128-blocks (K=512, bf16 out).  Grid (8, 8, 4).
// ---------------------------------------------------------------------------
__global__ __launch_bounds__(256) void gemm_YQ_bf16(
    const unsigned short* __restrict__ Y16a,
    const unsigned short* __restrict__ Q16a,
    unsigned short* __restrict__ G16a) {
  __shared__ unsigned short Alds[128][72];
  __shared__ unsigned short Blds[128][72];
  int row0 = blockIdx.y * 128;
  int col0 = blockIdx.x * 128;
  if (col0 > row0) return;
  int b = blockIdx.z;
  const unsigned short* Y = Y16a + (long long)b * 524288;
  const unsigned short* Q = Q16a + (long long)b * 524288;
  unsigned short* G = G16a + (long long)b * 1048576;
  int t = (int)threadIdx.x, lane = t & 63, wave = t >> 6;
  int wm = wave >> 1, wn = wave & 1;

  f32x4 acc[4][4];
#pragma unroll
  for (int i = 0; i < 4; i++)
#pragma unroll
    for (int j = 0; j < 4; j++) acc[i][j] = (f32x4){0.f, 0.f, 0.f, 0.f};

  int ar = t >> 2;
  int aq = (t & 3) * 16;
  const unsigned short* Ap = Y + (long long)(row0 + ar) * 512 + aq;
  const unsigned short* Ap2 = Ap + 64LL * 512;
  const unsigned short* Bp = Q + (long long)(col0 + ar) * 512 + aq;
  const unsigned short* Bp2 = Bp + 64LL * 512;

  for (int kb = 0; kb < 512; kb += 64) {
    i32x4 a0 = *(const i32x4*)(Ap + kb);
    i32x4 a1 = *(const i32x4*)(Ap + kb + 8);
    i32x4 a2 = *(const i32x4*)(Ap2 + kb);
    i32x4 a3 = *(const i32x4*)(Ap2 + kb + 8);
    i32x4 b0 = *(const i32x4*)(Bp + kb);
    i32x4 b1 = *(const i32x4*)(Bp + kb + 8);
    i32x4 b2 = *(const i32x4*)(Bp2 + kb);
    i32x4 b3 = *(const i32x4*)(Bp2 + kb + 8);
    __syncthreads();
    *(i32x4*)&Alds[ar][aq] = a0;
    *(i32x4*)&Alds[ar][aq + 8] = a1;
    *(i32x4*)&Alds[ar + 64][aq] = a2;
    *(i32x4*)&Alds[ar + 64][aq + 8] = a3;
    *(i32x4*)&Blds[ar][aq] = b0;
    *(i32x4*)&Blds[ar][aq + 8] = b1;
    *(i32x4*)&Blds[ar + 64][aq] = b2;
    *(i32x4*)&Blds[ar + 64][aq + 8] = b3;
    __syncthreads();

    int rr = lane & 15, ko = (lane >> 4) * 8;
#pragma unroll
    for (int k2 = 0; k2 < 2; k2++) {
      i32x4 af[4], bfv[4];
#pragma unroll
      for (int fm = 0; fm < 4; fm++)
        af[fm] = *(i32x4*)&Alds[wm * 64 + fm * 16 + rr][k2 * 32 + ko];
#pragma unroll
      for (int fn = 0; fn < 4; fn++)
        bfv[fn] = *(i32x4*)&Blds[wn * 64 + fn * 16 + rr][k2 * 32 + ko];
#pragma unroll
      for (int fm = 0; fm < 4; fm++)
#pragma unroll
        for (int fn = 0; fn < 4; fn++)
          acc[fm][fn] = mfma_bf16(af[fm], bfv[fn], acc[fm][fn]);
    }
  }

  int rq = lane >> 4, rr = lane & 15;
#pragma unroll
  for (int fm = 0; fm < 4; fm++) {
#pragma unroll
    for (int fn = 0; fn < 4; fn++) {
      int col = col0 + wn * 64 + fn * 16 + rr;
#pragma unroll
      for (int r = 0; r < 4; r++) {
        int row = row0 + wm * 64 + fm * 16 + rq * 4 + r;
        G[(long long)row * 1024 + col] = f2bf(acc[fm][fn][r]);
      }
    }
  }
}

// Mirror lower 128-blocks to upper (transpose16 body).  Grid (16, 16, 4).
__global__ __launch_bounds__(256) void mirror_G_kernel(
    unsigned short* __restrict__ G16a) {
  int txl = blockIdx.x, tyl = blockIdx.y;
  if ((txl >> 1) >= (tyl >> 1)) return;
  unsigned short* G = G16a + (long long)blockIdx.z * 1048576;
  __shared__ unsigned short T[64][72];
  int i0 = tyl * 64;
  int c0 = txl * 64;
  int t = (int)threadIdx.x;
  int r = t >> 2, cq = (t & 3) * 16;
  i32x4 v0 = *(const i32x4*)&G[(long long)(i0 + r) * 1024 + c0 + cq];
  i32x4 v1 = *(const i32x4*)&G[(long long)(i0 + r) * 1024 + c0 + cq + 8];
  *(i32x4*)&T[r][cq] = v0;
  *(i32x4*)&T[r][cq + 8] = v1;
  __syncthreads();
  int c = t >> 2, iq = (t & 3) * 16;
  unsigned short tmp[16];
#pragma unroll
  for (int j = 0; j < 16; j++) tmp[j] = T[iq + j][c];
  *(i32x4*)&G[(long long)(c0 + c) * 1024 + i0 + iq] = *(i32x4*)&tmp[0];
  *(i32x4*)&G[(long long)(c0 + c) * 1024 + i0 + iq + 8] = *(i32x4*)&tmp[8];
}

// ---------------------------------------------------------------------------
// M = C·G (bf16 MFMA, z-batched).
// ---------------------------------------------------------------------------
__global__ __launch_bounds__(256) void gemm_M_bf16(
    const unsigned short* __restrict__ Ca, const unsigned short* __restrict__ Ga,
    float* __restrict__ Ma) {
  int row0 = blockIdx.y * 64;
  int col0 = blockIdx.x * 64;
  if (col0 > row0) return;
  int b = blockIdx.z;
  const unsigned short* C = Ca + (long long)b * 1048576;
  const unsigned short* G = Ga + (long long)b * 1048576;
  float* M = Ma + (long long)b * 1048576;
  int Kend = row0 + 64;
  __shared__ unsigned short Asl[64][64];
  __shared__ unsigned short Bsl[64][64];
  int t = (int)threadIdx.x, lane = t & 63, wave = t >> 6;
  int wm = wave >> 1, wn = wave & 1;

  f32x4 acc[2][2];
#pragma unroll
  for (int i = 0; i < 2; i++)
#pragma unroll
    for (int j = 0; j < 2; j++) acc[i][j] = (f32x4){0.f, 0.f, 0.f, 0.f};

  int r = t >> 2, c0 = t & 3;
  int sw0 = ((c0 ^ (r & 7))) * 8;
  int sw1 = (((c0 + 4) ^ (r & 7))) * 8;
  const unsigned short* Ap = C + (long long)(row0 + r) * 1024 + c0 * 8;
  const unsigned short* Bp = G + (long long)(col0 + r) * 1024 + c0 * 8;

  for (int kb = 0; kb < Kend; kb += 64) {
    i32x4 a0 = *(const i32x4*)(Ap + kb);
    i32x4 a1 = *(const i32x4*)(Ap + kb + 32);
    i32x4 b0 = *(const i32x4*)(Bp + kb);
    i32x4 b1 = *(const i32x4*)(Bp + kb + 32);
    __syncthreads();
    *(i32x4*)&Asl[r][sw0] = a0;
    *(i32x4*)&Asl[r][sw1] = a1;
    *(i32x4*)&Bsl[r][sw0] = b0;
    *(i32x4*)&Bsl[r][sw1] = b1;
    __syncthreads();

    int rr = lane & 15, co = lane >> 4;
#pragma unroll
    for (int k2 = 0; k2 < 2; k2++) {
      int ch = ((k2 * 4 + co) ^ (rr & 7)) * 8;
      i32x4 af0 = *(i32x4*)&Asl[wm * 32 + rr][ch];
      i32x4 af1 = *(i32x4*)&Asl[wm * 32 + 16 + rr][ch];
      i32x4 bf0 = *(i32x4*)&Bsl[wn * 32 + rr][ch];
      i32x4 bf1 = *(i32x4*)&Bsl[wn * 32 + 16 + rr][ch];
      acc[0][0] = mfma_bf16(af0, bf0, acc[0][0]);
      acc[0][1] = mfma_bf16(af0, bf1, acc[0][1]);
      acc[1][0] = mfma_bf16(af1, bf0, acc[1][0]);
      acc[1][1] = mfma_bf16(af1, bf1, acc[1][1]);
    }
  }

  int rq = lane >> 4, rr = lane & 15;
#pragma unroll
  for (int fm = 0; fm < 2; fm++) {
#pragma unroll
    for (int fn = 0; fn < 2; fn++) {
      int j = col0 + wn * 32 + fn * 16 + rr;
#pragma unroll
      for (int rl = 0; rl < 4; rl++) {
        int i = row0 + wm * 32 + fm * 16 + rq * 4 + rl;
        M[(long long)i * 1024 + j] = acc[fm][fn][rl];
      }
    }
  }
}

// ---------------------------------------------------------------------------
// Fused scldot + b-update + causal softmax (it0/it1).  Grid (1024, 4).
// ---------------------------------------------------------------------------
template <int INIT>
__global__ __launch_bounds__(256) void fused_scl_bupd_kernel(
    float* __restrict__ bHa, const float* __restrict__ Ma,
    unsigned short* __restrict__ cH16a) {
  __shared__ float red[4];
  int i = blockIdx.x;
  int b = blockIdx.y;
  float* bH = bHa + (long long)b * 1048576;
  const float* M = Ma + (long long)b * 1048576;
  unsigned short* cH16 = cH16a + (long long)b * 1048576;
  long long base = (long long)i * 1024;
  int t = (int)threadIdx.x, k0 = t * 4;
  float4 m = *(const float4*)&M[base + k0];
  uint2 pc = *(const uint2*)&cH16[base + k0];
  float c0 = bf2f(pc.x & 0xffffu), c1 = bf2f(pc.x >> 16);
  float c2 = bf2f(pc.y & 0xffffu), c3 = bf2f(pc.y >> 16);
  bool m0 = (k0 + 0) <= i, m1 = (k0 + 1) <= i, m2 = (k0 + 2) <= i,
       m3 = (k0 + 3) <= i;
  float acc = 0.f;
  if (m0) acc += c0 * m.x;
  if (m1) acc += c1 * m.y;
  if (m2) acc += c2 * m.z;
  if (m3) acc += c3 * m.w;
  float ssq = blockSum(acc, red);
  float sc = (ssq / (1.f + ssq)) / sqrtf(ssq + SQ_EPS);

  float4 x;
  if (INIT) x = (float4){0.f, 0.f, 0.f, 0.f};
  else x = *(const float4*)&bH[base + k0];
  if (m0) x.x += sc * m.x;
  if (m1) x.y += sc * m.y;
  if (m2) x.z += sc * m.z;
  if (m3) x.w += sc * m.w;
  *(float4*)&bH[base + k0] = x;
  float mx = -3.0e38f;
  if (m0) mx = fmaxf(mx, x.x);
  if (m1) mx = fmaxf(mx, x.y);
  if (m2) mx = fmaxf(mx, x.z);
  if (m3) mx = fmaxf(mx, x.w);
  mx = blockMax(mx, red);
  float e0 = m0 ? expf(x.x - mx) : 0.f;
  float e1 = m1 ? expf(x.y - mx) : 0.f;
  float e2 = m2 ? expf(x.z - mx) : 0.f;
  float e3 = m3 ? expf(x.w - mx) : 0.f;
  float zz = blockSum(e0 + e1 + e2 + e3, red);
  float inv = 1.f / zz;
  uint2 o = {(unsigned int)f2bf(e0 * inv) | ((unsigned int)f2bf(e1 * inv) << 16),
             (unsigned int)f2bf(e2 * inv) | ((unsigned int)f2bf(e3 * inv) << 16)};
  *(uint2*)&cH16[base + k0] = o;
}

// ||s_i||^2 -> scl (it2).  Grid (1024, 4).
__global__ __launch_bounds__(256) void scldot_kernel(
    const float* __restrict__ Ma, const unsigned short* __restrict__ Ca,
    float* __restrict__ scl) {
  __shared__ float red[4];
  int i = blockIdx.x;
  int b = blockIdx.y;
  const float* M = Ma + (long long)b * 1048576;
  const unsigned short* C = Ca + (long long)b * 1048576;
  int t = (int)threadIdx.x, j0 = t * 4;
  long long base = (long long)i * 1024;
  float4 m = *(const float4*)&M[base + j0];
  uint2 pc = *(const uint2*)&C[base + j0];
  float c0 = bf2f(pc.x & 0xffffu), c1 = bf2f(pc.x >> 16);
  float c2 = bf2f(pc.y & 0xffffu), c3 = bf2f(pc.y >> 16);
  float acc = 0.f;
  if (j0 + 0 <= i) acc += c0 * m.x;
  if (j0 + 1 <= i) acc += c1 * m.y;
  if (j0 + 2 <= i) acc += c2 * m.z;
  if (j0 + 3 <= i) acc += c3 * m.w;
  float ssq = blockSum(acc, red);
  if (t == 0) scl[b * 1024 + i] = (ssq / (1.f + ssq)) / sqrtf(ssq + SQ_EPS);
}

// it=0 coupling.  Grid (1024, 4).
__global__ __launch_bounds__(256) void softmax_uniform_kernel(
    unsigned short* __restrict__ cH16a) {
  int i = blockIdx.x;
  int b = blockIdx.y;
  unsigned short* cH16 = cH16a + (long long)b * 1048576;
  int t = (int)threadIdx.x, k0 = t * 4;
  unsigned short c = f2bf(1.f / (float)(i + 1));
  unsigned short e0 = (k0 + 0) <= i ? c : (unsigned short)0;
  unsigned short e1 = (k0 + 1) <= i ? c : (unsigned short)0;
  unsigned short e2 = (k0 + 2) <= i ? c : (unsigned short)0;
  unsigned short e3 = (k0 + 3) <= i ? c : (unsigned short)0;
  uint2 o = {(unsigned int)e0 | ((unsigned int)e1 << 16),
             (unsigned int)e2 | ((unsigned int)e3 << 16)};
  *(uint2*)&cH16[(long long)i * 1024 + k0] = o;
}

// ---------------------------------------------------------------------------
// R = C·Q (causal).  Grid (4, 8, 4).
// ---------------------------------------------------------------------------
__global__ __launch_bounds__(256) void gemm_R_bf16(
    const unsigned short* __restrict__ Ca, const unsigned short* __restrict__ QTa,
    unsigned short* __restrict__ R16a) {
  __shared__ unsigned short Alds[128][32];
  __shared__ unsigned short Blds[128][32];
  int b = blockIdx.z;
  const unsigned short* Abf = Ca + (long long)b * 1048576;
  const unsigned short* BT = QTa + (long long)b * 524288;
  unsigned short* Cout = R16a + (long long)b * 524288;
  int rowblk = 7 - (int)blockIdx.y;
  int row0 = rowblk * 128;
  int col0 = blockIdx.x * 128;
  int t = (int)threadIdx.x, lane = t & 63, wave = t >> 6;
  int wm = wave >> 1, wn = wave & 1;
  int Kend = row0 + 128;

  f32x4 acc[4][4];
#pragma unroll
  for (int i = 0; i < 4; i++)
#pragma unroll
    for (int j = 0; j < 4; j++) acc[i][j] = (f32x4){0.f, 0.f, 0.f, 0.f};

  int ar = t >> 2;
  int aq = (t & 3) * 8;

  for (int kb = 0; kb < Kend; kb += 32) {
    i32x4 a0 = *(const i32x4*)&Abf[(long long)(row0 + ar) * 1024 + kb + aq];
    i32x4 a1 = *(const i32x4*)&Abf[(long long)(row0 + ar + 64) * 1024 + kb + aq];
    i32x4 b0 = *(const i32x4*)&BT[(long long)(col0 + ar) * 1024 + kb + aq];
    i32x4 b1 = *(const i32x4*)&BT[(long long)(col0 + ar + 64) * 1024 + kb + aq];
    __syncthreads();
    *(i32x4*)&Alds[ar][aq] = a0;
    *(i32x4*)&Alds[ar + 64][aq] = a1;
    *(i32x4*)&Blds[ar][aq] = b0;
    *(i32x4*)&Blds[ar + 64][aq] = b1;
    __syncthreads();

    int rr = lane & 15, koff = (lane >> 4) * 8;
    i32x4 af[4], bfv[4];
#pragma unroll
    for (int fm = 0; fm < 4; fm++)
      af[fm] = *(i32x4*)&Alds[wm * 64 + fm * 16 + rr][koff];
#pragma unroll
    for (int fn = 0; fn < 4; fn++)
      bfv[fn] = *(i32x4*)&Blds[wn * 64 + fn * 16 + rr][koff];
#pragma unroll
    for (int fm = 0; fm < 4; fm++)
#pragma unroll
      for (int fn = 0; fn < 4; fn++)
        acc[fm][fn] = mfma_bf16(af[fm], bfv[fn], acc[fm][fn]);
  }

  int rq = lane >> 4, rr = lane & 15;
#pragma unroll
  for (int fm = 0; fm < 4; fm++) {
#pragma unroll
    for (int fn = 0; fn < 4; fn++) {
      int col = col0 + wn * 64 + fn * 16 + rr;
#pragma unroll
      for (int r = 0; r < 4; r++) {
        int row = row0 + wm * 64 + fm * 16 + rq * 4 + r;
        Cout[(long long)row * 512 + col] = f2bf(acc[fm][fn][r]);
      }
    }
  }
}

// ---------------------------------------------------------------------------
// ctx (bf16 MFMA, bf16 out).  Grid (64, 8).
// ---------------------------------------------------------------------------
__global__ __launch_bounds__(256) void gemm_ctx_bf16(
    const unsigned short* __restrict__ w16,
    const unsigned short* __restrict__ VTa, unsigned short* __restrict__ ctx16) {
  int row0 = blockIdx.x * 64;
  int b = blockIdx.x >> 4;
  int h = blockIdx.y;
  const unsigned short* VT = VTa + (long long)b * 524288;
  __shared__ unsigned short Asl[64][68];
  __shared__ unsigned short Bsl[64][68];
  int t = (int)threadIdx.x, lane = t & 63, wave = t >> 6;

  f32x4 acc[4];
#pragma unroll
  for (int i = 0; i < 4; i++) acc[i] = (f32x4){0.f, 0.f, 0.f, 0.f};

  int r = t >> 2, kq = (t & 3) * 8;
  const unsigned short* Ap = w16 + (long long)(row0 + r) * 8192 + h * 1024 + kq;
  const unsigned short* Bp = VT + (long long)(h * 64 + r) * 1024 + kq;

  for (int kb = 0; kb < 1024; kb += 64) {
    i32x4 a0 = *(const i32x4*)(Ap + kb);
    i32x4 a1 = *(const i32x4*)(Ap + kb + 32);
    i32x4 b0 = *(const i32x4*)(Bp + kb);
    i32x4 b1 = *(const i32x4*)(Bp + kb + 32);
    __syncthreads();
    *(i32x4*)&Asl[r][kq] = a0;
    *(i32x4*)&Asl[r][kq + 32] = a1;
    *(i32x4*)&Bsl[r][kq] = b0;
    *(i32x4*)&Bsl[r][kq + 32] = b1;
    __syncthreads();

    int rr = lane & 15, ko = (lane >> 4) * 8;
#pragma unroll
    for (int k2 = 0; k2 < 2; k2++) {
      i32x4 af = *(i32x4*)&Asl[wave * 16 + rr][k2 * 32 + ko];
#pragma unroll
      for (int fn = 0; fn < 4; fn++) {
        i32x4 bf = *(i32x4*)&Bsl[fn * 16 + rr][k2 * 32 + ko];
        acc[fn] = mfma_bf16(af, bf, acc[fn]);
      }
    }
  }

  int rq = lane >> 4, rr = lane & 15;
#pragma unroll
  for (int fn = 0; fn < 4; fn++) {
#pragma unroll
    for (int rl = 0; rl < 4; rl++) {
      int i = row0 + wave * 16 + rq * 4 + rl;
      ctx16[(long long)i * 512 + h * 64 + fn * 16 + rr] = f2bf(acc[fn][rl]);
    }
  }
}

// ---------------------------------------------------------------------------
// Vertical routing.  Grid 4096.
// ---------------------------------------------------------------------------
__global__ __launch_bounds__(256) void vertical_routing_kernel(
    const unsigned short* __restrict__ u16, float* __restrict__ vV) {
  __shared__ float Ur[8 * 1024];
  __shared__ float red[4];
  __shared__ float red8[32];
  int bq = blockIdx.x;
  int t = (int)threadIdx.x;
  const unsigned short* Ub = u16 + (long long)bq * 8192;
#pragma unroll
  for (int r = 0; r < 8; r++) {
    uint2 p = *(const uint2*)&Ub[(t + 256 * r) * 4];
    Ur[(t + 256 * r) * 4 + 0] = bf2f(p.x & 0xffffu);
    Ur[(t + 256 * r) * 4 + 1] = bf2f(p.x >> 16);
    Ur[(t + 256 * r) * 4 + 2] = bf2f(p.y & 0xffffu);
    Ur[(t + 256 * r) * 4 + 3] = bf2f(p.y >> 16);
  }
  __syncthreads();

  float bh[8] = {0.f, 0.f, 0.f, 0.f, 0.f, 0.f, 0.f, 0.f};
  int k0 = t * 4;
  float4 v4 = {0.f, 0.f, 0.f, 0.f};
  for (int it = 0; it < 3; ++it) {
    float m = bh[0];
#pragma unroll
    for (int h = 1; h < 8; h++) m = fmaxf(m, bh[h]);
    float c[8], zz = 0.f;
#pragma unroll
    for (int h = 0; h < 8; h++) {
      c[h] = expf(bh[h] - m);
      zz += c[h];
    }
    float inv = 1.f / zz;
    float4 s4 = {0.f, 0.f, 0.f, 0.f};
#pragma unroll
    for (int h = 0; h < 8; h++) {
      float4 u = *(float4*)&Ur[h * 1024 + k0];
      float ch = c[h] * inv;
      s4.x = fmaf(ch, u.x, s4.x); s4.y = fmaf(ch, u.y, s4.y);
      s4.z = fmaf(ch, u.z, s4.z); s4.w = fmaf(ch, u.w, s4.w);
    }
    float sq =
        blockSum(s4.x * s4.x + s4.y * s4.y + s4.z * s4.z + s4.w * s4.w, red);
    float sc = (sq / (1.f + sq)) / sqrtf(sq + SQ_EPS);
    v4.x = sc * s4.x; v4.y = sc * s4.y; v4.z = sc * s4.z; v4.w = sc * s4.w;
    if (it < 2) {
      float p[8];
#pragma unroll
      for (int h = 0; h < 8; h++) {
        float4 u = *(float4*)&Ur[h * 1024 + k0];
        p[h] = u.x * v4.x + u.y * v4.y + u.z * v4.z + u.w * v4.w;
      }
      __syncthreads();
#pragma unroll
      for (int h = 0; h < 8; h++) {
        float w = wredSum(p[h]);
        if ((t & 63) == 0) red8[(t >> 6) * 8 + h] = w;
      }
      __syncthreads();
#pragma unroll
      for (int h = 0; h < 8; h++)
        bh[h] += red8[h] + red8[8 + h] + red8[16 + h] + red8[24 + h];
    }
  }
  *(float4*)&vV[(long long)bq * 1024 + k0] = v4;
}

// enhanced softmax.  Grid 32768.
__global__ __launch_bounds__(256) void enh_softmax_kernel(
    unsigned short* __restrict__ u16, const float* __restrict__ vV,
    const unsigned short* __restrict__ v16) {
  __shared__ float red[4];
  int idx = blockIdx.x;
  int h = idx & 7;
  int bq = idx >> 3;
  unsigned short* Urow = u16 + (long long)bq * 8192 + h * 1024;
  const float* va = vV + (long long)bq * 1024;
  const unsigned short* vb = v16 + (long long)bq * 8192 + h * 1024;
  int t = (int)threadIdx.x, k0 = t * 4;
  uint2 pu = *(const uint2*)&Urow[k0];
  float4 a = *(const float4*)&va[k0];
  uint2 pb = *(const uint2*)&vb[k0];
  float x0 = bf2f(pu.x & 0xffffu) + a.x + bf2f(pb.x & 0xffffu);
  float x1 = bf2f(pu.x >> 16) + a.y + bf2f(pb.x >> 16);
  float x2 = bf2f(pu.y & 0xffffu) + a.z + bf2f(pb.y & 0xffffu);
  float x3 = bf2f(pu.y >> 16) + a.w + bf2f(pb.y >> 16);
  float mx = blockMax(fmaxf(fmaxf(x0, x1), fmaxf(x2, x3)), red);
  float e0 = expf(x0 - mx), e1 = expf(x1 - mx), e2 = expf(x2 - mx),
        e3 = expf(x3 - mx);
  float zz = blockSum(e0 + e1 + e2 + e3, red);
  float inv = 1.f / zz;
  uint2 o = {(unsigned int)f2bf(e0 * inv) | ((unsigned int)f2bf(e1 * inv) << 16),
             (unsigned int)f2bf(e2 * inv) | ((unsigned int)f2bf(e3 * inv) << 16)};
  *(uint2*)&Urow[k0] = o;
}

// ---------------------------------------------------------------------------
extern "C" void kernel_launch(void* const* d_in, const int* in_sizes, int n_in,
                              void* d_out, int out_size, void* d_ws,
                              size_t ws_size, hipStream_t stream) {
  (void)in_sizes; (void)n_in; (void)out_size; (void)ws_size;
  const float* x = (const float*)d_in[0];
  const float* Wq = (const float*)d_in[1];
  const float* bq = (const float*)d_in[2];
  const float* Wk = (const float*)d_in[3];
  const float* bk = (const float*)d_in[4];
  const float* Wv = (const float*)d_in[5];
  const float* bv = (const float*)d_in[6];
  const float* Wo = (const float*)d_in[7];
  const float* bo = (const float*)d_in[8];
  float* out = (float*)d_out;
  float* ws = (float*)d_ws;

  unsigned short* u16a = (unsigned short*)(ws);              // 16M fl
  unsigned short* QT16 = (unsigned short*)(ws + 16777216);   // 1M fl
  unsigned short* K16 = (unsigned short*)(ws + 17825792);    // 1M fl
  unsigned short* KT16 = (unsigned short*)(ws + 18874368);   // 1M fl
  unsigned short* T16 = (unsigned short*)(ws + 19922944);    // 64K fl slot
  unsigned short* Y16 = (unsigned short*)(ws + 20971520);    // 1M fl
  unsigned short* Q16 = (unsigned short*)(ws + 22020096);    // 1M fl
  // Win @ 23068672 .. 39845888 (16M fl), time-multiplexed:
  float* Qf = ws + 23068672;                                 // 2M
  float* Kf = ws + 25165824;                                 // 2M
  unsigned short* V16a = (unsigned short*)(ws + 27262976);   // 1M fl
  unsigned short* sv16a = (unsigned short*)(ws + 23068672);  // 16M fl
  float* Mbufa = ws + 39845888;                              // 4M fl
  unsigned short* R16 = (unsigned short*)(ws + 39845888);    // 1M fl (after M)
  float* vVa = ws + 44040192;                                // 4M
  float* bHa = ws + 48234496;                                // 4M
  unsigned short* ctx16 = (unsigned short*)(ws + 48234496);  // overlays bHa
  unsigned short* cH16a = (unsigned short*)(ws + 52428800);  // 2M fl
  unsigned short* G16a = (unsigned short*)(ws + 54525952);   // 2M fl
  unsigned short* VT16a = (unsigned short*)(ws + 56623104);  // 1M fl
  unsigned short* WT16 = (unsigned short*)(ws + 57671680);   // 0.5M fl
  float* scl = ws + 58195968;                                // 4096
  // total 58,200,064 fl = 222 MiB

  // 1-4. prologue
  wtrans_kernel<<<dim3(8, 8, 4), 256, 0, stream>>>(Wq, Wk, Wv, Wo, WT16);
  gemm_qkv_mfma<<<dim3(8, 64, 3), 256, 0, stream>>>(x, WT16, bq, bk, bv, Qf,
                                                    Kf, Q16, K16, V16a);
  transpose16_kernel<<<dim3(16, 8, 4), 256, 0, stream>>>(V16a, VT16a, 512,
                                                         1024, 524288, 524288);
  transpose_f32_bf16_kernel<<<dim3(16, 8, 4), 256, 0, stream>>>(
      Qf, QT16, 512, 1024, 524288, 524288);
  transpose_f32_bf16_kernel<<<dim3(16, 8, 4), 256, 0, stream>>>(
      Kf, KT16, 512, 1024, 524288, 524288);

  // 5. scores (fp32, accuracy-pinned, double-buffered) -> u16a, all batches
  gemm_scores_bf16<<<dim3(8, 8, 32), 256, 0, stream>>>(Qf, Kf, u16a);

  // 6. vertical routing, all batches
  vertical_routing_kernel<<<dim3(4096), 256, 0, stream>>>(u16a, vVa);

  // 7. factored Gram: T = (1/64)K^T K; Y = Q·T; G = Y·Q^T (+mirror)
  gemm_T_bf16<<<dim3(32), 256, 0, stream>>>(KT16, T16);
  gemm_Y_bf16<<<dim3(1, 16, 32), 256, 0, stream>>>(Q16, T16, Y16);
  gemm_YQ_bf16<<<dim3(8, 8, 4), 256, 0, stream>>>(Y16, Q16, G16a);
  mirror_G_kernel<<<dim3(16, 16, 4), 256, 0, stream>>>(G16a);

  // 8. horizontal routing iterations (all batches per stage)
  softmax_uniform_kernel<<<dim3(1024, 4), 256, 0, stream>>>(cH16a);
  gemm_M_bf16<<<dim3(16, 16, 4), 256, 0, stream>>>(cH16a, G16a, Mbufa);
  fused_scl_bupd_kernel<1><<<dim3(1024, 4), 256, 0, stream>>>(bHa, Mbufa,
                                                              cH16a);
  gemm_M_bf16<<<dim3(16, 16, 4), 256, 0, stream>>>(cH16a, G16a, Mbufa);
  fused_scl_bupd_kernel<0><<<dim3(1024, 4), 256, 0, stream>>>(bHa, Mbufa,
                                                              cH16a);
  gemm_M_bf16<<<dim3(16, 16, 4), 256, 0, stream>>>(cH16a, G16a, Mbufa);
  scldot_kernel<<<dim3(1024, 4), 256, 0, stream>>>(Mbufa, cH16a, scl);

  // 9. factored final s: R = C·Q (causal), sv = scl·0.125·R·K^T
  gemm_R_bf16<<<dim3(4, 8, 4), 256, 0, stream>>>(cH16a, QT16, R16);
  gemm_sfinal<<<dim3(16, 16, 32), 256, 0, stream>>>(R16, K16, scl, sv16a);

  // 10. enhanced + softmax -> w into u16a
  enh_softmax_kernel<<<dim3(32768), 256, 0, stream>>>(u16a, vVa, sv16a);

  // 11. ctx = w x V (bf16 out, writes over dead bHa)
  gemm_ctx_bf16<<<dim3(64, 8), 256, 0, stream>>>(u16a, VT16a, ctx16);

  // 12. out = ctx16 x Wo + bo (bf16 MFMA, Wo^T at WT16 + 3*262144)
  gemm_out_mfma<<<dim3(8, 64), 256, 0, stream>>>(ctx16, WT16 + 786432, bo,
                                                 out);
}